// Round 5
// baseline (1519.158 us; speedup 1.0000x reference)
//
#include <hip/hip_runtime.h>
#include <math.h>

#define NN 100000
#define NE 400000
#define FI 64
#define HH 256
#define KT 50000
#define RPN (NN+1)

typedef unsigned short u16;
typedef __attribute__((ext_vector_type(8))) short bf16x8;
typedef __attribute__((ext_vector_type(4))) short bf16x4;
typedef __attribute__((ext_vector_type(4))) float f32x4;

__device__ __forceinline__ float leaky02(float x){ return x >= 0.f ? x : 0.2f*x; }
__device__ __forceinline__ float preluf(float x, float a){ return x >= 0.f ? x : a*x; }

__device__ __forceinline__ float wredmax(float v){
  #pragma unroll
  for (int o=32;o>0;o>>=1) v = fmaxf(v, __shfl_xor(v, o, 64));
  return v;
}
__device__ __forceinline__ float wredsum(float v){
  #pragma unroll
  for (int o=32;o>0;o>>=1) v += __shfl_xor(v, o, 64);
  return v;
}
__device__ __forceinline__ float qredsum(float v){
  #pragma unroll
  for (int o=8;o>0;o>>=1) v += __shfl_xor(v, o, 64);
  return v;
}

// barrier that does NOT drain vmcnt (keeps prefetch loads in flight)
__device__ __forceinline__ void softBarrier(){
  asm volatile("s_waitcnt lgkmcnt(0)" ::: "memory");
  __builtin_amdgcn_s_barrier();
}

__device__ __forceinline__ void atomicMaxF(float* a, float v){
  if (v >= 0.f) atomicMax((int*)a, __float_as_int(v));
  else atomicMin((unsigned int*)a, __float_as_uint(v));
}

__device__ __forceinline__ float4 bnprelu4(float4 v, float4 sc, float4 sh, float a){
  float4 r;
  r.x = preluf(v.x*sc.x+sh.x, a);
  r.y = preluf(v.y*sc.y+sh.y, a);
  r.z = preluf(v.z*sc.z+sh.z, a);
  r.w = preluf(v.w*sc.w+sh.w, a);
  return r;
}

__device__ __forceinline__ u16 f2bf(float f){
  unsigned u = __float_as_uint(f);
  unsigned r = u + 0x7FFFu + ((u>>16)&1u);
  return (u16)(r>>16);
}
__device__ __forceinline__ float bf2f(u16 h){
  return __uint_as_float(((unsigned)h)<<16);
}
__device__ __forceinline__ void split8(float4 a, float4 b, bf16x8& h, bf16x8& l){
  float va[8] = {a.x,a.y,a.z,a.w,b.x,b.y,b.z,b.w};
  #pragma unroll
  for (int j=0;j<8;j++){
    u16 hh = f2bf(va[j]);
    h[j] = (short)hh;
    l[j] = (short)f2bf(va[j] - bf2f(hh));
  }
}

// ---------------- CSR build (batched over blockIdx.y) ----------------
__global__ void k_count(const int* __restrict__ eiA, const int* __restrict__ eiB, int* __restrict__ deg_){
  int br = blockIdx.y;
  const int* dst = (br ? eiB : eiA) + NE;
  int* deg = deg_ + (size_t)br*NN;
  int e = blockIdx.x*blockDim.x + threadIdx.x;
  if (e < NE) atomicAdd(&deg[dst[e]], 1);
}

__global__ __launch_bounds__(1024) void k_scan1(const int* __restrict__ deg_, int* __restrict__ rowptr_, int* __restrict__ bsums_){
  int br = blockIdx.y;
  const int* deg = deg_ + (size_t)br*NN;
  int* rowptr = rowptr_ + (size_t)br*RPN;
  int* bsums = bsums_ + (size_t)br*128;
  __shared__ int sm[1024];
  int t = threadIdx.x; int g = blockIdx.x*1024 + t;
  int v = (g < NN) ? deg[g] : 0;
  sm[t] = v; __syncthreads();
  for (int o=1;o<1024;o<<=1){
    int add = (t>=o)? sm[t-o] : 0;
    __syncthreads();
    sm[t] += add;
    __syncthreads();
  }
  if (g < NN) rowptr[g] = sm[t] - v;
  if (t == 1023) bsums[blockIdx.x] = sm[1023];
}

__global__ __launch_bounds__(128) void k_scan2(int* __restrict__ bsums_, int nblk){
  int br = blockIdx.y;
  int* bsums = bsums_ + (size_t)br*128;
  __shared__ int sm[128];
  int t = threadIdx.x;
  int v = (t < nblk) ? bsums[t] : 0;
  sm[t] = v; __syncthreads();
  for (int o=1;o<128;o<<=1){
    int add = (t>=o)? sm[t-o] : 0;
    __syncthreads();
    sm[t] += add;
    __syncthreads();
  }
  if (t < nblk) bsums[t] = sm[t] - v;
}

__global__ __launch_bounds__(1024) void k_scan3(int* __restrict__ rowptr_, const int* __restrict__ bsums_, int* __restrict__ cursor_){
  int br = blockIdx.y;
  int* rowptr = rowptr_ + (size_t)br*RPN;
  const int* bsums = bsums_ + (size_t)br*128;
  int* cursor = cursor_ + (size_t)br*NN;
  int g = blockIdx.x*1024 + threadIdx.x;
  if (g < NN){ int r = rowptr[g] + bsums[blockIdx.x]; rowptr[g] = r; cursor[g] = r; }
  if (blockIdx.x==0 && threadIdx.x==0) rowptr[NN] = NE;
}

__global__ void k_scatter(const int* __restrict__ eiA, const int* __restrict__ eiB, int* __restrict__ cursor_, int* __restrict__ adj_){
  int br = blockIdx.y;
  const int* ei = br ? eiB : eiA;
  const int* src = ei;
  const int* dst = ei + NE;
  int* cursor = cursor_ + (size_t)br*NN;
  int* adj = adj_ + (size_t)br*NE;
  int e = blockIdx.x*blockDim.x + threadIdx.x;
  if (e < NE){ int d = dst[e]; int slot = atomicAdd(&cursor[d], 1); adj[slot] = src[e]; }
}

// ---------------- W pre-split (merged big + gat W) ----------------
__global__ __launch_bounds__(256) void k_splitWall(const float* __restrict__ WrA, const float* __restrict__ WrB,
    const float* __restrict__ WlA, const float* __restrict__ WlB,
    const float* __restrict__ WgA, const float* __restrict__ WgB,
    u16* __restrict__ WtT_, u16* __restrict__ WtT1_){
  int br = blockIdx.y;
  if (blockIdx.x < 512){
    const float* Wr = br ? WrB : WrA;
    const float* Wl = br ? WlB : WlA;
    u16* WtT = WtT_ + (size_t)br*16*16384;
    int idx = blockIdx.x*256 + threadIdx.x;
    int k = idx >> 8, n = idx & 255;
    float v = (k < HH) ? Wr[(size_t)k*HH + n] : Wl[(size_t)(k-HH)*HH + n];
    u16 hi = f2bf(v);
    float lo = v - bf2f(hi);
    size_t base = ((size_t)(k>>5))*16384 + (size_t)((k>>3)&3)*4096 + (size_t)n*8 + (k&7);
    WtT[base] = hi;
    WtT[base + 2048] = f2bf(lo);
  } else {
    const float* W = br ? WgB : WgA;
    u16* WtT = WtT1_ + (size_t)br*2*16384;
    int idx = (blockIdx.x-512)*256 + threadIdx.x;   // 64*256
    int k = idx >> 8, n = idx & 255;
    float v = W[(size_t)k*HH + n];
    u16 hi = f2bf(v);
    float lo = v - bf2f(hi);
    size_t base = ((size_t)(k>>5))*16384 + (size_t)((k>>3)&3)*4096 + (size_t)n*8 + (k&7);
    WtT[base] = hi;
    WtT[base + 2048] = f2bf(lo);
  }
}

#define ASTRIDE 528
#define ASTRIDE2 1040

// ---------------- GEMM1 ----------------
__global__ __launch_bounds__(256, 2) void k_gemm1(const float* __restrict__ xA, const float* __restrict__ xB,
    const u16* __restrict__ WtT_,
    const float* __restrict__ asA, const float* __restrict__ asB,
    const float* __restrict__ adA, const float* __restrict__ adB,
    float* __restrict__ out_, float* __restrict__ asrc_, float* __restrict__ adst_){
  int br = blockIdx.y;
  const float* x = br ? xB : xA;
  const u16* WtT = WtT_ + (size_t)br*2*16384;
  const float* a_src = br ? asB : asA;
  const float* a_dst = br ? adB : adA;
  float* out = out_ + (size_t)br*NN*HH;
  float* asrc = asrc_ + (size_t)br*NN;
  float* adst = adst_ + (size_t)br*NN;

  __shared__ u16 As[2][8*ASTRIDE];
  int tid = threadIdx.x;
  int row0 = blockIdx.x*64;
  int wave = tid>>6, lane = tid&63;
  int l15 = lane&15, quad = lane>>4;
  int col0 = wave*64;
  int sm_ = tid >> 2, sg = tid & 3;
  int sgrow = row0 + sm_; if (sgrow >= NN) sgrow = NN-1;
  f32x4 acc[4][4];
  #pragma unroll
  for (int mt=0;mt<4;mt++)
    #pragma unroll
    for (int nt=0;nt<4;nt++){ f32x4 z = {0.f,0.f,0.f,0.f}; acc[mt][nt] = z; }

  const u16* bbase = WtT + ((size_t)quad<<12) + (size_t)(col0 + l15)*8;
  bf16x8 B0h[4],B0l[4],B1h[4],B1l[4];
  float4 va0, va1;

  auto loadA = [&](int kc){
    va0 = *((const float4*)(x + (size_t)sgrow*FI + kc + sg*8));
    va1 = *((const float4*)(x + (size_t)sgrow*FI + kc + sg*8 + 4));
  };
  auto writeA = [&](int wb){
    bf16x8 h, l;
    split8(va0, va1, h, l);
    *((bf16x8*)&As[wb][sg*ASTRIDE + sm_*8]) = h;
    *((bf16x8*)&As[wb][(4+sg)*ASTRIDE + sm_*8]) = l;
  };
  auto loadB = [&](int ck, bf16x8 (&Bh)[4], bf16x8 (&Bl)[4]){
    const u16* bb = bbase + ((size_t)ck<<14);
    #pragma unroll
    for (int nt=0;nt<4;nt++){
      Bh[nt] = *((const bf16x8*)(bb + nt*128));
      Bl[nt] = *((const bf16x8*)(bb + 2048 + nt*128));
    }
  };
  auto mmacc = [&](int rb, bf16x8 (&Bh)[4], bf16x8 (&Bl)[4]){
    bf16x8 ah[4], al[4];
    #pragma unroll
    for (int mt=0;mt<4;mt++){
      int m = mt*16 + l15;
      ah[mt] = *((bf16x8*)&As[rb][quad*ASTRIDE + m*8]);
      al[mt] = *((bf16x8*)&As[rb][(4+quad)*ASTRIDE + m*8]);
    }
    #pragma unroll
    for (int nt=0;nt<4;nt++)
      #pragma unroll
      for (int mt=0;mt<4;mt++){
        acc[mt][nt] = __builtin_amdgcn_mfma_f32_16x16x32_bf16(ah[mt], Bh[nt], acc[mt][nt], 0, 0, 0);
        acc[mt][nt] = __builtin_amdgcn_mfma_f32_16x16x32_bf16(al[mt], Bh[nt], acc[mt][nt], 0, 0, 0);
        acc[mt][nt] = __builtin_amdgcn_mfma_f32_16x16x32_bf16(ah[mt], Bl[nt], acc[mt][nt], 0, 0, 0);
      }
  };

  loadA(0);
  writeA(0);
  loadA(32);
  loadB(0, B0h, B0l);
  softBarrier();
  writeA(1);
  loadB(1, B1h, B1l);
  mmacc(0, B0h, B0l);
  softBarrier();
  mmacc(1, B1h, B1l);

  float ps[4][4], pd[4][4];
  #pragma unroll
  for (int mt=0;mt<4;mt++)
    #pragma unroll
    for (int r=0;r<4;r++){ ps[mt][r]=0.f; pd[mt][r]=0.f; }
  #pragma unroll
  for (int nt=0;nt<4;nt++){
    int c = col0 + nt*16 + l15;
    float av = a_src[c], dv = a_dst[c];
    #pragma unroll
    for (int mt=0;mt<4;mt++){
      int gbase = row0 + mt*16 + quad*4;
      #pragma unroll
      for (int r=0;r<4;r++){
        int grow = gbase + r;
        float v = acc[mt][nt][r];
        if (grow < NN) out[(size_t)grow*HH + c] = v;
        ps[mt][r] += v*av; pd[mt][r] += v*dv;
      }
    }
  }
  __syncthreads();
  float* sda = (float*)As;
  float* sdd = sda + 256;
  #pragma unroll
  for (int mt=0;mt<4;mt++)
    #pragma unroll
    for (int r=0;r<4;r++){
      float s = qredsum(ps[mt][r]);
      float d = qredsum(pd[mt][r]);
      if (l15 == 0){
        int row = mt*16 + quad*4 + r;
        sda[wave*64 + row] = s;
        sdd[wave*64 + row] = d;
      }
    }
  __syncthreads();
  if (tid < 64){
    int grow = row0 + tid;
    if (grow < NN){
      asrc[grow] = sda[tid] + sda[64+tid] + sda[128+tid] + sda[192+tid];
      adst[grow] = sdd[tid] + sdd[64+tid] + sdd[128+tid] + sdd[192+tid];
    }
  }
}

// ---------------- GAT ----------------
__global__ __launch_bounds__(256) void k_gat(const float* __restrict__ h_, const float* __restrict__ asrc_,
     const float* __restrict__ adst_, const int* __restrict__ rowptr_, const int* __restrict__ adj_,
     const float* __restrict__ biasA, const float* __restrict__ biasB, float* __restrict__ out_){
  int br = blockIdx.y;
  const float* h = h_ + (size_t)br*NN*HH;
  const float* asrc = asrc_ + (size_t)br*NN;
  const float* adst = adst_ + (size_t)br*NN;
  const int* rowptr = rowptr_ + (size_t)br*RPN;
  const int* adj = adj_ + (size_t)br*NE;
  const float* bias = br ? biasB : biasA;
  float* out = out_ + (size_t)br*NN*HH;

  int node = blockIdx.x*4 + (threadIdx.x>>6);
  int lane = threadIdx.x & 63;
  int rs = rowptr[node], re = rowptr[node+1];
  int deg = re - rs;
  float adsti = adst[node];
  float eself = leaky02(asrc[node] + adsti);
  int c0 = lane*4;
  float4 acc;
  float4 bv = *((const float4*)&bias[c0]);
  if (deg <= 64){
    bool act = lane < deg;
    int sv = 0; float asv = 0.f;
    if (act){ sv = adj[rs + lane]; asv = asrc[sv]; }
    float e_l = act ? leaky02(asv + adsti) : -INFINITY;
    float m = fmaxf(eself, wredmax(e_l));
    float ex = act ? expf(e_l - m) : 0.f;
    float es = expf(eself - m);
    float denom = wredsum(ex) + es + 1e-16f;
    float aself = es/denom;
    float av = ex/denom;
    float4 hv = *((const float4*)&h[(size_t)node*HH + c0]);
    acc = make_float4(hv.x*aself, hv.y*aself, hv.z*aself, hv.w*aself);
    for (int jj=0; jj<deg; jj++){
      int sb = __shfl(sv, jj, 64);
      float ab = __shfl(av, jj, 64);
      float4 q = *((const float4*)&h[(size_t)sb*HH + c0]);
      acc.x = fmaxf(acc.x, q.x*ab); acc.y = fmaxf(acc.y, q.y*ab);
      acc.z = fmaxf(acc.z, q.z*ab); acc.w = fmaxf(acc.w, q.w*ab);
    }
  } else {
    float m = eself;
    for (int j = rs + lane; j < re; j += 64) m = fmaxf(m, leaky02(asrc[adj[j]] + adsti));
    m = wredmax(m);
    float ssum = 0.f;
    for (int j = rs + lane; j < re; j += 64) ssum += expf(leaky02(asrc[adj[j]] + adsti) - m);
    ssum = wredsum(ssum) + expf(eself - m);
    float denom = ssum + 1e-16f;
    float aself = expf(eself - m)/denom;
    float4 hv = *((const float4*)&h[(size_t)node*HH + c0]);
    acc = make_float4(hv.x*aself, hv.y*aself, hv.z*aself, hv.w*aself);
    for (int jb = rs; jb < re; jb += 64){
      int cnt = min(64, re - jb);
      int sv = 0; float av = 0.f;
      if (lane < cnt){ sv = adj[jb+lane]; av = expf(leaky02(asrc[sv] + adsti) - m)/denom; }
      for (int jj=0; jj<cnt; jj++){
        int sb = __shfl(sv, jj, 64);
        float ab = __shfl(av, jj, 64);
        float4 q = *((const float4*)&h[(size_t)sb*HH + c0]);
        acc.x = fmaxf(acc.x, q.x*ab); acc.y = fmaxf(acc.y, q.y*ab);
        acc.z = fmaxf(acc.z, q.z*ab); acc.w = fmaxf(acc.w, q.w*ab);
      }
    }
  }
  acc.x += bv.x; acc.y += bv.y; acc.z += bv.z; acc.w += bv.w;
  *((float4*)&out[(size_t)node*HH + c0]) = acc;
}

// ---------------- BatchNorm ----------------
__global__ __launch_bounds__(256) void k_bnstats(const float* __restrict__ x_, float* __restrict__ sums_){
  int br = blockIdx.y;
  const float* x = x_ + (size_t)br*NN*HH;
  float* s_ = sums_ + (size_t)br*2*HH;
  float* q_ = s_ + HH;
  int c = threadIdx.x;
  float s = 0.f, q = 0.f;
  for (int r = blockIdx.x; r < NN; r += gridDim.x){
    float v = x[(size_t)r*HH + c];
    s += v; q += v*v;
  }
  atomicAdd(&s_[c], s);
  atomicAdd(&q_[c], q);
}

__global__ __launch_bounds__(256) void k_bnfin(const float* __restrict__ sums_,
    const float* __restrict__ gA, const float* __restrict__ gB,
    const float* __restrict__ bA, const float* __restrict__ bB,
    float* __restrict__ scale_, float* __restrict__ shift_){
  int br = blockIdx.y;
  const float* sums = sums_ + (size_t)br*2*HH;
  const float* sumsq = sums + HH;
  const float* g = br ? gB : gA;
  const float* b = br ? bB : bA;
  float* scale = scale_ + (size_t)br*HH;
  float* shift = shift_ + (size_t)br*HH;
  int c = threadIdx.x;
  float mean = sums[c]/(float)NN;
  float var = sumsq[c]/(float)NN - mean*mean;
  float rstd = rsqrtf(var + 1e-5f);
  float sc = g[c]*rstd;
  scale[c] = sc; shift[c] = b[c] - mean*sc;
}

// ---------------- SAGE max-aggregate ----------------
__global__ __launch_bounds__(256) void k_sageagg(const float* __restrict__ xin_, const float* __restrict__ scale_,
    const float* __restrict__ shift_, const float* __restrict__ pA, const float* __restrict__ pB,
    const int* __restrict__ rowptr_, const int* __restrict__ adj_, float* __restrict__ agg_){
  int br = blockIdx.y;
  const float* xin = xin_ + (size_t)br*NN*HH;
  const float* scale = scale_ + (size_t)br*HH;
  const float* shift = shift_ + (size_t)br*HH;
  const float* prelu = br ? pB : pA;
  const int* rowptr = rowptr_ + (size_t)br*RPN;
  const int* adj = adj_ + (size_t)br*NE;
  float* agg = agg_ + (size_t)br*NN*HH;

  int node = blockIdx.x*4 + (threadIdx.x>>6);
  int lane = threadIdx.x & 63;
  int rs = rowptr[node], re = rowptr[node+1];
  int c0 = lane*4;
  float slope = prelu[0];
  float4 sc = *((const float4*)&scale[c0]);
  float4 sh = *((const float4*)&shift[c0]);
  float4 acc = make_float4(-INFINITY,-INFINITY,-INFINITY,-INFINITY);
  for (int jb = rs; jb < re; jb += 64){
    int cnt = min(64, re - jb);
    int sv = (lane < cnt) ? adj[jb+lane] : 0;
    for (int jj=0; jj<cnt; jj++){
      int sb = __shfl(sv, jj, 64);
      float4 q = *((const float4*)&xin[(size_t)sb*HH + c0]);
      q = bnprelu4(q, sc, sh, slope);
      acc.x = fmaxf(acc.x, q.x); acc.y = fmaxf(acc.y, q.y);
      acc.z = fmaxf(acc.z, q.z); acc.w = fmaxf(acc.w, q.w);
    }
  }
  if (re == rs) acc = make_float4(0.f,0.f,0.f,0.f);
  *((float4*)&agg[(size_t)node*HH + c0]) = acc;
}

// ---------------- GEMM2 (r14): M=128 x N=256 per block, 512 thr / 8 waves ----------------
// Wave tile 128x32 (acc[8][2]); B chunk read once per 128 rows -> L2 B-traffic
// halved vs M=64. Same verified 2-deep A pipeline + softBarrier schedule.
__global__ __launch_bounds__(512, 3) void k_gemm2(const float* __restrict__ graw_, const float* __restrict__ agg_,
    const u16* __restrict__ WtT_,
    const float* __restrict__ scale1_, const float* __restrict__ shift1_,
    const float* __restrict__ p1A, const float* __restrict__ p1B,
    const float* __restrict__ blA, const float* __restrict__ blB,
    float* __restrict__ out_, float* __restrict__ sums_){
  int br = blockIdx.y;
  const float* graw = graw_ + (size_t)br*NN*HH;
  const float* agg = agg_ + (size_t)br*NN*HH;
  const u16* WtT = WtT_ + (size_t)br*16*16384;
  const float* scale1 = scale1_ + (size_t)br*HH;
  const float* shift1 = shift1_ + (size_t)br*HH;
  const float* prelu1 = br ? p1B : p1A;
  const float* bl = br ? blB : blA;
  float* out = out_ + (size_t)br*NN*HH;
  float* sums = sums_ + (size_t)br*2*HH;
  float* sumsq = sums + HH;

  __shared__ u16 As[2][8*ASTRIDE2];
  int tid = threadIdx.x;
  int row0 = blockIdx.x*128;
  int wave = tid>>6, lane = tid&63;
  int l15 = lane&15, quad = lane>>4;
  int col0 = wave*32;
  int sm_ = tid >> 2, sg = tid & 3;   // 4 threads per row, 8 floats each (128 rows)
  int sgrow = row0 + sm_; if (sgrow >= NN) sgrow = NN-1;
  float slope = prelu1[0];
  f32x4 acc[8][2];
  #pragma unroll
  for (int mt=0;mt<8;mt++)
    #pragma unroll
    for (int nt=0;nt<2;nt++){ f32x4 z = {0.f,0.f,0.f,0.f}; acc[mt][nt] = z; }

  const u16* bbase = WtT + ((size_t)quad<<12) + (size_t)(col0 + l15)*8;
  bf16x8 B0h[2],B0l[2],B1h[2],B1l[2];
  float4 vaA0, vaA1, vaB0, vaB1;

  auto loadA = [&](int kc, float4& d0, float4& d1){
    const float* ab = (kc < HH) ? graw : agg;
    int ac = (kc < HH) ? kc : kc - HH;
    d0 = *((const float4*)(ab + (size_t)sgrow*HH + ac + sg*8));
    d1 = *((const float4*)(ab + (size_t)sgrow*HH + ac + sg*8 + 4));
  };
  auto writeA = [&](int kc, int wb, float4 v0, float4 v1){
    if (kc < HH){
      int kcol = kc + sg*8;
      v0 = bnprelu4(v0, *((const float4*)(scale1+kcol)),   *((const float4*)(shift1+kcol)),   slope);
      v1 = bnprelu4(v1, *((const float4*)(scale1+kcol+4)), *((const float4*)(shift1+kcol+4)), slope);
    }
    bf16x8 h, l;
    split8(v0, v1, h, l);
    *((bf16x8*)&As[wb][sg*ASTRIDE2 + sm_*8]) = h;
    *((bf16x8*)&As[wb][(4+sg)*ASTRIDE2 + sm_*8]) = l;
  };
  auto loadB = [&](int ck, bf16x8 (&Bh)[2], bf16x8 (&Bl)[2]){
    const u16* bb = bbase + ((size_t)ck<<14);
    #pragma unroll
    for (int nt=0;nt<2;nt++){
      Bh[nt] = *((const bf16x8*)(bb + nt*128));
      Bl[nt] = *((const bf16x8*)(bb + 2048 + nt*128));
    }
  };
  auto body = [&](int k, int rb, float4& vW0, float4& vW1, bf16x8 (&Bh)[2], bf16x8 (&Bl)[2], bf16x8 (&nBh)[2], bf16x8 (&nBl)[2]){
    softBarrier();
    if (k < 15) writeA((k+1)*32, rb^1, vW0, vW1);
    if (k < 13) loadA((k+3)*32, vW0, vW1);
    if (k < 15) loadB(k+1, nBh, nBl);
    #pragma unroll
    for (int mt=0;mt<8;mt++){
      int m = mt*16 + l15;
      bf16x8 ah = *((bf16x8*)&As[rb][quad*ASTRIDE2 + m*8]);
      bf16x8 al = *((bf16x8*)&As[rb][(4+quad)*ASTRIDE2 + m*8]);
      #pragma unroll
      for (int nt=0;nt<2;nt++){
        acc[mt][nt] = __builtin_amdgcn_mfma_f32_16x16x32_bf16(ah, Bh[nt], acc[mt][nt], 0, 0, 0);
        acc[mt][nt] = __builtin_amdgcn_mfma_f32_16x16x32_bf16(al, Bh[nt], acc[mt][nt], 0, 0, 0);
        acc[mt][nt] = __builtin_amdgcn_mfma_f32_16x16x32_bf16(ah, Bl[nt], acc[mt][nt], 0, 0, 0);
      }
    }
  };

  loadA(0, vaA0, vaA1);
  writeA(0, 0, vaA0, vaA1);
  loadA(32, vaA0, vaA1);
  loadA(64, vaB0, vaB1);
  loadB(0, B0h, B0l);
  #pragma unroll 1
  for (int k=0; k<16; k+=2){
    body(k,   0, vaA0, vaA1, B0h,B0l, B1h,B1l);
    body(k+1, 1, vaB0, vaB1, B1h,B1l, B0h,B0l);
  }

  // epilogue: bias, store, BN2 partial stats
  float psum[2], psq[2];
  #pragma unroll
  for (int nt=0;nt<2;nt++){
    int c = col0 + nt*16 + l15;
    float bcol = bl[c];
    float s=0.f, q=0.f;
    #pragma unroll
    for (int mt=0;mt<8;mt++){
      int gbase = row0 + mt*16 + quad*4;
      #pragma unroll
      for (int r=0;r<4;r++){
        int grow = gbase + r;
        float v = acc[mt][nt][r] + bcol;
        if (grow < NN){
          out[(size_t)grow*HH + c] = v;
          s += v; q += v*v;
        }
      }
    }
    psum[nt]=s; psq[nt]=q;
  }
  __syncthreads();
  float* sm2 = (float*)As;
  sm2[tid] = 0.f;
  __syncthreads();
  #pragma unroll
  for (int nt=0;nt<2;nt++){
    int c = col0 + nt*16 + l15;
    atomicAdd(&sm2[c], psum[nt]);
    atomicAdd(&sm2[256+c], psq[nt]);
  }
  __syncthreads();
  if (tid < 256){
    atomicAdd(&sums[tid],  sm2[tid]);
    atomicAdd(&sumsq[tid], sm2[256+tid]);
  }
}

// ---------------- pool GEMVs ----------------
__global__ __launch_bounds__(256) void k_gemv2(const float* __restrict__ x2_, const float* __restrict__ scale2_,
    const float* __restrict__ shift2_, const float* __restrict__ p2A, const float* __restrict__ p2B,
    const float* __restrict__ WrelA, const float* __restrict__ WrelB,
    const float* __restrict__ WrootA, const float* __restrict__ WrootB,
    float* __restrict__ y2_, float* __restrict__ y2r_){
  int br = blockIdx.y;
  const float* x2raw = x2_ + (size_t)br*NN*HH;
  const float* scale2 = scale2_ + (size_t)br*HH;
  const float* shift2 = shift2_ + (size_t)br*HH;
  const float* prelu2 = br ? p2B : p2A;
  const float* Wrel = br ? WrelB : WrelA;
  const float* Wroot = br ? WrootB : WrootA;
  float* y2 = y2_ + (size_t)br*NN;
  float* y2r = y2r_ + (size_t)br*NN;

  int node = blockIdx.x*4 + (threadIdx.x>>6);
  int lane = threadIdx.x & 63;
  int c0 = lane*4;
  float slope = prelu2[0];
  float4 v = *((const float4*)&x2raw[(size_t)node*HH + c0]);
  float4 sc = *((const float4*)&scale2[c0]);
  float4 sh = *((const float4*)&shift2[c0]);
  v = bnprelu4(v, sc, sh, slope);
  float4 wr = *((const float4*)&Wrel[c0]);
  float4 wo = *((const float4*)&Wroot[c0]);
  float pr = v.x*wr.x + v.y*wr.y + v.z*wr.z + v.w*wr.w;
  float po = v.x*wo.x + v.y*wo.y + v.z*wo.z + v.w*wo.w;
  pr = wredsum(pr); po = wredsum(po);
  if (lane==0){ y2[node] = pr; y2r[node] = po; }
}

// k_score with fused hist1 (r14)
__global__ void k_score(const int* __restrict__ rowptr_, const int* __restrict__ adj_, const float* __restrict__ y2_,
    const float* __restrict__ y2r_, const float* __restrict__ brelA, const float* __restrict__ brelB,
    float* __restrict__ score_, unsigned* __restrict__ keys_, unsigned* __restrict__ hist_){
  int br = blockIdx.y;
  const int* rowptr = rowptr_ + (size_t)br*RPN;
  const int* adj = adj_ + (size_t)br*NE;
  const float* y2 = y2_ + (size_t)br*NN;
  const float* y2r = y2r_ + (size_t)br*NN;
  const float* brel = br ? brelB : brelA;
  float* score = score_ + (size_t)br*NN;
  unsigned* keys = keys_ + (size_t)br*NN;
  unsigned* hist = hist_ + (size_t)br*65536;

  int i = blockIdx.x*blockDim.x + threadIdx.x;
  if (i >= NN) return;
  float s = 0.f;
  int rs = rowptr[i], re = rowptr[i+1];
  for (int j=rs;j<re;j++) s += y2[adj[j]];
  float sc = s + brel[0] + y2r[i];
  score[i] = sc;
  unsigned u = __float_as_uint(sc);
  u = (u & 0x80000000u) ? ~u : (u | 0x80000000u);
  keys[i] = u;
  atomicAdd(&hist[u>>16], 1u);
}

// parallel suffix-scan findbin: uint4 coarse sums + log-step scans
__global__ __launch_bounds__(256) void k_findbin1(const unsigned* __restrict__ hist_, unsigned* __restrict__ scal_){
  int br = blockIdx.y;
  const unsigned* hist = hist_ + (size_t)br*65536;
  unsigned* scal = scal_ + (size_t)br*16;
  __shared__ unsigned suf[256];
  __shared__ unsigned shc[2];
  int t = threadIdx.x;
  const uint4* h4 = (const uint4*)(hist + t*256);
  unsigned s = 0;
  #pragma unroll 8
  for (int b=0;b<64;b++){ uint4 v = h4[b]; s += v.x+v.y+v.z+v.w; }
  suf[t] = s; __syncthreads();
  #pragma unroll
  for (int o=1;o<256;o<<=1){
    unsigned add = (t+o<256)? suf[t+o] : 0u;
    __syncthreads();
    suf[t] += add;
    __syncthreads();
  }
  unsigned ab = suf[t] - s;
  if (ab < (unsigned)KT && ab + s >= (unsigned)KT){ shc[0] = (unsigned)t; shc[1] = ab; }
  __syncthreads();
  int cb = (int)shc[0]; unsigned runbase = shc[1];
  unsigned f = hist[cb*256 + t];
  suf[t] = f; __syncthreads();
  #pragma unroll
  for (int o=1;o<256;o<<=1){
    unsigned add = (t+o<256)? suf[t+o] : 0u;
    __syncthreads();
    suf[t] += add;
    __syncthreads();
  }
  unsigned ta = runbase + suf[t] - f;
  if (ta < (unsigned)KT && ta + f >= (unsigned)KT){
    scal[0] = (unsigned)(cb*256 + t);
    scal[1] = ta;
  }
}

__global__ void k_hist2(const unsigned* __restrict__ keys_, const unsigned* __restrict__ scal_, unsigned* __restrict__ hist_){
  int br = blockIdx.y;
  const unsigned* keys = keys_ + (size_t)br*NN;
  const unsigned* scal = scal_ + (size_t)br*16;
  unsigned* hist = hist_ + (size_t)br*65536;
  int i = blockIdx.x*blockDim.x + threadIdx.x;
  if (i < NN){ unsigned k = keys[i]; if ((k>>16) == scal[0]) atomicAdd(&hist[k & 0xFFFFu], 1u); }
}

__global__ __launch_bounds__(256) void k_findbin2(const unsigned* __restrict__ hist_, unsigned* __restrict__ scal_){
  int br = blockIdx.y;
  const unsigned* hist = hist_ + (size_t)br*65536;
  unsigned* scal = scal_ + (size_t)br*16;
  __shared__ unsigned suf[256];
  __shared__ unsigned shc[2];
  int t = threadIdx.x;
  unsigned target = (unsigned)KT - scal[1];
  const uint4* h4 = (const uint4*)(hist + t*256);
  unsigned s = 0;
  #pragma unroll 8
  for (int b=0;b<64;b++){ uint4 v = h4[b]; s += v.x+v.y+v.z+v.w; }
  suf[t] = s; __syncthreads();
  #pragma unroll
  for (int o=1;o<256;o<<=1){
    unsigned add = (t+o<256)? suf[t+o] : 0u;
    __syncthreads();
    suf[t] += add;
    __syncthreads();
  }
  unsigned ab = suf[t] - s;
  if (ab < target && ab + s >= target){ shc[0] = (unsigned)t; shc[1] = ab; }
  __syncthreads();
  int cb = (int)shc[0]; unsigned runbase = shc[1];
  unsigned f = hist[cb*256 + t];
  suf[t] = f; __syncthreads();
  #pragma unroll
  for (int o=1;o<256;o<<=1){
    unsigned add = (t+o<256)? suf[t+o] : 0u;
    __syncthreads();
    suf[t] += add;
    __syncthreads();
  }
  unsigned ta = runbase + suf[t] - f;
  if (ta < target && ta + f >= target){
    scal[2] = (scal[0] << 16) | (unsigned)(cb*256 + t);
    scal[3] = target - ta;
    scal[4] = f;
  }
}

__global__ void k_select(const unsigned* __restrict__ keys_, const float* __restrict__ score_,
    unsigned* __restrict__ scal_, int* __restrict__ selidx_, float* __restrict__ tvals_){
  int br = blockIdx.y;
  const unsigned* keys = keys_ + (size_t)br*NN;
  const float* score = score_ + (size_t)br*NN;
  unsigned* scal = scal_ + (size_t)br*16;
  int* selidx = selidx_ + (size_t)br*NN;
  float* tvals = tvals_ + (size_t)br*NN;

  int i = blockIdx.x*blockDim.x + threadIdx.x;
  if (i >= NN) return;
  unsigned T = scal[2], needed = scal[3], cnteq = scal[4];
  unsigned k = keys[i];
  int s = 0;
  if (k > T) s = 1;
  else if (k == T){
    if (cnteq <= needed) s = 1;
    else {
      unsigned rank = 0;
      for (int j=0;j<i;j++) rank += (keys[j] == T) ? 1u : 0u;
      s = (rank < needed) ? 1 : 0;
    }
  }
  if (s){
    unsigned idx = atomicAdd(&scal[8], 1u);
    selidx[idx] = i;
    tvals[idx] = tanhf(score[i]);
  }
}

__global__ __launch_bounds__(256) void k_embed(const float* __restrict__ x2_, const float* __restrict__ scale2_,
    const float* __restrict__ shift2_, const float* __restrict__ p2A, const float* __restrict__ p2B,
    const int* __restrict__ selidx_, const float* __restrict__ tvals_, float* __restrict__ embed){
  int br = blockIdx.y;
  const float* x2raw = x2_ + (size_t)br*NN*HH;
  const float* scale2 = scale2_ + (size_t)br*HH;
  const float* shift2 = shift2_ + (size_t)br*HH;
  const float* prelu2 = br ? p2B : p2A;
  const int* selidx = selidx_ + (size_t)br*NN;
  const float* tvals = tvals_ + (size_t)br*NN;

  int c = threadIdx.x;
  float slope = prelu2[0];
  float scv = scale2[c], shv = shift2[c];
  float best = -INFINITY;
  for (int j = blockIdx.x; j < KT; j += gridDim.x){
    int r = selidx[j];
    float v = x2raw[(size_t)r*HH + c]*scv + shv;
    v = preluf(v, slope);
    best = fmaxf(best, v*tvals[j]);
  }
  atomicMaxF(&embed[(size_t)br*HH + c], best);
}

__global__ void k_initembed(float* __restrict__ embed){
  int i = threadIdx.x;
  if (i < 2*HH) embed[i] = -INFINITY;
}

// ---------------- head ----------------
__global__ __launch_bounds__(256) void k_head(const float* __restrict__ embed, const float* __restrict__ addf,
    const float* __restrict__ fc1W, const float* __restrict__ fc1b, const float* __restrict__ preluh,
    const float* __restrict__ fc2W, const float* __restrict__ fc2b, float* __restrict__ out){
  __shared__ float z[2*HH + 8];
  __shared__ float h1s[HH];
  __shared__ float red[4];
  int t = threadIdx.x;
  for (int i=t;i<2*HH;i+=256) z[i] = embed[i];
  if (t < 8) z[2*HH + t] = addf[t];
  __syncthreads();
  float acc = fc1b[t];
  for (int k=0;k<2*HH+8;k++) acc += z[k]*fc1W[(size_t)k*HH + t];
  float slope = preluh[0];
  h1s[t] = preluf(acc, slope);
  __syncthreads();
  float p = h1s[t]*fc2W[t];
  p = wredsum(p);
  if ((t & 63) == 0) red[t>>6] = p;
  __syncthreads();
  if (t == 0) out[0] = expf(red[0]+red[1]+red[2]+red[3] + fc2b[0]);
}

// ---------------- orchestration ----------------
extern "C" void kernel_launch(void* const* d_in, const int* in_sizes, int n_in,
                              void* d_out, int out_size, void* d_ws, size_t ws_size,
                              hipStream_t stream) {
  (void)in_sizes; (void)n_in; (void)out_size;
  char* ws = (char*)d_ws;

  float *bufA, *bufB, *asrc, *adst, *sums, *scale1, *shift1, *scale2, *shift2;
  float *y2, *y2r, *score, *tvals, *embed;
  int *rowptr, *adj, *cursor, *bsums, *selidx;
  unsigned *keys, *hist1, *hist2, *scal;
  u16 *WtT, *WtT1;

  auto doAlloc = [&](int nb)->size_t{
    size_t o = 0;
    auto al = [&](size_t bytes)->char*{ char* p = ws + o; o = (o + bytes + 255) & ~(size_t)255; return p; };
    bufA   = (float*)al((size_t)nb*NN*HH*4);
    bufB   = (float*)al((size_t)nb*NN*HH*4);
    asrc   = (float*)al((size_t)nb*NN*4);
    adst   = (float*)al((size_t)nb*NN*4);
    rowptr = (int*)  al((size_t)nb*RPN*4);
    adj    = (int*)  al((size_t)nb*NE*4);
    cursor = (int*)  al((size_t)nb*NN*4);
    bsums  = (int*)  al((size_t)nb*128*4);
    sums   = (float*)al((size_t)nb*2*HH*4);
    scale1 = (float*)al((size_t)nb*HH*4);
    shift1 = (float*)al((size_t)nb*HH*4);
    scale2 = (float*)al((size_t)nb*HH*4);
    shift2 = (float*)al((size_t)nb*HH*4);
    y2     = (float*)al((size_t)nb*NN*4);
    y2r    = (float*)al((size_t)nb*NN*4);
    score  = (float*)al((size_t)nb*NN*4);
    keys   = (unsigned*)al((size_t)nb*NN*4);
    selidx = (int*)  al((size_t)nb*NN*4);
    tvals  = (float*)al((size_t)nb*NN*4);
    hist1  = (unsigned*)al((size_t)nb*65536*4);
    hist2  = (unsigned*)al((size_t)nb*65536*4);
    scal   = (unsigned*)al((size_t)nb*64);
    embed  = (float*)al((size_t)2*HH*4);
    WtT    = (u16*)al((size_t)nb*16*16384*2);
    WtT1   = (u16*)al((size_t)nb*2*16384*2);
    return o;
  };

  int NB = 2;
  if (doAlloc(2) > ws_size) NB = 1;
  doAlloc(NB);

  const float* addf = (const float*)d_in[2];

  k_initembed<<<dim3(1), dim3(512), 0, stream>>>(embed);

  int nIter = (NB==2) ? 1 : 2;
  for (int it = 0; it < nIter; ++it){
    const float *xA, *xB; const int *eiA, *eiB; int pa, pb;
    if (NB == 2){
      xA = (const float*)d_in[0]; xB = (const float*)d_in[1];
      eiA = (const int*)d_in[3]; eiB = (const int*)d_in[4];
      pa = 5; pb = 21;
    } else {
      xA = xB = (const float*)d_in[it];
      eiA = eiB = (const int*)d_in[3+it];
      pa = pb = (it==0) ? 5 : 21;
    }
    auto PA = [&](int i){ return (const float*)d_in[pa+i]; };
    auto PB = [&](int i){ return (const float*)d_in[pb+i]; };

    // CSR by dst (both branches)
    hipMemsetAsync(cursor, 0, (size_t)NB*NN*4, stream);
    k_count<<<dim3((NE+255)/256, NB), dim3(256), 0, stream>>>(eiA, eiB, cursor);
    k_scan1<<<dim3(98, NB), dim3(1024), 0, stream>>>(cursor, rowptr, bsums);
    k_scan2<<<dim3(1, NB), dim3(128), 0, stream>>>(bsums, 98);
    k_scan3<<<dim3(98, NB), dim3(1024), 0, stream>>>(rowptr, bsums, cursor);
    k_scatter<<<dim3((NE+255)/256, NB), dim3(256), 0, stream>>>(eiA, eiB, cursor, adj);

    // W pre-splits (merged)
    k_splitWall<<<dim3(576, NB), dim3(256), 0, stream>>>(PA(9), PB(9), PA(7), PB(7), PA(0), PB(0), WtT, WtT1);

    // GAT
    k_gemm1<<<dim3((NN+63)/64, NB), dim3(256), 0, stream>>>(xA, xB, WtT1,
        PA(1), PB(1), PA(2), PB(2), bufA, asrc, adst);
    k_gat<<<dim3(25000, NB), dim3(256), 0, stream>>>(bufA, asrc, adst, rowptr, adj, PA(3), PB(3), bufB);

    // BN1
    hipMemsetAsync(sums, 0, (size_t)NB*2*HH*4, stream);
    k_bnstats<<<dim3(512, NB), dim3(256), 0, stream>>>(bufB, sums);
    k_bnfin<<<dim3(1, NB), dim3(256), 0, stream>>>(sums, PA(4), PB(4), PA(5), PB(5), scale1, shift1);

    // SAGE
    k_sageagg<<<dim3(25000, NB), dim3(256), 0, stream>>>(bufB, scale1, shift1, PA(6), PB(6), rowptr, adj, bufA);
    hipMemsetAsync(sums, 0, (size_t)NB*2*HH*4, stream);
    k_gemm2<<<dim3((NN+127)/128, NB), dim3(512), 0, stream>>>(bufB, bufA, WtT,
        scale1, shift1, PA(6), PB(6), PA(8), PB(8), bufB, sums);
    k_bnfin<<<dim3(1, NB), dim3(256), 0, stream>>>(sums, PA(10), PB(10), PA(11), PB(11), scale2, shift2);

    // SAGPool (hist1 memset moved BEFORE score; hist1 fused into k_score)
    hipMemsetAsync(scal, 0, (size_t)NB*64, stream);
    hipMemsetAsync(hist1, 0, (size_t)NB*65536*4, stream);
    hipMemsetAsync(hist2, 0, (size_t)NB*65536*4, stream);
    k_gemv2<<<dim3(25000, NB), dim3(256), 0, stream>>>(bufB, scale2, shift2, PA(12), PB(12),
        PA(13), PB(13), PA(15), PB(15), y2, y2r);
    k_score<<<dim3((NN+255)/256, NB), dim3(256), 0, stream>>>(rowptr, adj, y2, y2r, PA(14), PB(14), score, keys, hist1);
    k_findbin1<<<dim3(1, NB), dim3(256), 0, stream>>>(hist1, scal);
    k_hist2<<<dim3((NN+255)/256, NB), dim3(256), 0, stream>>>(keys, scal, hist2);
    k_findbin2<<<dim3(1, NB), dim3(256), 0, stream>>>(hist2, scal);
    k_select<<<dim3((NN+255)/256, NB), dim3(256), 0, stream>>>(keys, score, scal, selidx, tvals);
    float* embDst = (NB==2) ? embed : (embed + it*HH);
    k_embed<<<dim3(256, NB), dim3(256), 0, stream>>>(bufB, scale2, shift2, PA(12), PB(12), selidx, tvals, embDst);
  }

  k_head<<<dim3(1), dim3(256), 0, stream>>>(embed, addf,
      (const float*)d_in[37], (const float*)d_in[38], (const float*)d_in[39],
      (const float*)d_in[40], (const float*)d_in[41], (float*)d_out);
}

// Round 6
// 1486.711 us; speedup vs baseline: 1.0218x; 1.0218x over previous
//
#include <hip/hip_runtime.h>
#include <math.h>

#define NN 100000
#define NE 400000
#define FI 64
#define HH 256
#define KT 50000
#define RPN (NN+1)

typedef unsigned short u16;
typedef __attribute__((ext_vector_type(8))) short bf16x8;
typedef __attribute__((ext_vector_type(4))) short bf16x4;
typedef __attribute__((ext_vector_type(4))) float f32x4;

__device__ __forceinline__ float leaky02(float x){ return x >= 0.f ? x : 0.2f*x; }
__device__ __forceinline__ float preluf(float x, float a){ return x >= 0.f ? x : a*x; }

__device__ __forceinline__ float wredmax(float v){
  #pragma unroll
  for (int o=32;o>0;o>>=1) v = fmaxf(v, __shfl_xor(v, o, 64));
  return v;
}
__device__ __forceinline__ float wredsum(float v){
  #pragma unroll
  for (int o=32;o>0;o>>=1) v += __shfl_xor(v, o, 64);
  return v;
}
__device__ __forceinline__ float qredsum(float v){
  #pragma unroll
  for (int o=8;o>0;o>>=1) v += __shfl_xor(v, o, 64);
  return v;
}

// barrier that does NOT drain vmcnt (keeps prefetch loads in flight)
__device__ __forceinline__ void softBarrier(){
  asm volatile("s_waitcnt lgkmcnt(0)" ::: "memory");
  __builtin_amdgcn_s_barrier();
}

__device__ __forceinline__ void atomicMaxF(float* a, float v){
  if (v >= 0.f) atomicMax((int*)a, __float_as_int(v));
  else atomicMin((unsigned int*)a, __float_as_uint(v));
}

__device__ __forceinline__ float4 bnprelu4(float4 v, float4 sc, float4 sh, float a){
  float4 r;
  r.x = preluf(v.x*sc.x+sh.x, a);
  r.y = preluf(v.y*sc.y+sh.y, a);
  r.z = preluf(v.z*sc.z+sh.z, a);
  r.w = preluf(v.w*sc.w+sh.w, a);
  return r;
}

__device__ __forceinline__ float4 fmax4(float4 a, float4 b){
  return make_float4(fmaxf(a.x,b.x), fmaxf(a.y,b.y), fmaxf(a.z,b.z), fmaxf(a.w,b.w));
}

__device__ __forceinline__ u16 f2bf(float f){
  unsigned u = __float_as_uint(f);
  unsigned r = u + 0x7FFFu + ((u>>16)&1u);
  return (u16)(r>>16);
}
__device__ __forceinline__ float bf2f(u16 h){
  return __uint_as_float(((unsigned)h)<<16);
}
__device__ __forceinline__ void split8(float4 a, float4 b, bf16x8& h, bf16x8& l){
  float va[8] = {a.x,a.y,a.z,a.w,b.x,b.y,b.z,b.w};
  #pragma unroll
  for (int j=0;j<8;j++){
    u16 hh = f2bf(va[j]);
    h[j] = (short)hh;
    l[j] = (short)f2bf(va[j] - bf2f(hh));
  }
}
__device__ __forceinline__ void split4(float4 a, bf16x4& h, bf16x4& l){
  float va[4] = {a.x,a.y,a.z,a.w};
  #pragma unroll
  for (int j=0;j<4;j++){
    u16 hh = f2bf(va[j]);
    h[j] = (short)hh;
    l[j] = (short)f2bf(va[j] - bf2f(hh));
  }
}

// ---------------- CSR build (batched over blockIdx.y) ----------------
__global__ void k_count(const int* __restrict__ eiA, const int* __restrict__ eiB, int* __restrict__ deg_){
  int br = blockIdx.y;
  const int* dst = (br ? eiB : eiA) + NE;
  int* deg = deg_ + (size_t)br*NN;
  int e = blockIdx.x*blockDim.x + threadIdx.x;
  if (e < NE) atomicAdd(&deg[dst[e]], 1);
}

__global__ __launch_bounds__(1024) void k_scan1(const int* __restrict__ deg_, int* __restrict__ rowptr_, int* __restrict__ bsums_){
  int br = blockIdx.y;
  const int* deg = deg_ + (size_t)br*NN;
  int* rowptr = rowptr_ + (size_t)br*RPN;
  int* bsums = bsums_ + (size_t)br*128;
  __shared__ int sm[1024];
  int t = threadIdx.x; int g = blockIdx.x*1024 + t;
  int v = (g < NN) ? deg[g] : 0;
  sm[t] = v; __syncthreads();
  for (int o=1;o<1024;o<<=1){
    int add = (t>=o)? sm[t-o] : 0;
    __syncthreads();
    sm[t] += add;
    __syncthreads();
  }
  if (g < NN) rowptr[g] = sm[t] - v;
  if (t == 1023) bsums[blockIdx.x] = sm[1023];
}

__global__ __launch_bounds__(128) void k_scan2(int* __restrict__ bsums_, int nblk){
  int br = blockIdx.y;
  int* bsums = bsums_ + (size_t)br*128;
  __shared__ int sm[128];
  int t = threadIdx.x;
  int v = (t < nblk) ? bsums[t] : 0;
  sm[t] = v; __syncthreads();
  for (int o=1;o<128;o<<=1){
    int add = (t>=o)? sm[t-o] : 0;
    __syncthreads();
    sm[t] += add;
    __syncthreads();
  }
  if (t < nblk) bsums[t] = sm[t] - v;
}

__global__ __launch_bounds__(1024) void k_scan3(int* __restrict__ rowptr_, const int* __restrict__ bsums_, int* __restrict__ cursor_){
  int br = blockIdx.y;
  int* rowptr = rowptr_ + (size_t)br*RPN;
  const int* bsums = bsums_ + (size_t)br*128;
  int* cursor = cursor_ + (size_t)br*NN;
  int g = blockIdx.x*1024 + threadIdx.x;
  if (g < NN){ int r = rowptr[g] + bsums[blockIdx.x]; rowptr[g] = r; cursor[g] = r; }
  if (blockIdx.x==0 && threadIdx.x==0) rowptr[NN] = NE;
}

__global__ void k_scatter(const int* __restrict__ eiA, const int* __restrict__ eiB, int* __restrict__ cursor_, int* __restrict__ adj_){
  int br = blockIdx.y;
  const int* ei = br ? eiB : eiA;
  const int* src = ei;
  const int* dst = ei + NE;
  int* cursor = cursor_ + (size_t)br*NN;
  int* adj = adj_ + (size_t)br*NE;
  int e = blockIdx.x*blockDim.x + threadIdx.x;
  if (e < NE){ int d = dst[e]; int slot = atomicAdd(&cursor[d], 1); adj[slot] = src[e]; }
}

// ---------------- W pre-split (merged big + gat W) ----------------
__global__ __launch_bounds__(256) void k_splitWall(const float* __restrict__ WrA, const float* __restrict__ WrB,
    const float* __restrict__ WlA, const float* __restrict__ WlB,
    const float* __restrict__ WgA, const float* __restrict__ WgB,
    u16* __restrict__ WtT_, u16* __restrict__ WtT1_){
  int br = blockIdx.y;
  if (blockIdx.x < 512){
    const float* Wr = br ? WrB : WrA;
    const float* Wl = br ? WlB : WlA;
    u16* WtT = WtT_ + (size_t)br*16*16384;
    int idx = blockIdx.x*256 + threadIdx.x;
    int k = idx >> 8, n = idx & 255;
    float v = (k < HH) ? Wr[(size_t)k*HH + n] : Wl[(size_t)(k-HH)*HH + n];
    u16 hi = f2bf(v);
    float lo = v - bf2f(hi);
    size_t base = ((size_t)(k>>5))*16384 + (size_t)((k>>3)&3)*4096 + (size_t)n*8 + (k&7);
    WtT[base] = hi;
    WtT[base + 2048] = f2bf(lo);
  } else {
    const float* W = br ? WgB : WgA;
    u16* WtT = WtT1_ + (size_t)br*2*16384;
    int idx = (blockIdx.x-512)*256 + threadIdx.x;   // 64*256
    int k = idx >> 8, n = idx & 255;
    float v = W[(size_t)k*HH + n];
    u16 hi = f2bf(v);
    float lo = v - bf2f(hi);
    size_t base = ((size_t)(k>>5))*16384 + (size_t)((k>>3)&3)*4096 + (size_t)n*8 + (k&7);
    WtT[base] = hi;
    WtT[base + 2048] = f2bf(lo);
  }
}

#define ASTRIDE 528

// ---------------- GEMM1 ----------------
__global__ __launch_bounds__(256, 2) void k_gemm1(const float* __restrict__ xA, const float* __restrict__ xB,
    const u16* __restrict__ WtT_,
    const float* __restrict__ asA, const float* __restrict__ asB,
    const float* __restrict__ adA, const float* __restrict__ adB,
    float* __restrict__ out_, float* __restrict__ asrc_, float* __restrict__ adst_){
  int br = blockIdx.y;
  const float* x = br ? xB : xA;
  const u16* WtT = WtT_ + (size_t)br*2*16384;
  const float* a_src = br ? asB : asA;
  const float* a_dst = br ? adB : adA;
  float* out = out_ + (size_t)br*NN*HH;
  float* asrc = asrc_ + (size_t)br*NN;
  float* adst = adst_ + (size_t)br*NN;

  __shared__ u16 As[2][8*ASTRIDE];
  int tid = threadIdx.x;
  int row0 = blockIdx.x*64;
  int wave = tid>>6, lane = tid&63;
  int l15 = lane&15, quad = lane>>4;
  int col0 = wave*64;
  int sm_ = tid >> 2, sg = tid & 3;
  int sgrow = row0 + sm_; if (sgrow >= NN) sgrow = NN-1;
  f32x4 acc[4][4];
  #pragma unroll
  for (int mt=0;mt<4;mt++)
    #pragma unroll
    for (int nt=0;nt<4;nt++){ f32x4 z = {0.f,0.f,0.f,0.f}; acc[mt][nt] = z; }

  const u16* bbase = WtT + ((size_t)quad<<12) + (size_t)(col0 + l15)*8;
  bf16x8 B0h[4],B0l[4],B1h[4],B1l[4];
  float4 va0, va1;

  auto loadA = [&](int kc){
    va0 = *((const float4*)(x + (size_t)sgrow*FI + kc + sg*8));
    va1 = *((const float4*)(x + (size_t)sgrow*FI + kc + sg*8 + 4));
  };
  auto writeA = [&](int wb){
    bf16x8 h, l;
    split8(va0, va1, h, l);
    *((bf16x8*)&As[wb][sg*ASTRIDE + sm_*8]) = h;
    *((bf16x8*)&As[wb][(4+sg)*ASTRIDE + sm_*8]) = l;
  };
  auto loadB = [&](int ck, bf16x8 (&Bh)[4], bf16x8 (&Bl)[4]){
    const u16* bb = bbase + ((size_t)ck<<14);
    #pragma unroll
    for (int nt=0;nt<4;nt++){
      Bh[nt] = *((const bf16x8*)(bb + nt*128));
      Bl[nt] = *((const bf16x8*)(bb + 2048 + nt*128));
    }
  };
  auto mmacc = [&](int rb, bf16x8 (&Bh)[4], bf16x8 (&Bl)[4]){
    bf16x8 ah[4], al[4];
    #pragma unroll
    for (int mt=0;mt<4;mt++){
      int m = mt*16 + l15;
      ah[mt] = *((bf16x8*)&As[rb][quad*ASTRIDE + m*8]);
      al[mt] = *((bf16x8*)&As[rb][(4+quad)*ASTRIDE + m*8]);
    }
    #pragma unroll
    for (int nt=0;nt<4;nt++)
      #pragma unroll
      for (int mt=0;mt<4;mt++){
        acc[mt][nt] = __builtin_amdgcn_mfma_f32_16x16x32_bf16(ah[mt], Bh[nt], acc[mt][nt], 0, 0, 0);
        acc[mt][nt] = __builtin_amdgcn_mfma_f32_16x16x32_bf16(al[mt], Bh[nt], acc[mt][nt], 0, 0, 0);
        acc[mt][nt] = __builtin_amdgcn_mfma_f32_16x16x32_bf16(ah[mt], Bl[nt], acc[mt][nt], 0, 0, 0);
      }
  };

  loadA(0);
  writeA(0);
  loadA(32);
  loadB(0, B0h, B0l);
  softBarrier();
  writeA(1);
  loadB(1, B1h, B1l);
  mmacc(0, B0h, B0l);
  softBarrier();
  mmacc(1, B1h, B1l);

  float ps[4][4], pd[4][4];
  #pragma unroll
  for (int mt=0;mt<4;mt++)
    #pragma unroll
    for (int r=0;r<4;r++){ ps[mt][r]=0.f; pd[mt][r]=0.f; }
  #pragma unroll
  for (int nt=0;nt<4;nt++){
    int c = col0 + nt*16 + l15;
    float av = a_src[c], dv = a_dst[c];
    #pragma unroll
    for (int mt=0;mt<4;mt++){
      int gbase = row0 + mt*16 + quad*4;
      #pragma unroll
      for (int r=0;r<4;r++){
        int grow = gbase + r;
        float v = acc[mt][nt][r];
        if (grow < NN) out[(size_t)grow*HH + c] = v;
        ps[mt][r] += v*av; pd[mt][r] += v*dv;
      }
    }
  }
  __syncthreads();
  float* sda = (float*)As;
  float* sdd = sda + 256;
  #pragma unroll
  for (int mt=0;mt<4;mt++)
    #pragma unroll
    for (int r=0;r<4;r++){
      float s = qredsum(ps[mt][r]);
      float d = qredsum(pd[mt][r]);
      if (l15 == 0){
        int row = mt*16 + quad*4 + r;
        sda[wave*64 + row] = s;
        sdd[wave*64 + row] = d;
      }
    }
  __syncthreads();
  if (tid < 64){
    int grow = row0 + tid;
    if (grow < NN){
      asrc[grow] = sda[tid] + sda[64+tid] + sda[128+tid] + sda[192+tid];
      adst[grow] = sdd[tid] + sdd[64+tid] + sdd[128+tid] + sdd[192+tid];
    }
  }
}

// ---------------- GAT (r15: 2-way unrolled gather, dual fmax accumulators) ----------------
__global__ __launch_bounds__(256) void k_gat(const float* __restrict__ h_, const float* __restrict__ asrc_,
     const float* __restrict__ adst_, const int* __restrict__ rowptr_, const int* __restrict__ adj_,
     const float* __restrict__ biasA, const float* __restrict__ biasB, float* __restrict__ out_){
  int br = blockIdx.y;
  const float* h = h_ + (size_t)br*NN*HH;
  const float* asrc = asrc_ + (size_t)br*NN;
  const float* adst = adst_ + (size_t)br*NN;
  const int* rowptr = rowptr_ + (size_t)br*RPN;
  const int* adj = adj_ + (size_t)br*NE;
  const float* bias = br ? biasB : biasA;
  float* out = out_ + (size_t)br*NN*HH;

  int node = blockIdx.x*4 + (threadIdx.x>>6);
  int lane = threadIdx.x & 63;
  int rs = rowptr[node], re = rowptr[node+1];
  int deg = re - rs;
  float adsti = adst[node];
  float eself = leaky02(asrc[node] + adsti);
  int c0 = lane*4;
  float4 acc;
  float4 bv = *((const float4*)&bias[c0]);
  if (deg <= 64){
    bool act = lane < deg;
    int sv = 0; float asv = 0.f;
    if (act){ sv = adj[rs + lane]; asv = asrc[sv]; }
    float e_l = act ? leaky02(asv + adsti) : -INFINITY;
    float m = fmaxf(eself, wredmax(e_l));
    float ex = act ? expf(e_l - m) : 0.f;
    float es = expf(eself - m);
    float denom = wredsum(ex) + es + 1e-16f;
    float aself = es/denom;
    float av = ex/denom;
    float4 hv = *((const float4*)&h[(size_t)node*HH + c0]);
    acc = make_float4(hv.x*aself, hv.y*aself, hv.z*aself, hv.w*aself);
    float4 acc2 = make_float4(-INFINITY,-INFINITY,-INFINITY,-INFINITY);
    int jj = 0;
    for (; jj+1 < deg; jj += 2){
      int sb0 = __shfl(sv, jj, 64);
      int sb1 = __shfl(sv, jj+1, 64);
      float ab0 = __shfl(av, jj, 64);
      float ab1 = __shfl(av, jj+1, 64);
      float4 q0 = *((const float4*)&h[(size_t)sb0*HH + c0]);
      float4 q1 = *((const float4*)&h[(size_t)sb1*HH + c0]);
      acc  = fmax4(acc,  make_float4(q0.x*ab0, q0.y*ab0, q0.z*ab0, q0.w*ab0));
      acc2 = fmax4(acc2, make_float4(q1.x*ab1, q1.y*ab1, q1.z*ab1, q1.w*ab1));
    }
    if (jj < deg){
      int sb = __shfl(sv, jj, 64);
      float ab = __shfl(av, jj, 64);
      float4 q = *((const float4*)&h[(size_t)sb*HH + c0]);
      acc = fmax4(acc, make_float4(q.x*ab, q.y*ab, q.z*ab, q.w*ab));
    }
    acc = fmax4(acc, acc2);
  } else {
    float m = eself;
    for (int j = rs + lane; j < re; j += 64) m = fmaxf(m, leaky02(asrc[adj[j]] + adsti));
    m = wredmax(m);
    float ssum = 0.f;
    for (int j = rs + lane; j < re; j += 64) ssum += expf(leaky02(asrc[adj[j]] + adsti) - m);
    ssum = wredsum(ssum) + expf(eself - m);
    float denom = ssum + 1e-16f;
    float aself = expf(eself - m)/denom;
    float4 hv = *((const float4*)&h[(size_t)node*HH + c0]);
    acc = make_float4(hv.x*aself, hv.y*aself, hv.z*aself, hv.w*aself);
    float4 acc2 = make_float4(-INFINITY,-INFINITY,-INFINITY,-INFINITY);
    for (int jb = rs; jb < re; jb += 64){
      int cnt = min(64, re - jb);
      int sv = 0; float av = 0.f;
      if (lane < cnt){ sv = adj[jb+lane]; av = expf(leaky02(asrc[sv] + adsti) - m)/denom; }
      int jj = 0;
      for (; jj+1 < cnt; jj += 2){
        int sb0 = __shfl(sv, jj, 64);
        int sb1 = __shfl(sv, jj+1, 64);
        float ab0 = __shfl(av, jj, 64);
        float ab1 = __shfl(av, jj+1, 64);
        float4 q0 = *((const float4*)&h[(size_t)sb0*HH + c0]);
        float4 q1 = *((const float4*)&h[(size_t)sb1*HH + c0]);
        acc  = fmax4(acc,  make_float4(q0.x*ab0, q0.y*ab0, q0.z*ab0, q0.w*ab0));
        acc2 = fmax4(acc2, make_float4(q1.x*ab1, q1.y*ab1, q1.z*ab1, q1.w*ab1));
      }
      if (jj < cnt){
        int sb = __shfl(sv, jj, 64);
        float ab = __shfl(av, jj, 64);
        float4 q = *((const float4*)&h[(size_t)sb*HH + c0]);
        acc = fmax4(acc, make_float4(q.x*ab, q.y*ab, q.z*ab, q.w*ab));
      }
    }
    acc = fmax4(acc, acc2);
  }
  acc.x += bv.x; acc.y += bv.y; acc.z += bv.z; acc.w += bv.w;
  *((float4*)&out[(size_t)node*HH + c0]) = acc;
}

// ---------------- BatchNorm ----------------
__global__ __launch_bounds__(256) void k_bnstats(const float* __restrict__ x_, float* __restrict__ sums_){
  int br = blockIdx.y;
  const float* x = x_ + (size_t)br*NN*HH;
  float* s_ = sums_ + (size_t)br*2*HH;
  float* q_ = s_ + HH;
  int c = threadIdx.x;
  float s = 0.f, q = 0.f;
  for (int r = blockIdx.x; r < NN; r += gridDim.x){
    float v = x[(size_t)r*HH + c];
    s += v; q += v*v;
  }
  atomicAdd(&s_[c], s);
  atomicAdd(&q_[c], q);
}

__global__ __launch_bounds__(256) void k_bnfin(const float* __restrict__ sums_,
    const float* __restrict__ gA, const float* __restrict__ gB,
    const float* __restrict__ bA, const float* __restrict__ bB,
    float* __restrict__ scale_, float* __restrict__ shift_){
  int br = blockIdx.y;
  const float* sums = sums_ + (size_t)br*2*HH;
  const float* sumsq = sums + HH;
  const float* g = br ? gB : gA;
  const float* b = br ? bB : bA;
  float* scale = scale_ + (size_t)br*HH;
  float* shift = shift_ + (size_t)br*HH;
  int c = threadIdx.x;
  float mean = sums[c]/(float)NN;
  float var = sumsq[c]/(float)NN - mean*mean;
  float rstd = rsqrtf(var + 1e-5f);
  float sc = g[c]*rstd;
  scale[c] = sc; shift[c] = b[c] - mean*sc;
}

// ---------------- SAGE max-aggregate (r15: 2-way unrolled gather) ----------------
__global__ __launch_bounds__(256) void k_sageagg(const float* __restrict__ xin_, const float* __restrict__ scale_,
    const float* __restrict__ shift_, const float* __restrict__ pA, const float* __restrict__ pB,
    const int* __restrict__ rowptr_, const int* __restrict__ adj_, float* __restrict__ agg_){
  int br = blockIdx.y;
  const float* xin = xin_ + (size_t)br*NN*HH;
  const float* scale = scale_ + (size_t)br*HH;
  const float* shift = shift_ + (size_t)br*HH;
  const float* prelu = br ? pB : pA;
  const int* rowptr = rowptr_ + (size_t)br*RPN;
  const int* adj = adj_ + (size_t)br*NE;
  float* agg = agg_ + (size_t)br*NN*HH;

  int node = blockIdx.x*4 + (threadIdx.x>>6);
  int lane = threadIdx.x & 63;
  int rs = rowptr[node], re = rowptr[node+1];
  int c0 = lane*4;
  float slope = prelu[0];
  float4 sc = *((const float4*)&scale[c0]);
  float4 sh = *((const float4*)&shift[c0]);
  float4 acc  = make_float4(-INFINITY,-INFINITY,-INFINITY,-INFINITY);
  float4 acc2 = make_float4(-INFINITY,-INFINITY,-INFINITY,-INFINITY);
  for (int jb = rs; jb < re; jb += 64){
    int cnt = min(64, re - jb);
    int sv = (lane < cnt) ? adj[jb+lane] : 0;
    int jj = 0;
    for (; jj+1 < cnt; jj += 2){
      int sb0 = __shfl(sv, jj, 64);
      int sb1 = __shfl(sv, jj+1, 64);
      float4 q0 = *((const float4*)&xin[(size_t)sb0*HH + c0]);
      float4 q1 = *((const float4*)&xin[(size_t)sb1*HH + c0]);
      acc  = fmax4(acc,  bnprelu4(q0, sc, sh, slope));
      acc2 = fmax4(acc2, bnprelu4(q1, sc, sh, slope));
    }
    if (jj < cnt){
      int sb = __shfl(sv, jj, 64);
      float4 q = *((const float4*)&xin[(size_t)sb*HH + c0]);
      acc = fmax4(acc, bnprelu4(q, sc, sh, slope));
    }
  }
  acc = fmax4(acc, acc2);
  if (re == rs) acc = make_float4(0.f,0.f,0.f,0.f);
  *((float4*)&agg[(size_t)node*HH + c0]) = acc;
}

// ---------------- GEMM2 (r13-verified: M=64 x N=256, 512 thr / 8 waves, wave 64x32) ----------------
// 2-deep A register prefetch (vaA/vaB), softBarrier, B ping-pong; 56 VGPR, 4 blk/CU.
__global__ __launch_bounds__(512, 4) void k_gemm2(const float* __restrict__ graw_, const float* __restrict__ agg_,
    const u16* __restrict__ WtT_,
    const float* __restrict__ scale1_, const float* __restrict__ shift1_,
    const float* __restrict__ p1A, const float* __restrict__ p1B,
    const float* __restrict__ blA, const float* __restrict__ blB,
    float* __restrict__ out_, float* __restrict__ sums_){
  int br = blockIdx.y;
  const float* graw = graw_ + (size_t)br*NN*HH;
  const float* agg = agg_ + (size_t)br*NN*HH;
  const u16* WtT = WtT_ + (size_t)br*16*16384;
  const float* scale1 = scale1_ + (size_t)br*HH;
  const float* shift1 = shift1_ + (size_t)br*HH;
  const float* prelu1 = br ? p1B : p1A;
  const float* bl = br ? blB : blA;
  float* out = out_ + (size_t)br*NN*HH;
  float* sums = sums_ + (size_t)br*2*HH;
  float* sumsq = sums + HH;

  __shared__ u16 As[2][8*ASTRIDE];
  int tid = threadIdx.x;
  int row0 = blockIdx.x*64;
  int wave = tid>>6, lane = tid&63;
  int l15 = lane&15, quad = lane>>4;
  int col0 = wave*32;
  int sm_ = tid >> 3, sg = tid & 7;   // 8 threads per row, 4 floats each
  int sgrow = row0 + sm_; if (sgrow >= NN) sgrow = NN-1;
  float slope = prelu1[0];
  f32x4 acc[4][2];
  #pragma unroll
  for (int mt=0;mt<4;mt++)
    #pragma unroll
    for (int nt=0;nt<2;nt++){ f32x4 z = {0.f,0.f,0.f,0.f}; acc[mt][nt] = z; }

  const u16* bbase = WtT + ((size_t)quad<<12) + (size_t)(col0 + l15)*8;
  bf16x8 B0h[2],B0l[2],B1h[2],B1l[2];
  float4 vaA, vaB;

  auto loadA = [&](int kc, float4& dst){
    const float* ab = (kc < HH) ? graw : agg;
    int ac = (kc < HH) ? kc : kc - HH;
    dst = *((const float4*)(ab + (size_t)sgrow*HH + ac + sg*4));
  };
  auto writeA = [&](int kc, int wb, float4 v){
    if (kc < HH){
      int kcol = kc + sg*4;
      v = bnprelu4(v, *((const float4*)(scale1+kcol)), *((const float4*)(shift1+kcol)), slope);
    }
    bf16x4 h, l;
    split4(v, h, l);
    int cell = (sg>>1)*ASTRIDE + sm_*8 + (sg&1)*4;
    *((bf16x4*)&As[wb][cell]) = h;
    *((bf16x4*)&As[wb][cell + 4*ASTRIDE]) = l;
  };
  auto loadB = [&](int ck, bf16x8 (&Bh)[2], bf16x8 (&Bl)[2]){
    const u16* bb = bbase + ((size_t)ck<<14);
    #pragma unroll
    for (int nt=0;nt<2;nt++){
      Bh[nt] = *((const bf16x8*)(bb + nt*128));
      Bl[nt] = *((const bf16x8*)(bb + 2048 + nt*128));
    }
  };
  auto body = [&](int k, int rb, float4& vaW, float4& vaL, bf16x8 (&Bh)[2], bf16x8 (&Bl)[2], bf16x8 (&nBh)[2], bf16x8 (&nBl)[2]){
    softBarrier();
    if (k < 15) writeA((k+1)*32, rb^1, vaW);
    if (k < 13) loadA((k+3)*32, vaW);
    if (k < 15) loadB(k+1, nBh, nBl);
    (void)vaL;
    #pragma unroll
    for (int mt=0;mt<4;mt++){
      int m = mt*16 + l15;
      bf16x8 ah = *((bf16x8*)&As[rb][quad*ASTRIDE + m*8]);
      bf16x8 al = *((bf16x8*)&As[rb][(4+quad)*ASTRIDE + m*8]);
      #pragma unroll
      for (int nt=0;nt<2;nt++){
        acc[mt][nt] = __builtin_amdgcn_mfma_f32_16x16x32_bf16(ah, Bh[nt], acc[mt][nt], 0, 0, 0);
        acc[mt][nt] = __builtin_amdgcn_mfma_f32_16x16x32_bf16(al, Bh[nt], acc[mt][nt], 0, 0, 0);
        acc[mt][nt] = __builtin_amdgcn_mfma_f32_16x16x32_bf16(ah, Bl[nt], acc[mt][nt], 0, 0, 0);
      }
    }
  };

  loadA(0, vaA);
  writeA(0, 0, vaA);
  loadA(32, vaA);
  loadA(64, vaB);
  loadB(0, B0h, B0l);
  #pragma unroll 1
  for (int k=0; k<16; k+=2){
    body(k,   0, vaA, vaB, B0h,B0l, B1h,B1l);
    body(k+1, 1, vaB, vaA, B1h,B1l, B0h,B0l);
  }

  float psum[2], psq[2];
  #pragma unroll
  for (int nt=0;nt<2;nt++){
    int c = col0 + nt*16 + l15;
    float bcol = bl[c];
    float s=0.f, q=0.f;
    #pragma unroll
    for (int mt=0;mt<4;mt++){
      int gbase = row0 + mt*16 + quad*4;
      #pragma unroll
      for (int r=0;r<4;r++){
        int grow = gbase + r;
        float v = acc[mt][nt][r] + bcol;
        if (grow < NN){
          out[(size_t)grow*HH + c] = v;
          s += v; q += v*v;
        }
      }
    }
    psum[nt]=s; psq[nt]=q;
  }
  __syncthreads();
  float* sm2 = (float*)As;
  sm2[tid] = 0.f;
  __syncthreads();
  #pragma unroll
  for (int nt=0;nt<2;nt++){
    int c = col0 + nt*16 + l15;
    atomicAdd(&sm2[c], psum[nt]);
    atomicAdd(&sm2[256+c], psq[nt]);
  }
  __syncthreads();
  if (tid < 256){
    atomicAdd(&sums[tid],  sm2[tid]);
    atomicAdd(&sumsq[tid], sm2[256+tid]);
  }
}

// ---------------- pool GEMVs ----------------
__global__ __launch_bounds__(256) void k_gemv2(const float* __restrict__ x2_, const float* __restrict__ scale2_,
    const float* __restrict__ shift2_, const float* __restrict__ p2A, const float* __restrict__ p2B,
    const float* __restrict__ WrelA, const float* __restrict__ WrelB,
    const float* __restrict__ WrootA, const float* __restrict__ WrootB,
    float* __restrict__ y2_, float* __restrict__ y2r_){
  int br = blockIdx.y;
  const float* x2raw = x2_ + (size_t)br*NN*HH;
  const float* scale2 = scale2_ + (size_t)br*HH;
  const float* shift2 = shift2_ + (size_t)br*HH;
  const float* prelu2 = br ? p2B : p2A;
  const float* Wrel = br ? WrelB : WrelA;
  const float* Wroot = br ? WrootB : WrootA;
  float* y2 = y2_ + (size_t)br*NN;
  float* y2r = y2r_ + (size_t)br*NN;

  int node = blockIdx.x*4 + (threadIdx.x>>6);
  int lane = threadIdx.x & 63;
  int c0 = lane*4;
  float slope = prelu2[0];
  float4 v = *((const float4*)&x2raw[(size_t)node*HH + c0]);
  float4 sc = *((const float4*)&scale2[c0]);
  float4 sh = *((const float4*)&shift2[c0]);
  v = bnprelu4(v, sc, sh, slope);
  float4 wr = *((const float4*)&Wrel[c0]);
  float4 wo = *((const float4*)&Wroot[c0]);
  float pr = v.x*wr.x + v.y*wr.y + v.z*wr.z + v.w*wr.w;
  float po = v.x*wo.x + v.y*wo.y + v.z*wo.z + v.w*wo.w;
  pr = wredsum(pr); po = wredsum(po);
  if (lane==0){ y2[node] = pr; y2r[node] = po; }
}

// k_score with fused hist1
__global__ void k_score(const int* __restrict__ rowptr_, const int* __restrict__ adj_, const float* __restrict__ y2_,
    const float* __restrict__ y2r_, const float* __restrict__ brelA, const float* __restrict__ brelB,
    float* __restrict__ score_, unsigned* __restrict__ keys_, unsigned* __restrict__ hist_){
  int br = blockIdx.y;
  const int* rowptr = rowptr_ + (size_t)br*RPN;
  const int* adj = adj_ + (size_t)br*NE;
  const float* y2 = y2_ + (size_t)br*NN;
  const float* y2r = y2r_ + (size_t)br*NN;
  const float* brel = br ? brelB : brelA;
  float* score = score_ + (size_t)br*NN;
  unsigned* keys = keys_ + (size_t)br*NN;
  unsigned* hist = hist_ + (size_t)br*65536;

  int i = blockIdx.x*blockDim.x + threadIdx.x;
  if (i >= NN) return;
  float s = 0.f;
  int rs = rowptr[i], re = rowptr[i+1];
  for (int j=rs;j<re;j++) s += y2[adj[j]];
  float sc = s + brel[0] + y2r[i];
  score[i] = sc;
  unsigned u = __float_as_uint(sc);
  u = (u & 0x80000000u) ? ~u : (u | 0x80000000u);
  keys[i] = u;
  atomicAdd(&hist[u>>16], 1u);
}

// parallel suffix-scan findbin: uint4 coarse sums + log-step scans
__global__ __launch_bounds__(256) void k_findbin1(const unsigned* __restrict__ hist_, unsigned* __restrict__ scal_){
  int br = blockIdx.y;
  const unsigned* hist = hist_ + (size_t)br*65536;
  unsigned* scal = scal_ + (size_t)br*16;
  __shared__ unsigned suf[256];
  __shared__ unsigned shc[2];
  int t = threadIdx.x;
  const uint4* h4 = (const uint4*)(hist + t*256);
  unsigned s = 0;
  #pragma unroll 8
  for (int b=0;b<64;b++){ uint4 v = h4[b]; s += v.x+v.y+v.z+v.w; }
  suf[t] = s; __syncthreads();
  #pragma unroll
  for (int o=1;o<256;o<<=1){
    unsigned add = (t+o<256)? suf[t+o] : 0u;
    __syncthreads();
    suf[t] += add;
    __syncthreads();
  }
  unsigned ab = suf[t] - s;
  if (ab < (unsigned)KT && ab + s >= (unsigned)KT){ shc[0] = (unsigned)t; shc[1] = ab; }
  __syncthreads();
  int cb = (int)shc[0]; unsigned runbase = shc[1];
  unsigned f = hist[cb*256 + t];
  suf[t] = f; __syncthreads();
  #pragma unroll
  for (int o=1;o<256;o<<=1){
    unsigned add = (t+o<256)? suf[t+o] : 0u;
    __syncthreads();
    suf[t] += add;
    __syncthreads();
  }
  unsigned ta = runbase + suf[t] - f;
  if (ta < (unsigned)KT && ta + f >= (unsigned)KT){
    scal[0] = (unsigned)(cb*256 + t);
    scal[1] = ta;
  }
}

__global__ void k_hist2(const unsigned* __restrict__ keys_, const unsigned* __restrict__ scal_, unsigned* __restrict__ hist_){
  int br = blockIdx.y;
  const unsigned* keys = keys_ + (size_t)br*NN;
  const unsigned* scal = scal_ + (size_t)br*16;
  unsigned* hist = hist_ + (size_t)br*65536;
  int i = blockIdx.x*blockDim.x + threadIdx.x;
  if (i < NN){ unsigned k = keys[i]; if ((k>>16) == scal[0]) atomicAdd(&hist[k & 0xFFFFu], 1u); }
}

__global__ __launch_bounds__(256) void k_findbin2(const unsigned* __restrict__ hist_, unsigned* __restrict__ scal_){
  int br = blockIdx.y;
  const unsigned* hist = hist_ + (size_t)br*65536;
  unsigned* scal = scal_ + (size_t)br*16;
  __shared__ unsigned suf[256];
  __shared__ unsigned shc[2];
  int t = threadIdx.x;
  unsigned target = (unsigned)KT - scal[1];
  const uint4* h4 = (const uint4*)(hist + t*256);
  unsigned s = 0;
  #pragma unroll 8
  for (int b=0;b<64;b++){ uint4 v = h4[b]; s += v.x+v.y+v.z+v.w; }
  suf[t] = s; __syncthreads();
  #pragma unroll
  for (int o=1;o<256;o<<=1){
    unsigned add = (t+o<256)? suf[t+o] : 0u;
    __syncthreads();
    suf[t] += add;
    __syncthreads();
  }
  unsigned ab = suf[t] - s;
  if (ab < target && ab + s >= target){ shc[0] = (unsigned)t; shc[1] = ab; }
  __syncthreads();
  int cb = (int)shc[0]; unsigned runbase = shc[1];
  unsigned f = hist[cb*256 + t];
  suf[t] = f; __syncthreads();
  #pragma unroll
  for (int o=1;o<256;o<<=1){
    unsigned add = (t+o<256)? suf[t+o] : 0u;
    __syncthreads();
    suf[t] += add;
    __syncthreads();
  }
  unsigned ta = runbase + suf[t] - f;
  if (ta < target && ta + f >= target){
    scal[2] = (scal[0] << 16) | (unsigned)(cb*256 + t);
    scal[3] = target - ta;
    scal[4] = f;
  }
}

__global__ void k_select(const unsigned* __restrict__ keys_, const float* __restrict__ score_,
    unsigned* __restrict__ scal_, int* __restrict__ selidx_, float* __restrict__ tvals_){
  int br = blockIdx.y;
  const unsigned* keys = keys_ + (size_t)br*NN;
  const float* score = score_ + (size_t)br*NN;
  unsigned* scal = scal_ + (size_t)br*16;
  int* selidx = selidx_ + (size_t)br*NN;
  float* tvals = tvals_ + (size_t)br*NN;

  int i = blockIdx.x*blockDim.x + threadIdx.x;
  if (i >= NN) return;
  unsigned T = scal[2], needed = scal[3], cnteq = scal[4];
  unsigned k = keys[i];
  int s = 0;
  if (k > T) s = 1;
  else if (k == T){
    if (cnteq <= needed) s = 1;
    else {
      unsigned rank = 0;
      for (int j=0;j<i;j++) rank += (keys[j] == T) ? 1u : 0u;
      s = (rank < needed) ? 1 : 0;
    }
  }
  if (s){
    unsigned idx = atomicAdd(&scal[8], 1u);
    selidx[idx] = i;
    tvals[idx] = tanhf(score[i]);
  }
}

__global__ __launch_bounds__(256) void k_embed(const float* __restrict__ x2_, const float* __restrict__ scale2_,
    const float* __restrict__ shift2_, const float* __restrict__ p2A, const float* __restrict__ p2B,
    const int* __restrict__ selidx_, const float* __restrict__ tvals_, float* __restrict__ embed){
  int br = blockIdx.y;
  const float* x2raw = x2_ + (size_t)br*NN*HH;
  const float* scale2 = scale2_ + (size_t)br*HH;
  const float* shift2 = shift2_ + (size_t)br*HH;
  const float* prelu2 = br ? p2B : p2A;
  const int* selidx = selidx_ + (size_t)br*NN;
  const float* tvals = tvals_ + (size_t)br*NN;

  int c = threadIdx.x;
  float slope = prelu2[0];
  float scv = scale2[c], shv = shift2[c];
  float best = -INFINITY;
  for (int j = blockIdx.x; j < KT; j += gridDim.x){
    int r = selidx[j];
    float v = x2raw[(size_t)r*HH + c]*scv + shv;
    v = preluf(v, slope);
    best = fmaxf(best, v*tvals[j]);
  }
  atomicMaxF(&embed[(size_t)br*HH + c], best);
}

__global__ void k_initembed(float* __restrict__ embed){
  int i = threadIdx.x;
  if (i < 2*HH) embed[i] = -INFINITY;
}

// ---------------- head ----------------
__global__ __launch_bounds__(256) void k_head(const float* __restrict__ embed, const float* __restrict__ addf,
    const float* __restrict__ fc1W, const float* __restrict__ fc1b, const float* __restrict__ preluh,
    const float* __restrict__ fc2W, const float* __restrict__ fc2b, float* __restrict__ out){
  __shared__ float z[2*HH + 8];
  __shared__ float h1s[HH];
  __shared__ float red[4];
  int t = threadIdx.x;
  for (int i=t;i<2*HH;i+=256) z[i] = embed[i];
  if (t < 8) z[2*HH + t] = addf[t];
  __syncthreads();
  float acc = fc1b[t];
  for (int k=0;k<2*HH+8;k++) acc += z[k]*fc1W[(size_t)k*HH + t];
  float slope = preluh[0];
  h1s[t] = preluf(acc, slope);
  __syncthreads();
  float p = h1s[t]*fc2W[t];
  p = wredsum(p);
  if ((t & 63) == 0) red[t>>6] = p;
  __syncthreads();
  if (t == 0) out[0] = expf(red[0]+red[1]+red[2]+red[3] + fc2b[0]);
}

// ---------------- orchestration ----------------
extern "C" void kernel_launch(void* const* d_in, const int* in_sizes, int n_in,
                              void* d_out, int out_size, void* d_ws, size_t ws_size,
                              hipStream_t stream) {
  (void)in_sizes; (void)n_in; (void)out_size;
  char* ws = (char*)d_ws;

  float *bufA, *bufB, *asrc, *adst, *sums, *scale1, *shift1, *scale2, *shift2;
  float *y2, *y2r, *score, *tvals, *embed;
  int *rowptr, *adj, *cursor, *bsums, *selidx;
  unsigned *keys, *hist1, *hist2, *scal;
  u16 *WtT, *WtT1;

  auto doAlloc = [&](int nb)->size_t{
    size_t o = 0;
    auto al = [&](size_t bytes)->char*{ char* p = ws + o; o = (o + bytes + 255) & ~(size_t)255; return p; };
    bufA   = (float*)al((size_t)nb*NN*HH*4);
    bufB   = (float*)al((size_t)nb*NN*HH*4);
    asrc   = (float*)al((size_t)nb*NN*4);
    adst   = (float*)al((size_t)nb*NN*4);
    rowptr = (int*)  al((size_t)nb*RPN*4);
    adj    = (int*)  al((size_t)nb*NE*4);
    cursor = (int*)  al((size_t)nb*NN*4);
    bsums  = (int*)  al((size_t)nb*128*4);
    sums   = (float*)al((size_t)nb*2*HH*4);
    scale1 = (float*)al((size_t)nb*HH*4);
    shift1 = (float*)al((size_t)nb*HH*4);
    scale2 = (float*)al((size_t)nb*HH*4);
    shift2 = (float*)al((size_t)nb*HH*4);
    y2     = (float*)al((size_t)nb*NN*4);
    y2r    = (float*)al((size_t)nb*NN*4);
    score  = (float*)al((size_t)nb*NN*4);
    keys   = (unsigned*)al((size_t)nb*NN*4);
    selidx = (int*)  al((size_t)nb*NN*4);
    tvals  = (float*)al((size_t)nb*NN*4);
    hist1  = (unsigned*)al((size_t)nb*65536*4);
    hist2  = (unsigned*)al((size_t)nb*65536*4);
    scal   = (unsigned*)al((size_t)nb*64);
    embed  = (float*)al((size_t)2*HH*4);
    WtT    = (u16*)al((size_t)nb*16*16384*2);
    WtT1   = (u16*)al((size_t)nb*2*16384*2);
    return o;
  };

  int NB = 2;
  if (doAlloc(2) > ws_size) NB = 1;
  doAlloc(NB);

  const float* addf = (const float*)d_in[2];

  k_initembed<<<dim3(1), dim3(512), 0, stream>>>(embed);

  int nIter = (NB==2) ? 1 : 2;
  for (int it = 0; it < nIter; ++it){
    const float *xA, *xB; const int *eiA, *eiB; int pa, pb;
    if (NB == 2){
      xA = (const float*)d_in[0]; xB = (const float*)d_in[1];
      eiA = (const int*)d_in[3]; eiB = (const int*)d_in[4];
      pa = 5; pb = 21;
    } else {
      xA = xB = (const float*)d_in[it];
      eiA = eiB = (const int*)d_in[3+it];
      pa = pb = (it==0) ? 5 : 21;
    }
    auto PA = [&](int i){ return (const float*)d_in[pa+i]; };
    auto PB = [&](int i){ return (const float*)d_in[pb+i]; };

    // CSR by dst (both branches)
    hipMemsetAsync(cursor, 0, (size_t)NB*NN*4, stream);
    k_count<<<dim3((NE+255)/256, NB), dim3(256), 0, stream>>>(eiA, eiB, cursor);
    k_scan1<<<dim3(98, NB), dim3(1024), 0, stream>>>(cursor, rowptr, bsums);
    k_scan2<<<dim3(1, NB), dim3(128), 0, stream>>>(bsums, 98);
    k_scan3<<<dim3(98, NB), dim3(1024), 0, stream>>>(rowptr, bsums, cursor);
    k_scatter<<<dim3((NE+255)/256, NB), dim3(256), 0, stream>>>(eiA, eiB, cursor, adj);

    // W pre-splits (merged)
    k_splitWall<<<dim3(576, NB), dim3(256), 0, stream>>>(PA(9), PB(9), PA(7), PB(7), PA(0), PB(0), WtT, WtT1);

    // GAT
    k_gemm1<<<dim3((NN+63)/64, NB), dim3(256), 0, stream>>>(xA, xB, WtT1,
        PA(1), PB(1), PA(2), PB(2), bufA, asrc, adst);
    k_gat<<<dim3(25000, NB), dim3(256), 0, stream>>>(bufA, asrc, adst, rowptr, adj, PA(3), PB(3), bufB);

    // BN1
    hipMemsetAsync(sums, 0, (size_t)NB*2*HH*4, stream);
    k_bnstats<<<dim3(512, NB), dim3(256), 0, stream>>>(bufB, sums);
    k_bnfin<<<dim3(1, NB), dim3(256), 0, stream>>>(sums, PA(4), PB(4), PA(5), PB(5), scale1, shift1);

    // SAGE
    k_sageagg<<<dim3(25000, NB), dim3(256), 0, stream>>>(bufB, scale1, shift1, PA(6), PB(6), rowptr, adj, bufA);
    hipMemsetAsync(sums, 0, (size_t)NB*2*HH*4, stream);
    k_gemm2<<<dim3((NN+63)/64, NB), dim3(512), 0, stream>>>(bufB, bufA, WtT,
        scale1, shift1, PA(6), PB(6), PA(8), PB(8), bufB, sums);
    k_bnfin<<<dim3(1, NB), dim3(256), 0, stream>>>(sums, PA(10), PB(10), PA(11), PB(11), scale2, shift2);

    // SAGPool (hist1 fused into k_score; memsets hoisted)
    hipMemsetAsync(scal, 0, (size_t)NB*64, stream);
    hipMemsetAsync(hist1, 0, (size_t)NB*65536*4, stream);
    hipMemsetAsync(hist2, 0, (size_t)NB*65536*4, stream);
    k_gemv2<<<dim3(25000, NB), dim3(256), 0, stream>>>(bufB, scale2, shift2, PA(12), PB(12),
        PA(13), PB(13), PA(15), PB(15), y2, y2r);
    k_score<<<dim3((NN+255)/256, NB), dim3(256), 0, stream>>>(rowptr, adj, y2, y2r, PA(14), PB(14), score, keys, hist1);
    k_findbin1<<<dim3(1, NB), dim3(256), 0, stream>>>(hist1, scal);
    k_hist2<<<dim3((NN+255)/256, NB), dim3(256), 0, stream>>>(keys, scal, hist2);
    k_findbin2<<<dim3(1, NB), dim3(256), 0, stream>>>(hist2, scal);
    k_select<<<dim3((NN+255)/256, NB), dim3(256), 0, stream>>>(keys, score, scal, selidx, tvals);
    float* embDst = (NB==2) ? embed : (embed + it*HH);
    k_embed<<<dim3(256, NB), dim3(256), 0, stream>>>(bufB, scale2, shift2, PA(12), PB(12), selidx, tvals, embDst);
  }

  k_head<<<dim3(1), dim3(256), 0, stream>>>(embed, addf,
      (const float*)d_in[37], (const float*)d_in[38], (const float*)d_in[39],
      (const float*)d_in[40], (const float*)d_in[41], (float*)d_out);
}

// Round 8
// 1384.935 us; speedup vs baseline: 1.0969x; 1.0735x over previous
//
#include <hip/hip_runtime.h>
#include <math.h>

#define NN 100000
#define NE 400000
#define FI 64
#define HH 256
#define KT 50000
#define RPN (NN+1)
#define PCOPIES 64

typedef unsigned short u16;
typedef __attribute__((ext_vector_type(8))) short bf16x8;
typedef __attribute__((ext_vector_type(4))) short bf16x4;
typedef __attribute__((ext_vector_type(4))) float f32x4;

__device__ __forceinline__ float leaky02(float x){ return x >= 0.f ? x : 0.2f*x; }
__device__ __forceinline__ float preluf(float x, float a){ return x >= 0.f ? x : a*x; }

__device__ __forceinline__ float wredmax(float v){
  #pragma unroll
  for (int o=32;o>0;o>>=1) v = fmaxf(v, __shfl_xor(v, o, 64));
  return v;
}
__device__ __forceinline__ float wredsum(float v){
  #pragma unroll
  for (int o=32;o>0;o>>=1) v += __shfl_xor(v, o, 64);
  return v;
}
__device__ __forceinline__ float qredsum(float v){
  #pragma unroll
  for (int o=8;o>0;o>>=1) v += __shfl_xor(v, o, 64);
  return v;
}

// barrier that does NOT drain vmcnt (keeps prefetch loads in flight)
__device__ __forceinline__ void softBarrier(){
  asm volatile("s_waitcnt lgkmcnt(0)" ::: "memory");
  __builtin_amdgcn_s_barrier();
}

__device__ __forceinline__ void atomicMaxF(float* a, float v){
  if (v >= 0.f) atomicMax((int*)a, __float_as_int(v));
  else atomicMin((unsigned int*)a, __float_as_uint(v));
}

__device__ __forceinline__ float4 bnprelu4(float4 v, float4 sc, float4 sh, float a){
  float4 r;
  r.x = preluf(v.x*sc.x+sh.x, a);
  r.y = preluf(v.y*sc.y+sh.y, a);
  r.z = preluf(v.z*sc.z+sh.z, a);
  r.w = preluf(v.w*sc.w+sh.w, a);
  return r;
}

__device__ __forceinline__ float4 fmax4(float4 a, float4 b){
  return make_float4(fmaxf(a.x,b.x), fmaxf(a.y,b.y), fmaxf(a.z,b.z), fmaxf(a.w,b.w));
}

__device__ __forceinline__ u16 f2bf(float f){
  unsigned u = __float_as_uint(f);
  unsigned r = u + 0x7FFFu + ((u>>16)&1u);
  return (u16)(r>>16);
}
__device__ __forceinline__ float bf2f(u16 h){
  return __uint_as_float(((unsigned)h)<<16);
}
__device__ __forceinline__ void split8(float4 a, float4 b, bf16x8& h, bf16x8& l){
  float va[8] = {a.x,a.y,a.z,a.w,b.x,b.y,b.z,b.w};
  #pragma unroll
  for (int j=0;j<8;j++){
    u16 hh = f2bf(va[j]);
    h[j] = (short)hh;
    l[j] = (short)f2bf(va[j] - bf2f(hh));
  }
}
__device__ __forceinline__ void split4(float4 a, bf16x4& h, bf16x4& l){
  float va[4] = {a.x,a.y,a.z,a.w};
  #pragma unroll
  for (int j=0;j<4;j++){
    u16 hh = f2bf(va[j]);
    h[j] = (short)hh;
    l[j] = (short)f2bf(va[j] - bf2f(hh));
  }
}

// ---------------- CSR build (batched over blockIdx.y) ----------------
__global__ void k_count(const int* __restrict__ eiA, const int* __restrict__ eiB, int* __restrict__ deg_){
  int br = blockIdx.y;
  const int* dst = (br ? eiB : eiA) + NE;
  int* deg = deg_ + (size_t)br*NN;
  int e = blockIdx.x*blockDim.x + threadIdx.x;
  if (e < NE) atomicAdd(&deg[dst[e]], 1);
}

__global__ __launch_bounds__(1024) void k_scan1(const int* __restrict__ deg_, int* __restrict__ rowptr_, int* __restrict__ bsums_){
  int br = blockIdx.y;
  const int* deg = deg_ + (size_t)br*NN;
  int* rowptr = rowptr_ + (size_t)br*RPN;
  int* bsums = bsums_ + (size_t)br*128;
  __shared__ int sm[1024];
  int t = threadIdx.x; int g = blockIdx.x*1024 + t;
  int v = (g < NN) ? deg[g] : 0;
  sm[t] = v; __syncthreads();
  for (int o=1;o<1024;o<<=1){
    int add = (t>=o)? sm[t-o] : 0;
    __syncthreads();
    sm[t] += add;
    __syncthreads();
  }
  if (g < NN) rowptr[g] = sm[t] - v;
  if (t == 1023) bsums[blockIdx.x] = sm[1023];
}

__global__ __launch_bounds__(128) void k_scan2(int* __restrict__ bsums_, int nblk){
  int br = blockIdx.y;
  int* bsums = bsums_ + (size_t)br*128;
  __shared__ int sm[128];
  int t = threadIdx.x;
  int v = (t < nblk) ? bsums[t] : 0;
  sm[t] = v; __syncthreads();
  for (int o=1;o<128;o<<=1){
    int add = (t>=o)? sm[t-o] : 0;
    __syncthreads();
    sm[t] += add;
    __syncthreads();
  }
  if (t < nblk) bsums[t] = sm[t] - v;
}

__global__ __launch_bounds__(1024) void k_scan3(int* __restrict__ rowptr_, const int* __restrict__ bsums_, int* __restrict__ cursor_){
  int br = blockIdx.y;
  int* rowptr = rowptr_ + (size_t)br*RPN;
  const int* bsums = bsums_ + (size_t)br*128;
  int* cursor = cursor_ + (size_t)br*NN;
  int g = blockIdx.x*1024 + threadIdx.x;
  if (g < NN){ int r = rowptr[g] + bsums[blockIdx.x]; rowptr[g] = r; cursor[g] = r; }
  if (blockIdx.x==0 && threadIdx.x==0) rowptr[NN] = NE;
}

__global__ void k_scatter(const int* __restrict__ eiA, const int* __restrict__ eiB, int* __restrict__ cursor_, int* __restrict__ adj_){
  int br = blockIdx.y;
  const int* ei = br ? eiB : eiA;
  const int* src = ei;
  const int* dst = ei + NE;
  int* cursor = cursor_ + (size_t)br*NN;
  int* adj = adj_ + (size_t)br*NE;
  int e = blockIdx.x*blockDim.x + threadIdx.x;
  if (e < NE){ int d = dst[e]; int slot = atomicAdd(&cursor[d], 1); adj[slot] = src[e]; }
}

// ---------------- W pre-split (merged big + gat W) ----------------
__global__ __launch_bounds__(256) void k_splitWall(const float* __restrict__ WrA, const float* __restrict__ WrB,
    const float* __restrict__ WlA, const float* __restrict__ WlB,
    const float* __restrict__ WgA, const float* __restrict__ WgB,
    u16* __restrict__ WtT_, u16* __restrict__ WtT1_){
  int br = blockIdx.y;
  if (blockIdx.x < 512){
    const float* Wr = br ? WrB : WrA;
    const float* Wl = br ? WlB : WlA;
    u16* WtT = WtT_ + (size_t)br*16*16384;
    int idx = blockIdx.x*256 + threadIdx.x;
    int k = idx >> 8, n = idx & 255;
    float v = (k < HH) ? Wr[(size_t)k*HH + n] : Wl[(size_t)(k-HH)*HH + n];
    u16 hi = f2bf(v);
    float lo = v - bf2f(hi);
    size_t base = ((size_t)(k>>5))*16384 + (size_t)((k>>3)&3)*4096 + (size_t)n*8 + (k&7);
    WtT[base] = hi;
    WtT[base + 2048] = f2bf(lo);
  } else {
    const float* W = br ? WgB : WgA;
    u16* WtT = WtT1_ + (size_t)br*2*16384;
    int idx = (blockIdx.x-512)*256 + threadIdx.x;   // 64*256
    int k = idx >> 8, n = idx & 255;
    float v = W[(size_t)k*HH + n];
    u16 hi = f2bf(v);
    float lo = v - bf2f(hi);
    size_t base = ((size_t)(k>>5))*16384 + (size_t)((k>>3)&3)*4096 + (size_t)n*8 + (k&7);
    WtT[base] = hi;
    WtT[base + 2048] = f2bf(lo);
  }
}

#define ASTRIDE 528

// ---------------- GEMM1 ----------------
__global__ __launch_bounds__(256, 2) void k_gemm1(const float* __restrict__ xA, const float* __restrict__ xB,
    const u16* __restrict__ WtT_,
    const float* __restrict__ asA, const float* __restrict__ asB,
    const float* __restrict__ adA, const float* __restrict__ adB,
    float* __restrict__ out_, float* __restrict__ asrc_, float* __restrict__ adst_){
  int br = blockIdx.y;
  const float* x = br ? xB : xA;
  const u16* WtT = WtT_ + (size_t)br*2*16384;
  const float* a_src = br ? asB : asA;
  const float* a_dst = br ? adB : adA;
  float* out = out_ + (size_t)br*NN*HH;
  float* asrc = asrc_ + (size_t)br*NN;
  float* adst = adst_ + (size_t)br*NN;

  __shared__ u16 As[2][8*ASTRIDE];
  int tid = threadIdx.x;
  int row0 = blockIdx.x*64;
  int wave = tid>>6, lane = tid&63;
  int l15 = lane&15, quad = lane>>4;
  int col0 = wave*64;
  int sm_ = tid >> 2, sg = tid & 3;
  int sgrow = row0 + sm_; if (sgrow >= NN) sgrow = NN-1;
  f32x4 acc[4][4];
  #pragma unroll
  for (int mt=0;mt<4;mt++)
    #pragma unroll
    for (int nt=0;nt<4;nt++){ f32x4 z = {0.f,0.f,0.f,0.f}; acc[mt][nt] = z; }

  const u16* bbase = WtT + ((size_t)quad<<12) + (size_t)(col0 + l15)*8;
  bf16x8 B0h[4],B0l[4],B1h[4],B1l[4];
  float4 va0, va1;

  auto loadA = [&](int kc){
    va0 = *((const float4*)(x + (size_t)sgrow*FI + kc + sg*8));
    va1 = *((const float4*)(x + (size_t)sgrow*FI + kc + sg*8 + 4));
  };
  auto writeA = [&](int wb){
    bf16x8 h, l;
    split8(va0, va1, h, l);
    *((bf16x8*)&As[wb][sg*ASTRIDE + sm_*8]) = h;
    *((bf16x8*)&As[wb][(4+sg)*ASTRIDE + sm_*8]) = l;
  };
  auto loadB = [&](int ck, bf16x8 (&Bh)[4], bf16x8 (&Bl)[4]){
    const u16* bb = bbase + ((size_t)ck<<14);
    #pragma unroll
    for (int nt=0;nt<4;nt++){
      Bh[nt] = *((const bf16x8*)(bb + nt*128));
      Bl[nt] = *((const bf16x8*)(bb + 2048 + nt*128));
    }
  };
  auto mmacc = [&](int rb, bf16x8 (&Bh)[4], bf16x8 (&Bl)[4]){
    bf16x8 ah[4], al[4];
    #pragma unroll
    for (int mt=0;mt<4;mt++){
      int m = mt*16 + l15;
      ah[mt] = *((bf16x8*)&As[rb][quad*ASTRIDE + m*8]);
      al[mt] = *((bf16x8*)&As[rb][(4+quad)*ASTRIDE + m*8]);
    }
    #pragma unroll
    for (int nt=0;nt<4;nt++)
      #pragma unroll
      for (int mt=0;mt<4;mt++){
        acc[mt][nt] = __builtin_amdgcn_mfma_f32_16x16x32_bf16(ah[mt], Bh[nt], acc[mt][nt], 0, 0, 0);
        acc[mt][nt] = __builtin_amdgcn_mfma_f32_16x16x32_bf16(al[mt], Bh[nt], acc[mt][nt], 0, 0, 0);
        acc[mt][nt] = __builtin_amdgcn_mfma_f32_16x16x32_bf16(ah[mt], Bl[nt], acc[mt][nt], 0, 0, 0);
      }
  };

  loadA(0);
  writeA(0);
  loadA(32);
  loadB(0, B0h, B0l);
  softBarrier();
  writeA(1);
  loadB(1, B1h, B1l);
  mmacc(0, B0h, B0l);
  softBarrier();
  mmacc(1, B1h, B1l);

  float ps[4][4], pd[4][4];
  #pragma unroll
  for (int mt=0;mt<4;mt++)
    #pragma unroll
    for (int r=0;r<4;r++){ ps[mt][r]=0.f; pd[mt][r]=0.f; }
  #pragma unroll
  for (int nt=0;nt<4;nt++){
    int c = col0 + nt*16 + l15;
    float av = a_src[c], dv = a_dst[c];
    #pragma unroll
    for (int mt=0;mt<4;mt++){
      int gbase = row0 + mt*16 + quad*4;
      #pragma unroll
      for (int r=0;r<4;r++){
        int grow = gbase + r;
        float v = acc[mt][nt][r];
        if (grow < NN) out[(size_t)grow*HH + c] = v;
        ps[mt][r] += v*av; pd[mt][r] += v*dv;
      }
    }
  }
  __syncthreads();
  float* sda = (float*)As;
  float* sdd = sda + 256;
  #pragma unroll
  for (int mt=0;mt<4;mt++)
    #pragma unroll
    for (int r=0;r<4;r++){
      float s = qredsum(ps[mt][r]);
      float d = qredsum(pd[mt][r]);
      if (l15 == 0){
        int row = mt*16 + quad*4 + r;
        sda[wave*64 + row] = s;
        sdd[wave*64 + row] = d;
      }
    }
  __syncthreads();
  if (tid < 64){
    int grow = row0 + tid;
    if (grow < NN){
      asrc[grow] = sda[tid] + sda[64+tid] + sda[128+tid] + sda[192+tid];
      adst[grow] = sdd[tid] + sdd[64+tid] + sdd[128+tid] + sdd[192+tid];
    }
  }
}

// ---------------- GAT (r16: fused BN1 partial stats; 2-way unrolled gather) ----------------
__global__ __launch_bounds__(256) void k_gat(const float* __restrict__ h_, const float* __restrict__ asrc_,
     const float* __restrict__ adst_, const int* __restrict__ rowptr_, const int* __restrict__ adj_,
     const float* __restrict__ biasA, const float* __restrict__ biasB, float* __restrict__ out_,
     float* __restrict__ gpart_){
  int br = blockIdx.y;
  const float* h = h_ + (size_t)br*NN*HH;
  const float* asrc = asrc_ + (size_t)br*NN;
  const float* adst = adst_ + (size_t)br*NN;
  const int* rowptr = rowptr_ + (size_t)br*RPN;
  const int* adj = adj_ + (size_t)br*NE;
  const float* bias = br ? biasB : biasA;
  float* out = out_ + (size_t)br*NN*HH;
  float* gpart = gpart_ + (size_t)br*PCOPIES*512;

  __shared__ float smst[4*512];

  int wid = threadIdx.x>>6;
  int node = blockIdx.x*4 + wid;
  int lane = threadIdx.x & 63;
  int rs = rowptr[node], re = rowptr[node+1];
  int deg = re - rs;
  float adsti = adst[node];
  float eself = leaky02(asrc[node] + adsti);
  int c0 = lane*4;
  float4 acc;
  float4 bv = *((const float4*)&bias[c0]);
  if (deg <= 64){
    bool act = lane < deg;
    int sv = 0; float asv = 0.f;
    if (act){ sv = adj[rs + lane]; asv = asrc[sv]; }
    float e_l = act ? leaky02(asv + adsti) : -INFINITY;
    float m = fmaxf(eself, wredmax(e_l));
    float ex = act ? expf(e_l - m) : 0.f;
    float es = expf(eself - m);
    float denom = wredsum(ex) + es + 1e-16f;
    float aself = es/denom;
    float av = ex/denom;
    float4 hv = *((const float4*)&h[(size_t)node*HH + c0]);
    acc = make_float4(hv.x*aself, hv.y*aself, hv.z*aself, hv.w*aself);
    float4 acc2 = make_float4(-INFINITY,-INFINITY,-INFINITY,-INFINITY);
    int jj = 0;
    for (; jj+1 < deg; jj += 2){
      int sb0 = __shfl(sv, jj, 64);
      int sb1 = __shfl(sv, jj+1, 64);
      float ab0 = __shfl(av, jj, 64);
      float ab1 = __shfl(av, jj+1, 64);
      float4 q0 = *((const float4*)&h[(size_t)sb0*HH + c0]);
      float4 q1 = *((const float4*)&h[(size_t)sb1*HH + c0]);
      acc  = fmax4(acc,  make_float4(q0.x*ab0, q0.y*ab0, q0.z*ab0, q0.w*ab0));
      acc2 = fmax4(acc2, make_float4(q1.x*ab1, q1.y*ab1, q1.z*ab1, q1.w*ab1));
    }
    if (jj < deg){
      int sb = __shfl(sv, jj, 64);
      float ab = __shfl(av, jj, 64);
      float4 q = *((const float4*)&h[(size_t)sb*HH + c0]);
      acc = fmax4(acc, make_float4(q.x*ab, q.y*ab, q.z*ab, q.w*ab));
    }
    acc = fmax4(acc, acc2);
  } else {
    float m = eself;
    for (int j = rs + lane; j < re; j += 64) m = fmaxf(m, leaky02(asrc[adj[j]] + adsti));
    m = wredmax(m);
    float ssum = 0.f;
    for (int j = rs + lane; j < re; j += 64) ssum += expf(leaky02(asrc[adj[j]] + adsti) - m);
    ssum = wredsum(ssum) + expf(eself - m);
    float denom = ssum + 1e-16f;
    float aself = expf(eself - m)/denom;
    float4 hv = *((const float4*)&h[(size_t)node*HH + c0]);
    acc = make_float4(hv.x*aself, hv.y*aself, hv.z*aself, hv.w*aself);
    float4 acc2 = make_float4(-INFINITY,-INFINITY,-INFINITY,-INFINITY);
    for (int jb = rs; jb < re; jb += 64){
      int cnt = min(64, re - jb);
      int sv = 0; float av = 0.f;
      if (lane < cnt){ sv = adj[jb+lane]; av = expf(leaky02(asrc[sv] + adsti) - m)/denom; }
      int jj = 0;
      for (; jj+1 < cnt; jj += 2){
        int sb0 = __shfl(sv, jj, 64);
        int sb1 = __shfl(sv, jj+1, 64);
        float ab0 = __shfl(av, jj, 64);
        float ab1 = __shfl(av, jj+1, 64);
        float4 q0 = *((const float4*)&h[(size_t)sb0*HH + c0]);
        float4 q1 = *((const float4*)&h[(size_t)sb1*HH + c0]);
        acc  = fmax4(acc,  make_float4(q0.x*ab0, q0.y*ab0, q0.z*ab0, q0.w*ab0));
        acc2 = fmax4(acc2, make_float4(q1.x*ab1, q1.y*ab1, q1.z*ab1, q1.w*ab1));
      }
      if (jj < cnt){
        int sb = __shfl(sv, jj, 64);
        float ab = __shfl(av, jj, 64);
        float4 q = *((const float4*)&h[(size_t)sb*HH + c0]);
        acc = fmax4(acc, make_float4(q.x*ab, q.y*ab, q.z*ab, q.w*ab));
      }
    }
    acc = fmax4(acc, acc2);
  }
  acc.x += bv.x; acc.y += bv.y; acc.z += bv.z; acc.w += bv.w;
  *((float4*)&out[(size_t)node*HH + c0]) = acc;

  // fused BN1 partial statistics (value + square per channel, 4 nodes/block)
  float* my = &smst[wid*512];
  my[c0+0] = acc.x; my[c0+1] = acc.y; my[c0+2] = acc.z; my[c0+3] = acc.w;
  my[256+c0+0] = acc.x*acc.x; my[256+c0+1] = acc.y*acc.y;
  my[256+c0+2] = acc.z*acc.z; my[256+c0+3] = acc.w*acc.w;
  __syncthreads();
  int t = threadIdx.x;   // 0..255: channel t
  float p0 = smst[t]     + smst[512+t]     + smst[1024+t]     + smst[1536+t];
  float p1 = smst[256+t] + smst[512+256+t] + smst[1024+256+t] + smst[1536+256+t];
  int copy = blockIdx.x & (PCOPIES-1);
  atomicAdd(&gpart[copy*512 + t], p0);
  atomicAdd(&gpart[copy*512 + 256 + t], p1);
}

// ---------------- BN finalize from gat partials (BN1) ----------------
__global__ __launch_bounds__(256) void k_bnfinP(const float* __restrict__ gpart_,
    const float* __restrict__ gA, const float* __restrict__ gB,
    const float* __restrict__ bA, const float* __restrict__ bB,
    float* __restrict__ scale_, float* __restrict__ shift_){
  int br = blockIdx.y;
  const float* gp = gpart_ + (size_t)br*PCOPIES*512;
  const float* g = br ? gB : gA;
  const float* b = br ? bB : bA;
  float* scale = scale_ + (size_t)br*HH;
  float* shift = shift_ + (size_t)br*HH;
  int c = threadIdx.x;
  float s = 0.f, q = 0.f;
  #pragma unroll 8
  for (int p=0;p<PCOPIES;p++){ s += gp[p*512 + c]; q += gp[p*512 + 256 + c]; }
  float mean = s/(float)NN;
  float var = q/(float)NN - mean*mean;
  float rstd = rsqrtf(var + 1e-5f);
  float sc = g[c]*rstd;
  scale[c] = sc; shift[c] = b[c] - mean*sc;
}

// ---------------- BN finalize from sums (BN2) ----------------
__global__ __launch_bounds__(256) void k_bnfin(const float* __restrict__ sums_,
    const float* __restrict__ gA, const float* __restrict__ gB,
    const float* __restrict__ bA, const float* __restrict__ bB,
    float* __restrict__ scale_, float* __restrict__ shift_){
  int br = blockIdx.y;
  const float* sums = sums_ + (size_t)br*2*HH;
  const float* sumsq = sums + HH;
  const float* g = br ? gB : gA;
  const float* b = br ? bB : bA;
  float* scale = scale_ + (size_t)br*HH;
  float* shift = shift_ + (size_t)br*HH;
  int c = threadIdx.x;
  float mean = sums[c]/(float)NN;
  float var = sumsq[c]/(float)NN - mean*mean;
  float rstd = rsqrtf(var + 1e-5f);
  float sc = g[c]*rstd;
  scale[c] = sc; shift[c] = b[c] - mean*sc;
}

// ---------------- SAGE max-aggregate (2-way unrolled gather) ----------------
__global__ __launch_bounds__(256) void k_sageagg(const float* __restrict__ xin_, const float* __restrict__ scale_,
    const float* __restrict__ shift_, const float* __restrict__ pA, const float* __restrict__ pB,
    const int* __restrict__ rowptr_, const int* __restrict__ adj_, float* __restrict__ agg_){
  int br = blockIdx.y;
  const float* xin = xin_ + (size_t)br*NN*HH;
  const float* scale = scale_ + (size_t)br*HH;
  const float* shift = shift_ + (size_t)br*HH;
  const float* prelu = br ? pB : pA;
  const int* rowptr = rowptr_ + (size_t)br*RPN;
  const int* adj = adj_ + (size_t)br*NE;
  float* agg = agg_ + (size_t)br*NN*HH;

  int node = blockIdx.x*4 + (threadIdx.x>>6);
  int lane = threadIdx.x & 63;
  int rs = rowptr[node], re = rowptr[node+1];
  int c0 = lane*4;
  float slope = prelu[0];
  float4 sc = *((const float4*)&scale[c0]);
  float4 sh = *((const float4*)&shift[c0]);
  float4 acc  = make_float4(-INFINITY,-INFINITY,-INFINITY,-INFINITY);
  float4 acc2 = make_float4(-INFINITY,-INFINITY,-INFINITY,-INFINITY);
  for (int jb = rs; jb < re; jb += 64){
    int cnt = min(64, re - jb);
    int sv = (lane < cnt) ? adj[jb+lane] : 0;
    int jj = 0;
    for (; jj+1 < cnt; jj += 2){
      int sb0 = __shfl(sv, jj, 64);
      int sb1 = __shfl(sv, jj+1, 64);
      float4 q0 = *((const float4*)&xin[(size_t)sb0*HH + c0]);
      float4 q1 = *((const float4*)&xin[(size_t)sb1*HH + c0]);
      acc  = fmax4(acc,  bnprelu4(q0, sc, sh, slope));
      acc2 = fmax4(acc2, bnprelu4(q1, sc, sh, slope));
    }
    if (jj < cnt){
      int sb = __shfl(sv, jj, 64);
      float4 q = *((const float4*)&xin[(size_t)sb*HH + c0]);
      acc = fmax4(acc, bnprelu4(q, sc, sh, slope));
    }
  }
  acc = fmax4(acc, acc2);
  if (re == rs) acc = make_float4(0.f,0.f,0.f,0.f);
  *((float4*)&agg[(size_t)node*HH + c0]) = acc;
}

// ---------------- GEMM2 (r13-verified: M=64 x N=256, 512 thr / 8 waves, wave 64x32) ----------------
__global__ __launch_bounds__(512, 4) void k_gemm2(const float* __restrict__ graw_, const float* __restrict__ agg_,
    const u16* __restrict__ WtT_,
    const float* __restrict__ scale1_, const float* __restrict__ shift1_,
    const float* __restrict__ p1A, const float* __restrict__ p1B,
    const float* __restrict__ blA, const float* __restrict__ blB,
    float* __restrict__ out_, float* __restrict__ sums_){
  int br = blockIdx.y;
  const float* graw = graw_ + (size_t)br*NN*HH;
  const float* agg = agg_ + (size_t)br*NN*HH;
  const u16* WtT = WtT_ + (size_t)br*16*16384;
  const float* scale1 = scale1_ + (size_t)br*HH;
  const float* shift1 = shift1_ + (size_t)br*HH;
  const float* prelu1 = br ? p1B : p1A;
  const float* bl = br ? blB : blA;
  float* out = out_ + (size_t)br*NN*HH;
  float* sums = sums_ + (size_t)br*2*HH;
  float* sumsq = sums + HH;

  __shared__ u16 As[2][8*ASTRIDE];
  int tid = threadIdx.x;
  int row0 = blockIdx.x*64;
  int wave = tid>>6, lane = tid&63;
  int l15 = lane&15, quad = lane>>4;
  int col0 = wave*32;
  int sm_ = tid >> 3, sg = tid & 7;   // 8 threads per row, 4 floats each
  int sgrow = row0 + sm_; if (sgrow >= NN) sgrow = NN-1;
  float slope = prelu1[0];
  f32x4 acc[4][2];
  #pragma unroll
  for (int mt=0;mt<4;mt++)
    #pragma unroll
    for (int nt=0;nt<2;nt++){ f32x4 z = {0.f,0.f,0.f,0.f}; acc[mt][nt] = z; }

  const u16* bbase = WtT + ((size_t)quad<<12) + (size_t)(col0 + l15)*8;
  bf16x8 B0h[2],B0l[2],B1h[2],B1l[2];
  float4 vaA, vaB;

  auto loadA = [&](int kc, float4& dst){
    const float* ab = (kc < HH) ? graw : agg;
    int ac = (kc < HH) ? kc : kc - HH;
    dst = *((const float4*)(ab + (size_t)sgrow*HH + ac + sg*4));
  };
  auto writeA = [&](int kc, int wb, float4 v){
    if (kc < HH){
      int kcol = kc + sg*4;
      v = bnprelu4(v, *((const float4*)(scale1+kcol)), *((const float4*)(shift1+kcol)), slope);
    }
    bf16x4 h, l;
    split4(v, h, l);
    int cell = (sg>>1)*ASTRIDE + sm_*8 + (sg&1)*4;
    *((bf16x4*)&As[wb][cell]) = h;
    *((bf16x4*)&As[wb][cell + 4*ASTRIDE]) = l;
  };
  auto loadB = [&](int ck, bf16x8 (&Bh)[2], bf16x8 (&Bl)[2]){
    const u16* bb = bbase + ((size_t)ck<<14);
    #pragma unroll
    for (int nt=0;nt<2;nt++){
      Bh[nt] = *((const bf16x8*)(bb + nt*128));
      Bl[nt] = *((const bf16x8*)(bb + 2048 + nt*128));
    }
  };
  auto body = [&](int k, int rb, float4& vaW, float4& vaL, bf16x8 (&Bh)[2], bf16x8 (&Bl)[2], bf16x8 (&nBh)[2], bf16x8 (&nBl)[2]){
    softBarrier();
    if (k < 15) writeA((k+1)*32, rb^1, vaW);
    if (k < 13) loadA((k+3)*32, vaW);
    if (k < 15) loadB(k+1, nBh, nBl);
    (void)vaL;
    #pragma unroll
    for (int mt=0;mt<4;mt++){
      int m = mt*16 + l15;
      bf16x8 ah = *((bf16x8*)&As[rb][quad*ASTRIDE + m*8]);
      bf16x8 al = *((bf16x8*)&As[rb][(4+quad)*ASTRIDE + m*8]);
      #pragma unroll
      for (int nt=0;nt<2;nt++){
        acc[mt][nt] = __builtin_amdgcn_mfma_f32_16x16x32_bf16(ah, Bh[nt], acc[mt][nt], 0, 0, 0);
        acc[mt][nt] = __builtin_amdgcn_mfma_f32_16x16x32_bf16(al, Bh[nt], acc[mt][nt], 0, 0, 0);
        acc[mt][nt] = __builtin_amdgcn_mfma_f32_16x16x32_bf16(ah, Bl[nt], acc[mt][nt], 0, 0, 0);
      }
    }
  };

  loadA(0, vaA);
  writeA(0, 0, vaA);
  loadA(32, vaA);
  loadA(64, vaB);
  loadB(0, B0h, B0l);
  #pragma unroll 1
  for (int k=0; k<16; k+=2){
    body(k,   0, vaA, vaB, B0h,B0l, B1h,B1l);
    body(k+1, 1, vaB, vaA, B1h,B1l, B0h,B0l);
  }

  float psum[2], psq[2];
  #pragma unroll
  for (int nt=0;nt<2;nt++){
    int c = col0 + nt*16 + l15;
    float bcol = bl[c];
    float s=0.f, q=0.f;
    #pragma unroll
    for (int mt=0;mt<4;mt++){
      int gbase = row0 + mt*16 + quad*4;
      #pragma unroll
      for (int r=0;r<4;r++){
        int grow = gbase + r;
        float v = acc[mt][nt][r] + bcol;
        if (grow < NN){
          out[(size_t)grow*HH + c] = v;
          s += v; q += v*v;
        }
      }
    }
    psum[nt]=s; psq[nt]=q;
  }
  __syncthreads();
  float* sm2 = (float*)As;
  sm2[tid] = 0.f;
  __syncthreads();
  #pragma unroll
  for (int nt=0;nt<2;nt++){
    int c = col0 + nt*16 + l15;
    atomicAdd(&sm2[c], psum[nt]);
    atomicAdd(&sm2[256+c], psq[nt]);
  }
  __syncthreads();
  if (tid < 256){
    atomicAdd(&sums[tid],  sm2[tid]);
    atomicAdd(&sumsq[tid], sm2[256+tid]);
  }
}

// ---------------- pool GEMVs ----------------
__global__ __launch_bounds__(256) void k_gemv2(const float* __restrict__ x2_, const float* __restrict__ scale2_,
    const float* __restrict__ shift2_, const float* __restrict__ p2A, const float* __restrict__ p2B,
    const float* __restrict__ WrelA, const float* __restrict__ WrelB,
    const float* __restrict__ WrootA, const float* __restrict__ WrootB,
    float* __restrict__ y2_, float* __restrict__ y2r_){
  int br = blockIdx.y;
  const float* x2raw = x2_ + (size_t)br*NN*HH;
  const float* scale2 = scale2_ + (size_t)br*HH;
  const float* shift2 = shift2_ + (size_t)br*HH;
  const float* prelu2 = br ? p2B : p2A;
  const float* Wrel = br ? WrelB : WrelA;
  const float* Wroot = br ? WrootB : WrootA;
  float* y2 = y2_ + (size_t)br*NN;
  float* y2r = y2r_ + (size_t)br*NN;

  int node = blockIdx.x*4 + (threadIdx.x>>6);
  int lane = threadIdx.x & 63;
  int c0 = lane*4;
  float slope = prelu2[0];
  float4 v = *((const float4*)&x2raw[(size_t)node*HH + c0]);
  float4 sc = *((const float4*)&scale2[c0]);
  float4 sh = *((const float4*)&shift2[c0]);
  v = bnprelu4(v, sc, sh, slope);
  float4 wr = *((const float4*)&Wrel[c0]);
  float4 wo = *((const float4*)&Wroot[c0]);
  float pr = v.x*wr.x + v.y*wr.y + v.z*wr.z + v.w*wr.w;
  float po = v.x*wo.x + v.y*wo.y + v.z*wo.z + v.w*wo.w;
  pr = wredsum(pr); po = wredsum(po);
  if (lane==0){ y2[node] = pr; y2r[node] = po; }
}

// k_score with fused hist1
__global__ void k_score(const int* __restrict__ rowptr_, const int* __restrict__ adj_, const float* __restrict__ y2_,
    const float* __restrict__ y2r_, const float* __restrict__ brelA, const float* __restrict__ brelB,
    float* __restrict__ score_, unsigned* __restrict__ keys_, unsigned* __restrict__ hist_){
  int br = blockIdx.y;
  const int* rowptr = rowptr_ + (size_t)br*RPN;
  const int* adj = adj_ + (size_t)br*NE;
  const float* y2 = y2_ + (size_t)br*NN;
  const float* y2r = y2r_ + (size_t)br*NN;
  const float* brel = br ? brelB : brelA;
  float* score = score_ + (size_t)br*NN;
  unsigned* keys = keys_ + (size_t)br*NN;
  unsigned* hist = hist_ + (size_t)br*65536;

  int i = blockIdx.x*blockDim.x + threadIdx.x;
  if (i >= NN) return;
  float s = 0.f;
  int rs = rowptr[i], re = rowptr[i+1];
  for (int j=rs;j<re;j++) s += y2[adj[j]];
  float sc = s + brel[0] + y2r[i];
  score[i] = sc;
  unsigned u = __float_as_uint(sc);
  u = (u & 0x80000000u) ? ~u : (u | 0x80000000u);
  keys[i] = u;
  atomicAdd(&hist[u>>16], 1u);
}

// parallel suffix-scan findbin: uint4 coarse sums + log-step scans
__global__ __launch_bounds__(256) void k_findbin1(const unsigned* __restrict__ hist_, unsigned* __restrict__ scal_){
  int br = blockIdx.y;
  const unsigned* hist = hist_ + (size_t)br*65536;
  unsigned* scal = scal_ + (size_t)br*16;
  __shared__ unsigned suf[256];
  __shared__ unsigned shc[2];
  int t = threadIdx.x;
  const uint4* h4 = (const uint4*)(hist + t*256);
  unsigned s = 0;
  #pragma unroll 8
  for (int b=0;b<64;b++){ uint4 v = h4[b]; s += v.x+v.y+v.z+v.w; }
  suf[t] = s; __syncthreads();
  #pragma unroll
  for (int o=1;o<256;o<<=1){
    unsigned add = (t+o<256)? suf[t+o] : 0u;
    __syncthreads();
    suf[t] += add;
    __syncthreads();
  }
  unsigned ab = suf[t] - s;
  if (ab < (unsigned)KT && ab + s >= (unsigned)KT){ shc[0] = (unsigned)t; shc[1] = ab; }
  __syncthreads();
  int cb = (int)shc[0]; unsigned runbase = shc[1];
  unsigned f = hist[cb*256 + t];
  suf[t] = f; __syncthreads();
  #pragma unroll
  for (int o=1;o<256;o<<=1){
    unsigned add = (t+o<256)? suf[t+o] : 0u;
    __syncthreads();
    suf[t] += add;
    __syncthreads();
  }
  unsigned ta = runbase + suf[t] - f;
  if (ta < (unsigned)KT && ta + f >= (unsigned)KT){
    scal[0] = (unsigned)(cb*256 + t);
    scal[1] = ta;
  }
}

__global__ void k_hist2(const unsigned* __restrict__ keys_, const unsigned* __restrict__ scal_, unsigned* __restrict__ hist_){
  int br = blockIdx.y;
  const unsigned* keys = keys_ + (size_t)br*NN;
  const unsigned* scal = scal_ + (size_t)br*16;
  unsigned* hist = hist_ + (size_t)br*65536;
  int i = blockIdx.x*blockDim.x + threadIdx.x;
  if (i < NN){ unsigned k = keys[i]; if ((k>>16) == scal[0]) atomicAdd(&hist[k & 0xFFFFu], 1u); }
}

__global__ __launch_bounds__(256) void k_findbin2(const unsigned* __restrict__ hist_, unsigned* __restrict__ scal_){
  int br = blockIdx.y;
  const unsigned* hist = hist_ + (size_t)br*65536;
  unsigned* scal = scal_ + (size_t)br*16;
  __shared__ unsigned suf[256];
  __shared__ unsigned shc[2];
  int t = threadIdx.x;
  unsigned target = (unsigned)KT - scal[1];
  const uint4* h4 = (const uint4*)(hist + t*256);
  unsigned s = 0;
  #pragma unroll 8
  for (int b=0;b<64;b++){ uint4 v = h4[b]; s += v.x+v.y+v.z+v.w; }
  suf[t] = s; __syncthreads();
  #pragma unroll
  for (int o=1;o<256;o<<=1){
    unsigned add = (t+o<256)? suf[t+o] : 0u;
    __syncthreads();
    suf[t] += add;
    __syncthreads();
  }
  unsigned ab = suf[t] - s;
  if (ab < target && ab + s >= target){ shc[0] = (unsigned)t; shc[1] = ab; }
  __syncthreads();
  int cb = (int)shc[0]; unsigned runbase = shc[1];
  unsigned f = hist[cb*256 + t];
  suf[t] = f; __syncthreads();
  #pragma unroll
  for (int o=1;o<256;o<<=1){
    unsigned add = (t+o<256)? suf[t+o] : 0u;
    __syncthreads();
    suf[t] += add;
    __syncthreads();
  }
  unsigned ta = runbase + suf[t] - f;
  if (ta < target && ta + f >= target){
    scal[2] = (scal[0] << 16) | (unsigned)(cb*256 + t);
    scal[3] = target - ta;
    scal[4] = f;
  }
}

__global__ void k_select(const unsigned* __restrict__ keys_, const float* __restrict__ score_,
    unsigned* __restrict__ scal_, int* __restrict__ selidx_, float* __restrict__ tvals_){
  int br = blockIdx.y;
  const unsigned* keys = keys_ + (size_t)br*NN;
  const float* score = score_ + (size_t)br*NN;
  unsigned* scal = scal_ + (size_t)br*16;
  int* selidx = selidx_ + (size_t)br*NN;
  float* tvals = tvals_ + (size_t)br*NN;

  int i = blockIdx.x*blockDim.x + threadIdx.x;
  if (i >= NN) return;
  unsigned T = scal[2], needed = scal[3], cnteq = scal[4];
  unsigned k = keys[i];
  int s = 0;
  if (k > T) s = 1;
  else if (k == T){
    if (cnteq <= needed) s = 1;
    else {
      unsigned rank = 0;
      for (int j=0;j<i;j++) rank += (keys[j] == T) ? 1u : 0u;
      s = (rank < needed) ? 1 : 0;
    }
  }
  if (s){
    unsigned idx = atomicAdd(&scal[8], 1u);
    selidx[idx] = i;
    tvals[idx] = tanhf(score[i]);
  }
}

__global__ __launch_bounds__(256) void k_embed(const float* __restrict__ x2_, const float* __restrict__ scale2_,
    const float* __restrict__ shift2_, const float* __restrict__ p2A, const float* __restrict__ p2B,
    const int* __restrict__ selidx_, const float* __restrict__ tvals_, float* __restrict__ embed){
  int br = blockIdx.y;
  const float* x2raw = x2_ + (size_t)br*NN*HH;
  const float* scale2 = scale2_ + (size_t)br*HH;
  const float* shift2 = shift2_ + (size_t)br*HH;
  const float* prelu2 = br ? p2B : p2A;
  const int* selidx = selidx_ + (size_t)br*NN;
  const float* tvals = tvals_ + (size_t)br*NN;

  int c = threadIdx.x;
  float slope = prelu2[0];
  float scv = scale2[c], shv = shift2[c];
  float best = -INFINITY;
  for (int j = blockIdx.x; j < KT; j += gridDim.x){
    int r = selidx[j];
    float v = x2raw[(size_t)r*HH + c]*scv + shv;
    v = preluf(v, slope);
    best = fmaxf(best, v*tvals[j]);
  }
  atomicMaxF(&embed[(size_t)br*HH + c], best);
}

__global__ void k_initembed(float* __restrict__ embed){
  int i = threadIdx.x;
  if (i < 2*HH) embed[i] = -INFINITY;
}

// ---------------- head ----------------
__global__ __launch_bounds__(256) void k_head(const float* __restrict__ embed, const float* __restrict__ addf,
    const float* __restrict__ fc1W, const float* __restrict__ fc1b, const float* __restrict__ preluh,
    const float* __restrict__ fc2W, const float* __restrict__ fc2b, float* __restrict__ out){
  __shared__ float z[2*HH + 8];
  __shared__ float h1s[HH];
  __shared__ float red[4];
  int t = threadIdx.x;
  for (int i=t;i<2*HH;i+=256) z[i] = embed[i];
  if (t < 8) z[2*HH + t] = addf[t];
  __syncthreads();
  float acc = fc1b[t];
  for (int k=0;k<2*HH+8;k++) acc += z[k]*fc1W[(size_t)k*HH + t];
  float slope = preluh[0];
  h1s[t] = preluf(acc, slope);
  __syncthreads();
  float p = h1s[t]*fc2W[t];
  p = wredsum(p);
  if ((t & 63) == 0) red[t>>6] = p;
  __syncthreads();
  if (t == 0) out[0] = expf(red[0]+red[1]+red[2]+red[3] + fc2b[0]);
}

// ---------------- orchestration ----------------
extern "C" void kernel_launch(void* const* d_in, const int* in_sizes, int n_in,
                              void* d_out, int out_size, void* d_ws, size_t ws_size,
                              hipStream_t stream) {
  (void)in_sizes; (void)n_in; (void)out_size;
  char* ws = (char*)d_ws;

  float *bufA, *bufB, *asrc, *adst, *sums, *scale1, *shift1, *scale2, *shift2;
  float *y2, *y2r, *score, *tvals, *embed, *gpart;
  int *rowptr, *adj, *cursor, *bsums, *selidx;
  unsigned *keys, *hist1, *hist2, *scal;
  u16 *WtT, *WtT1;

  auto doAlloc = [&](int nb)->size_t{
    size_t o = 0;
    auto al = [&](size_t bytes)->char*{ char* p = ws + o; o = (o + bytes + 255) & ~(size_t)255; return p; };
    bufA   = (float*)al((size_t)nb*NN*HH*4);
    bufB   = (float*)al((size_t)nb*NN*HH*4);
    asrc   = (float*)al((size_t)nb*NN*4);
    adst   = (float*)al((size_t)nb*NN*4);
    rowptr = (int*)  al((size_t)nb*RPN*4);
    adj    = (int*)  al((size_t)nb*NE*4);
    cursor = (int*)  al((size_t)nb*NN*4);
    bsums  = (int*)  al((size_t)nb*128*4);
    sums   = (float*)al((size_t)nb*2*HH*4);
    gpart  = (float*)al((size_t)nb*PCOPIES*512*4);
    scale1 = (float*)al((size_t)nb*HH*4);
    shift1 = (float*)al((size_t)nb*HH*4);
    scale2 = (float*)al((size_t)nb*HH*4);
    shift2 = (float*)al((size_t)nb*HH*4);
    y2     = (float*)al((size_t)nb*NN*4);
    y2r    = (float*)al((size_t)nb*NN*4);
    score  = (float*)al((size_t)nb*NN*4);
    keys   = (unsigned*)al((size_t)nb*NN*4);
    selidx = (int*)  al((size_t)nb*NN*4);
    tvals  = (float*)al((size_t)nb*NN*4);
    hist1  = (unsigned*)al((size_t)nb*65536*4);
    hist2  = (unsigned*)al((size_t)nb*65536*4);
    scal   = (unsigned*)al((size_t)nb*64);
    embed  = (float*)al((size_t)2*HH*4);
    WtT    = (u16*)al((size_t)nb*16*16384*2);
    WtT1   = (u16*)al((size_t)nb*2*16384*2);
    return o;
  };

  int NB = 2;
  if (doAlloc(2) > ws_size) NB = 1;
  doAlloc(NB);

  const float* addf = (const float*)d_in[2];

  k_initembed<<<dim3(1), dim3(512), 0, stream>>>(embed);

  int nIter = (NB==2) ? 1 : 2;
  for (int it = 0; it < nIter; ++it){
    const float *xA, *xB; const int *eiA, *eiB; int pa, pb;
    if (NB == 2){
      xA = (const float*)d_in[0]; xB = (const float*)d_in[1];
      eiA = (const int*)d_in[3]; eiB = (const int*)d_in[4];
      pa = 5; pb = 21;
    } else {
      xA = xB = (const float*)d_in[it];
      eiA = eiB = (const int*)d_in[3+it];
      pa = pb = (it==0) ? 5 : 21;
    }
    auto PA = [&](int i){ return (const float*)d_in[pa+i]; };
    auto PB = [&](int i){ return (const float*)d_in[pb+i]; };

    // CSR by dst (both branches)
    hipMemsetAsync(cursor, 0, (size_t)NB*NN*4, stream);
    hipMemsetAsync(gpart, 0, (size_t)NB*PCOPIES*512*4, stream);
    k_count<<<dim3((NE+255)/256, NB), dim3(256), 0, stream>>>(eiA, eiB, cursor);
    k_scan1<<<dim3(98, NB), dim3(1024), 0, stream>>>(cursor, rowptr, bsums);
    k_scan2<<<dim3(1, NB), dim3(128), 0, stream>>>(bsums, 98);
    k_scan3<<<dim3(98, NB), dim3(1024), 0, stream>>>(rowptr, bsums, cursor);
    k_scatter<<<dim3((NE+255)/256, NB), dim3(256), 0, stream>>>(eiA, eiB, cursor, adj);

    // W pre-splits (merged)
    k_splitWall<<<dim3(576, NB), dim3(256), 0, stream>>>(PA(9), PB(9), PA(7), PB(7), PA(0), PB(0), WtT, WtT1);

    // GAT (BN1 stats fused into k_gat -> gpart partials)
    k_gemm1<<<dim3((NN+63)/64, NB), dim3(256), 0, stream>>>(xA, xB, WtT1,
        PA(1), PB(1), PA(2), PB(2), bufA, asrc, adst);
    k_gat<<<dim3(25000, NB), dim3(256), 0, stream>>>(bufA, asrc, adst, rowptr, adj, PA(3), PB(3), bufB, gpart);

    // BN1 finalize from partials
    k_bnfinP<<<dim3(1, NB), dim3(256), 0, stream>>>(gpart, PA(4), PB(4), PA(5), PB(5), scale1, shift1);

    // SAGE
    k_sageagg<<<dim3(25000, NB), dim3(256), 0, stream>>>(bufB, scale1, shift1, PA(6), PB(6), rowptr, adj, bufA);
    hipMemsetAsync(sums, 0, (size_t)NB*2*HH*4, stream);
    k_gemm2<<<dim3((NN+63)/64, NB), dim3(512), 0, stream>>>(bufB, bufA, WtT,
        scale1, shift1, PA(6), PB(6), PA(8), PB(8), bufB, sums);
    k_bnfin<<<dim3(1, NB), dim3(256), 0, stream>>>(sums, PA(10), PB(10), PA(11), PB(11), scale2, shift2);

    // SAGPool (hist1 fused into k_score; memsets hoisted)
    hipMemsetAsync(scal, 0, (size_t)NB*64, stream);
    hipMemsetAsync(hist1, 0, (size_t)NB*65536*4, stream);
    hipMemsetAsync(hist2, 0, (size_t)NB*65536*4, stream);
    k_gemv2<<<dim3(25000, NB), dim3(256), 0, stream>>>(bufB, scale2, shift2, PA(12), PB(12),
        PA(13), PB(13), PA(15), PB(15), y2, y2r);
    k_score<<<dim3((NN+255)/256, NB), dim3(256), 0, stream>>>(rowptr, adj, y2, y2r, PA(14), PB(14), score, keys, hist1);
    k_findbin1<<<dim3(1, NB), dim3(256), 0, stream>>>(hist1, scal);
    k_hist2<<<dim3((NN+255)/256, NB), dim3(256), 0, stream>>>(keys, scal, hist2);
    k_findbin2<<<dim3(1, NB), dim3(256), 0, stream>>>(hist2, scal);
    k_select<<<dim3((NN+255)/256, NB), dim3(256), 0, stream>>>(keys, score, scal, selidx, tvals);
    float* embDst = (NB==2) ? embed : (embed + it*HH);
    k_embed<<<dim3(256, NB), dim3(256), 0, stream>>>(bufB, scale2, shift2, PA(12), PB(12), selidx, tvals, embDst);
  }

  k_head<<<dim3(1), dim3(256), 0, stream>>>(embed, addf,
      (const float*)d_in[37], (const float*)d_in[38], (const float*)d_in[39],
      (const float*)d_in[40], (const float*)d_in[41], (float*)d_out);
}

// Round 9
// 1307.657 us; speedup vs baseline: 1.1617x; 1.0591x over previous
//
#include <hip/hip_runtime.h>
#include <math.h>

#define NN 100000
#define NE 400000
#define FI 64
#define HH 256
#define KT 50000
#define RPN (NN+1)
#define PCOPIES 64

typedef unsigned short u16;
typedef __attribute__((ext_vector_type(8))) short bf16x8;
typedef __attribute__((ext_vector_type(4))) short bf16x4;
typedef __attribute__((ext_vector_type(4))) float f32x4;

__device__ __forceinline__ float leaky02(float x){ return x >= 0.f ? x : 0.2f*x; }
__device__ __forceinline__ float preluf(float x, float a){ return x >= 0.f ? x : a*x; }

__device__ __forceinline__ float wredmax(float v){
  #pragma unroll
  for (int o=32;o>0;o>>=1) v = fmaxf(v, __shfl_xor(v, o, 64));
  return v;
}
__device__ __forceinline__ float wredsum(float v){
  #pragma unroll
  for (int o=32;o>0;o>>=1) v += __shfl_xor(v, o, 64);
  return v;
}
__device__ __forceinline__ float qredsum(float v){
  #pragma unroll
  for (int o=8;o>0;o>>=1) v += __shfl_xor(v, o, 64);
  return v;
}

// barrier that does NOT drain vmcnt (keeps prefetch loads in flight)
__device__ __forceinline__ void softBarrier(){
  asm volatile("s_waitcnt lgkmcnt(0)" ::: "memory");
  __builtin_amdgcn_s_barrier();
}

__device__ __forceinline__ void atomicMaxF(float* a, float v){
  if (v >= 0.f) atomicMax((int*)a, __float_as_int(v));
  else atomicMin((unsigned int*)a, __float_as_uint(v));
}

__device__ __forceinline__ float4 bnprelu4(float4 v, float4 sc, float4 sh, float a){
  float4 r;
  r.x = preluf(v.x*sc.x+sh.x, a);
  r.y = preluf(v.y*sc.y+sh.y, a);
  r.z = preluf(v.z*sc.z+sh.z, a);
  r.w = preluf(v.w*sc.w+sh.w, a);
  return r;
}

__device__ __forceinline__ float4 fmax4(float4 a, float4 b){
  return make_float4(fmaxf(a.x,b.x), fmaxf(a.y,b.y), fmaxf(a.z,b.z), fmaxf(a.w,b.w));
}

__device__ __forceinline__ u16 f2bf(float f){
  unsigned u = __float_as_uint(f);
  unsigned r = u + 0x7FFFu + ((u>>16)&1u);
  return (u16)(r>>16);
}
__device__ __forceinline__ float bf2f(u16 h){
  return __uint_as_float(((unsigned)h)<<16);
}
__device__ __forceinline__ void split8(float4 a, float4 b, bf16x8& h, bf16x8& l){
  float va[8] = {a.x,a.y,a.z,a.w,b.x,b.y,b.z,b.w};
  #pragma unroll
  for (int j=0;j<8;j++){
    u16 hh = f2bf(va[j]);
    h[j] = (short)hh;
    l[j] = (short)f2bf(va[j] - bf2f(hh));
  }
}
__device__ __forceinline__ void split4(float4 a, bf16x4& h, bf16x4& l){
  float va[4] = {a.x,a.y,a.z,a.w};
  #pragma unroll
  for (int j=0;j<4;j++){
    u16 hh = f2bf(va[j]);
    h[j] = (short)hh;
    l[j] = (short)f2bf(va[j] - bf2f(hh));
  }
}

// ---------------- CSR build (batched over blockIdx.y) ----------------
__global__ void k_count(const int* __restrict__ eiA, const int* __restrict__ eiB, int* __restrict__ deg_){
  int br = blockIdx.y;
  const int* dst = (br ? eiB : eiA) + NE;
  int* deg = deg_ + (size_t)br*NN;
  int e = blockIdx.x*blockDim.x + threadIdx.x;
  if (e < NE) atomicAdd(&deg[dst[e]], 1);
}

__global__ __launch_bounds__(1024) void k_scan1(const int* __restrict__ deg_, int* __restrict__ rowptr_, int* __restrict__ bsums_){
  int br = blockIdx.y;
  const int* deg = deg_ + (size_t)br*NN;
  int* rowptr = rowptr_ + (size_t)br*RPN;
  int* bsums = bsums_ + (size_t)br*128;
  __shared__ int sm[1024];
  int t = threadIdx.x; int g = blockIdx.x*1024 + t;
  int v = (g < NN) ? deg[g] : 0;
  sm[t] = v; __syncthreads();
  for (int o=1;o<1024;o<<=1){
    int add = (t>=o)? sm[t-o] : 0;
    __syncthreads();
    sm[t] += add;
    __syncthreads();
  }
  if (g < NN) rowptr[g] = sm[t] - v;
  if (t == 1023) bsums[blockIdx.x] = sm[1023];
}

__global__ __launch_bounds__(128) void k_scan2(int* __restrict__ bsums_, int nblk){
  int br = blockIdx.y;
  int* bsums = bsums_ + (size_t)br*128;
  __shared__ int sm[128];
  int t = threadIdx.x;
  int v = (t < nblk) ? bsums[t] : 0;
  sm[t] = v; __syncthreads();
  for (int o=1;o<128;o<<=1){
    int add = (t>=o)? sm[t-o] : 0;
    __syncthreads();
    sm[t] += add;
    __syncthreads();
  }
  if (t < nblk) bsums[t] = sm[t] - v;
}

__global__ __launch_bounds__(1024) void k_scan3(int* __restrict__ rowptr_, const int* __restrict__ bsums_, int* __restrict__ cursor_){
  int br = blockIdx.y;
  int* rowptr = rowptr_ + (size_t)br*RPN;
  const int* bsums = bsums_ + (size_t)br*128;
  int* cursor = cursor_ + (size_t)br*NN;
  int g = blockIdx.x*1024 + threadIdx.x;
  if (g < NN){ int r = rowptr[g] + bsums[blockIdx.x]; rowptr[g] = r; cursor[g] = r; }
  if (blockIdx.x==0 && threadIdx.x==0) rowptr[NN] = NE;
}

__global__ void k_scatter(const int* __restrict__ eiA, const int* __restrict__ eiB, int* __restrict__ cursor_, int* __restrict__ adj_){
  int br = blockIdx.y;
  const int* ei = br ? eiB : eiA;
  const int* src = ei;
  const int* dst = ei + NE;
  int* cursor = cursor_ + (size_t)br*NN;
  int* adj = adj_ + (size_t)br*NE;
  int e = blockIdx.x*blockDim.x + threadIdx.x;
  if (e < NE){ int d = dst[e]; int slot = atomicAdd(&cursor[d], 1); adj[slot] = src[e]; }
}

// ---------------- W pre-split (merged big + gat W) ----------------
__global__ __launch_bounds__(256) void k_splitWall(const float* __restrict__ WrA, const float* __restrict__ WrB,
    const float* __restrict__ WlA, const float* __restrict__ WlB,
    const float* __restrict__ WgA, const float* __restrict__ WgB,
    u16* __restrict__ WtT_, u16* __restrict__ WtT1_){
  int br = blockIdx.y;
  if (blockIdx.x < 512){
    const float* Wr = br ? WrB : WrA;
    const float* Wl = br ? WlB : WlA;
    u16* WtT = WtT_ + (size_t)br*16*16384;
    int idx = blockIdx.x*256 + threadIdx.x;
    int k = idx >> 8, n = idx & 255;
    float v = (k < HH) ? Wr[(size_t)k*HH + n] : Wl[(size_t)(k-HH)*HH + n];
    u16 hi = f2bf(v);
    float lo = v - bf2f(hi);
    size_t base = ((size_t)(k>>5))*16384 + (size_t)((k>>3)&3)*4096 + (size_t)n*8 + (k&7);
    WtT[base] = hi;
    WtT[base + 2048] = f2bf(lo);
  } else {
    const float* W = br ? WgB : WgA;
    u16* WtT = WtT1_ + (size_t)br*2*16384;
    int idx = (blockIdx.x-512)*256 + threadIdx.x;   // 64*256
    int k = idx >> 8, n = idx & 255;
    float v = W[(size_t)k*HH + n];
    u16 hi = f2bf(v);
    float lo = v - bf2f(hi);
    size_t base = ((size_t)(k>>5))*16384 + (size_t)((k>>3)&3)*4096 + (size_t)n*8 + (k&7);
    WtT[base] = hi;
    WtT[base + 2048] = f2bf(lo);
  }
}

#define ASTRIDE 528

// ---------------- GEMM1 ----------------
__global__ __launch_bounds__(256, 2) void k_gemm1(const float* __restrict__ xA, const float* __restrict__ xB,
    const u16* __restrict__ WtT_,
    const float* __restrict__ asA, const float* __restrict__ asB,
    const float* __restrict__ adA, const float* __restrict__ adB,
    float* __restrict__ out_, float* __restrict__ asrc_, float* __restrict__ adst_){
  int br = blockIdx.y;
  const float* x = br ? xB : xA;
  const u16* WtT = WtT_ + (size_t)br*2*16384;
  const float* a_src = br ? asB : asA;
  const float* a_dst = br ? adB : adA;
  float* out = out_ + (size_t)br*NN*HH;
  float* asrc = asrc_ + (size_t)br*NN;
  float* adst = adst_ + (size_t)br*NN;

  __shared__ u16 As[2][8*ASTRIDE];
  int tid = threadIdx.x;
  int row0 = blockIdx.x*64;
  int wave = tid>>6, lane = tid&63;
  int l15 = lane&15, quad = lane>>4;
  int col0 = wave*64;
  int sm_ = tid >> 2, sg = tid & 3;
  int sgrow = row0 + sm_; if (sgrow >= NN) sgrow = NN-1;
  f32x4 acc[4][4];
  #pragma unroll
  for (int mt=0;mt<4;mt++)
    #pragma unroll
    for (int nt=0;nt<4;nt++){ f32x4 z = {0.f,0.f,0.f,0.f}; acc[mt][nt] = z; }

  const u16* bbase = WtT + ((size_t)quad<<12) + (size_t)(col0 + l15)*8;
  bf16x8 B0h[4],B0l[4],B1h[4],B1l[4];
  float4 va0, va1;

  auto loadA = [&](int kc){
    va0 = *((const float4*)(x + (size_t)sgrow*FI + kc + sg*8));
    va1 = *((const float4*)(x + (size_t)sgrow*FI + kc + sg*8 + 4));
  };
  auto writeA = [&](int wb){
    bf16x8 h, l;
    split8(va0, va1, h, l);
    *((bf16x8*)&As[wb][sg*ASTRIDE + sm_*8]) = h;
    *((bf16x8*)&As[wb][(4+sg)*ASTRIDE + sm_*8]) = l;
  };
  auto loadB = [&](int ck, bf16x8 (&Bh)[4], bf16x8 (&Bl)[4]){
    const u16* bb = bbase + ((size_t)ck<<14);
    #pragma unroll
    for (int nt=0;nt<4;nt++){
      Bh[nt] = *((const bf16x8*)(bb + nt*128));
      Bl[nt] = *((const bf16x8*)(bb + 2048 + nt*128));
    }
  };
  auto mmacc = [&](int rb, bf16x8 (&Bh)[4], bf16x8 (&Bl)[4]){
    bf16x8 ah[4], al[4];
    #pragma unroll
    for (int mt=0;mt<4;mt++){
      int m = mt*16 + l15;
      ah[mt] = *((bf16x8*)&As[rb][quad*ASTRIDE + m*8]);
      al[mt] = *((bf16x8*)&As[rb][(4+quad)*ASTRIDE + m*8]);
    }
    #pragma unroll
    for (int nt=0;nt<4;nt++)
      #pragma unroll
      for (int mt=0;mt<4;mt++){
        acc[mt][nt] = __builtin_amdgcn_mfma_f32_16x16x32_bf16(ah[mt], Bh[nt], acc[mt][nt], 0, 0, 0);
        acc[mt][nt] = __builtin_amdgcn_mfma_f32_16x16x32_bf16(al[mt], Bh[nt], acc[mt][nt], 0, 0, 0);
        acc[mt][nt] = __builtin_amdgcn_mfma_f32_16x16x32_bf16(ah[mt], Bl[nt], acc[mt][nt], 0, 0, 0);
      }
  };

  loadA(0);
  writeA(0);
  loadA(32);
  loadB(0, B0h, B0l);
  softBarrier();
  writeA(1);
  loadB(1, B1h, B1l);
  mmacc(0, B0h, B0l);
  softBarrier();
  mmacc(1, B1h, B1l);

  float ps[4][4], pd[4][4];
  #pragma unroll
  for (int mt=0;mt<4;mt++)
    #pragma unroll
    for (int r=0;r<4;r++){ ps[mt][r]=0.f; pd[mt][r]=0.f; }
  #pragma unroll
  for (int nt=0;nt<4;nt++){
    int c = col0 + nt*16 + l15;
    float av = a_src[c], dv = a_dst[c];
    #pragma unroll
    for (int mt=0;mt<4;mt++){
      int gbase = row0 + mt*16 + quad*4;
      #pragma unroll
      for (int r=0;r<4;r++){
        int grow = gbase + r;
        float v = acc[mt][nt][r];
        if (grow < NN) out[(size_t)grow*HH + c] = v;
        ps[mt][r] += v*av; pd[mt][r] += v*dv;
      }
    }
  }
  __syncthreads();
  float* sda = (float*)As;
  float* sdd = sda + 256;
  #pragma unroll
  for (int mt=0;mt<4;mt++)
    #pragma unroll
    for (int r=0;r<4;r++){
      float s = qredsum(ps[mt][r]);
      float d = qredsum(pd[mt][r]);
      if (l15 == 0){
        int row = mt*16 + quad*4 + r;
        sda[wave*64 + row] = s;
        sdd[wave*64 + row] = d;
      }
    }
  __syncthreads();
  if (tid < 64){
    int grow = row0 + tid;
    if (grow < NN){
      asrc[grow] = sda[tid] + sda[64+tid] + sda[128+tid] + sda[192+tid];
      adst[grow] = sdd[tid] + sdd[64+tid] + sdd[128+tid] + sdd[192+tid];
    }
  }
}

// ---------------- GAT (r17: 4-way unrolled gather; fused BN1 partial stats) ----------------
__global__ __launch_bounds__(256) void k_gat(const float* __restrict__ h_, const float* __restrict__ asrc_,
     const float* __restrict__ adst_, const int* __restrict__ rowptr_, const int* __restrict__ adj_,
     const float* __restrict__ biasA, const float* __restrict__ biasB, float* __restrict__ out_,
     float* __restrict__ gpart_){
  int br = blockIdx.y;
  const float* h = h_ + (size_t)br*NN*HH;
  const float* asrc = asrc_ + (size_t)br*NN;
  const float* adst = adst_ + (size_t)br*NN;
  const int* rowptr = rowptr_ + (size_t)br*RPN;
  const int* adj = adj_ + (size_t)br*NE;
  const float* bias = br ? biasB : biasA;
  float* out = out_ + (size_t)br*NN*HH;
  float* gpart = gpart_ + (size_t)br*PCOPIES*512;

  __shared__ float smst[4*512];

  int wid = threadIdx.x>>6;
  int node = blockIdx.x*4 + wid;
  int lane = threadIdx.x & 63;
  int rs = rowptr[node], re = rowptr[node+1];
  int deg = re - rs;
  float adsti = adst[node];
  float eself = leaky02(asrc[node] + adsti);
  int c0 = lane*4;
  float4 acc;
  float4 bv = *((const float4*)&bias[c0]);
  if (deg <= 64){
    bool act = lane < deg;
    int sv = 0; float asv = 0.f;
    if (act){ sv = adj[rs + lane]; asv = asrc[sv]; }
    float e_l = act ? leaky02(asv + adsti) : -INFINITY;
    float m = fmaxf(eself, wredmax(e_l));
    float ex = act ? expf(e_l - m) : 0.f;
    float es = expf(eself - m);
    float denom = wredsum(ex) + es + 1e-16f;
    float aself = es/denom;
    float av = ex/denom;
    float4 hv = *((const float4*)&h[(size_t)node*HH + c0]);
    acc = make_float4(hv.x*aself, hv.y*aself, hv.z*aself, hv.w*aself);
    float4 a2 = make_float4(-INFINITY,-INFINITY,-INFINITY,-INFINITY);
    float4 a3 = a2, a4 = a2;
    int jj = 0;
    for (; jj+3 < deg; jj += 4){
      int sb0 = __shfl(sv, jj,   64); float ab0 = __shfl(av, jj,   64);
      int sb1 = __shfl(sv, jj+1, 64); float ab1 = __shfl(av, jj+1, 64);
      int sb2 = __shfl(sv, jj+2, 64); float ab2 = __shfl(av, jj+2, 64);
      int sb3 = __shfl(sv, jj+3, 64); float ab3 = __shfl(av, jj+3, 64);
      float4 q0 = *((const float4*)&h[(size_t)sb0*HH + c0]);
      float4 q1 = *((const float4*)&h[(size_t)sb1*HH + c0]);
      float4 q2 = *((const float4*)&h[(size_t)sb2*HH + c0]);
      float4 q3 = *((const float4*)&h[(size_t)sb3*HH + c0]);
      acc = fmax4(acc, make_float4(q0.x*ab0, q0.y*ab0, q0.z*ab0, q0.w*ab0));
      a2  = fmax4(a2,  make_float4(q1.x*ab1, q1.y*ab1, q1.z*ab1, q1.w*ab1));
      a3  = fmax4(a3,  make_float4(q2.x*ab2, q2.y*ab2, q2.z*ab2, q2.w*ab2));
      a4  = fmax4(a4,  make_float4(q3.x*ab3, q3.y*ab3, q3.z*ab3, q3.w*ab3));
    }
    for (; jj < deg; jj++){
      int sb = __shfl(sv, jj, 64);
      float ab = __shfl(av, jj, 64);
      float4 q = *((const float4*)&h[(size_t)sb*HH + c0]);
      acc = fmax4(acc, make_float4(q.x*ab, q.y*ab, q.z*ab, q.w*ab));
    }
    acc = fmax4(fmax4(acc, a2), fmax4(a3, a4));
  } else {
    float m = eself;
    for (int j = rs + lane; j < re; j += 64) m = fmaxf(m, leaky02(asrc[adj[j]] + adsti));
    m = wredmax(m);
    float ssum = 0.f;
    for (int j = rs + lane; j < re; j += 64) ssum += expf(leaky02(asrc[adj[j]] + adsti) - m);
    ssum = wredsum(ssum) + expf(eself - m);
    float denom = ssum + 1e-16f;
    float aself = expf(eself - m)/denom;
    float4 hv = *((const float4*)&h[(size_t)node*HH + c0]);
    acc = make_float4(hv.x*aself, hv.y*aself, hv.z*aself, hv.w*aself);
    float4 a2 = make_float4(-INFINITY,-INFINITY,-INFINITY,-INFINITY);
    float4 a3 = a2, a4 = a2;
    for (int jb = rs; jb < re; jb += 64){
      int cnt = min(64, re - jb);
      int sv = 0; float av = 0.f;
      if (lane < cnt){ sv = adj[jb+lane]; av = expf(leaky02(asrc[sv] + adsti) - m)/denom; }
      int jj = 0;
      for (; jj+3 < cnt; jj += 4){
        int sb0 = __shfl(sv, jj,   64); float ab0 = __shfl(av, jj,   64);
        int sb1 = __shfl(sv, jj+1, 64); float ab1 = __shfl(av, jj+1, 64);
        int sb2 = __shfl(sv, jj+2, 64); float ab2 = __shfl(av, jj+2, 64);
        int sb3 = __shfl(sv, jj+3, 64); float ab3 = __shfl(av, jj+3, 64);
        float4 q0 = *((const float4*)&h[(size_t)sb0*HH + c0]);
        float4 q1 = *((const float4*)&h[(size_t)sb1*HH + c0]);
        float4 q2 = *((const float4*)&h[(size_t)sb2*HH + c0]);
        float4 q3 = *((const float4*)&h[(size_t)sb3*HH + c0]);
        acc = fmax4(acc, make_float4(q0.x*ab0, q0.y*ab0, q0.z*ab0, q0.w*ab0));
        a2  = fmax4(a2,  make_float4(q1.x*ab1, q1.y*ab1, q1.z*ab1, q1.w*ab1));
        a3  = fmax4(a3,  make_float4(q2.x*ab2, q2.y*ab2, q2.z*ab2, q2.w*ab2));
        a4  = fmax4(a4,  make_float4(q3.x*ab3, q3.y*ab3, q3.z*ab3, q3.w*ab3));
      }
      for (; jj < cnt; jj++){
        int sb = __shfl(sv, jj, 64);
        float ab = __shfl(av, jj, 64);
        float4 q = *((const float4*)&h[(size_t)sb*HH + c0]);
        acc = fmax4(acc, make_float4(q.x*ab, q.y*ab, q.z*ab, q.w*ab));
      }
    }
    acc = fmax4(fmax4(acc, a2), fmax4(a3, a4));
  }
  acc.x += bv.x; acc.y += bv.y; acc.z += bv.z; acc.w += bv.w;
  *((float4*)&out[(size_t)node*HH + c0]) = acc;

  // fused BN1 partial statistics (value + square per channel, 4 nodes/block)
  float* my = &smst[wid*512];
  my[c0+0] = acc.x; my[c0+1] = acc.y; my[c0+2] = acc.z; my[c0+3] = acc.w;
  my[256+c0+0] = acc.x*acc.x; my[256+c0+1] = acc.y*acc.y;
  my[256+c0+2] = acc.z*acc.z; my[256+c0+3] = acc.w*acc.w;
  __syncthreads();
  int t = threadIdx.x;   // 0..255: channel t
  float p0 = smst[t]     + smst[512+t]     + smst[1024+t]     + smst[1536+t];
  float p1 = smst[256+t] + smst[512+256+t] + smst[1024+256+t] + smst[1536+256+t];
  int copy = blockIdx.x & (PCOPIES-1);
  atomicAdd(&gpart[copy*512 + t], p0);
  atomicAdd(&gpart[copy*512 + 256 + t], p1);
}

// ---------------- BN finalize from gat partials (BN1) ----------------
__global__ __launch_bounds__(256) void k_bnfinP(const float* __restrict__ gpart_,
    const float* __restrict__ gA, const float* __restrict__ gB,
    const float* __restrict__ bA, const float* __restrict__ bB,
    float* __restrict__ scale_, float* __restrict__ shift_){
  int br = blockIdx.y;
  const float* gp = gpart_ + (size_t)br*PCOPIES*512;
  const float* g = br ? gB : gA;
  const float* b = br ? bB : bA;
  float* scale = scale_ + (size_t)br*HH;
  float* shift = shift_ + (size_t)br*HH;
  int c = threadIdx.x;
  float s = 0.f, q = 0.f;
  #pragma unroll 8
  for (int p=0;p<PCOPIES;p++){ s += gp[p*512 + c]; q += gp[p*512 + 256 + c]; }
  float mean = s/(float)NN;
  float var = q/(float)NN - mean*mean;
  float rstd = rsqrtf(var + 1e-5f);
  float sc = g[c]*rstd;
  scale[c] = sc; shift[c] = b[c] - mean*sc;
}

// ---------------- BN finalize from sums (BN2) ----------------
__global__ __launch_bounds__(256) void k_bnfin(const float* __restrict__ sums_,
    const float* __restrict__ gA, const float* __restrict__ gB,
    const float* __restrict__ bA, const float* __restrict__ bB,
    float* __restrict__ scale_, float* __restrict__ shift_){
  int br = blockIdx.y;
  const float* sums = sums_ + (size_t)br*2*HH;
  const float* sumsq = sums + HH;
  const float* g = br ? gB : gA;
  const float* b = br ? bB : bA;
  float* scale = scale_ + (size_t)br*HH;
  float* shift = shift_ + (size_t)br*HH;
  int c = threadIdx.x;
  float mean = sums[c]/(float)NN;
  float var = sumsq[c]/(float)NN - mean*mean;
  float rstd = rsqrtf(var + 1e-5f);
  float sc = g[c]*rstd;
  scale[c] = sc; shift[c] = b[c] - mean*sc;
}

// ---------------- SAGE max-aggregate (r17: 4-way unrolled gather) ----------------
__global__ __launch_bounds__(256) void k_sageagg(const float* __restrict__ xin_, const float* __restrict__ scale_,
    const float* __restrict__ shift_, const float* __restrict__ pA, const float* __restrict__ pB,
    const int* __restrict__ rowptr_, const int* __restrict__ adj_, float* __restrict__ agg_){
  int br = blockIdx.y;
  const float* xin = xin_ + (size_t)br*NN*HH;
  const float* scale = scale_ + (size_t)br*HH;
  const float* shift = shift_ + (size_t)br*HH;
  const float* prelu = br ? pB : pA;
  const int* rowptr = rowptr_ + (size_t)br*RPN;
  const int* adj = adj_ + (size_t)br*NE;
  float* agg = agg_ + (size_t)br*NN*HH;

  int node = blockIdx.x*4 + (threadIdx.x>>6);
  int lane = threadIdx.x & 63;
  int rs = rowptr[node], re = rowptr[node+1];
  int c0 = lane*4;
  float slope = prelu[0];
  float4 sc = *((const float4*)&scale[c0]);
  float4 sh = *((const float4*)&shift[c0]);
  float4 acc = make_float4(-INFINITY,-INFINITY,-INFINITY,-INFINITY);
  float4 a2 = acc, a3 = acc, a4 = acc;
  for (int jb = rs; jb < re; jb += 64){
    int cnt = min(64, re - jb);
    int sv = (lane < cnt) ? adj[jb+lane] : 0;
    int jj = 0;
    for (; jj+3 < cnt; jj += 4){
      int sb0 = __shfl(sv, jj,   64);
      int sb1 = __shfl(sv, jj+1, 64);
      int sb2 = __shfl(sv, jj+2, 64);
      int sb3 = __shfl(sv, jj+3, 64);
      float4 q0 = *((const float4*)&xin[(size_t)sb0*HH + c0]);
      float4 q1 = *((const float4*)&xin[(size_t)sb1*HH + c0]);
      float4 q2 = *((const float4*)&xin[(size_t)sb2*HH + c0]);
      float4 q3 = *((const float4*)&xin[(size_t)sb3*HH + c0]);
      acc = fmax4(acc, bnprelu4(q0, sc, sh, slope));
      a2  = fmax4(a2,  bnprelu4(q1, sc, sh, slope));
      a3  = fmax4(a3,  bnprelu4(q2, sc, sh, slope));
      a4  = fmax4(a4,  bnprelu4(q3, sc, sh, slope));
    }
    for (; jj < cnt; jj++){
      int sb = __shfl(sv, jj, 64);
      float4 q = *((const float4*)&xin[(size_t)sb*HH + c0]);
      acc = fmax4(acc, bnprelu4(q, sc, sh, slope));
    }
  }
  acc = fmax4(fmax4(acc, a2), fmax4(a3, a4));
  if (re == rs) acc = make_float4(0.f,0.f,0.f,0.f);
  *((float4*)&agg[(size_t)node*HH + c0]) = acc;
}

// ---------------- GEMM2 (r13-verified: M=64 x N=256, 512 thr / 8 waves, wave 64x32) ----------------
__global__ __launch_bounds__(512, 4) void k_gemm2(const float* __restrict__ graw_, const float* __restrict__ agg_,
    const u16* __restrict__ WtT_,
    const float* __restrict__ scale1_, const float* __restrict__ shift1_,
    const float* __restrict__ p1A, const float* __restrict__ p1B,
    const float* __restrict__ blA, const float* __restrict__ blB,
    float* __restrict__ out_, float* __restrict__ sums_){
  int br = blockIdx.y;
  const float* graw = graw_ + (size_t)br*NN*HH;
  const float* agg = agg_ + (size_t)br*NN*HH;
  const u16* WtT = WtT_ + (size_t)br*16*16384;
  const float* scale1 = scale1_ + (size_t)br*HH;
  const float* shift1 = shift1_ + (size_t)br*HH;
  const float* prelu1 = br ? p1B : p1A;
  const float* bl = br ? blB : blA;
  float* out = out_ + (size_t)br*NN*HH;
  float* sums = sums_ + (size_t)br*2*HH;
  float* sumsq = sums + HH;

  __shared__ u16 As[2][8*ASTRIDE];
  int tid = threadIdx.x;
  int row0 = blockIdx.x*64;
  int wave = tid>>6, lane = tid&63;
  int l15 = lane&15, quad = lane>>4;
  int col0 = wave*32;
  int sm_ = tid >> 3, sg = tid & 7;   // 8 threads per row, 4 floats each
  int sgrow = row0 + sm_; if (sgrow >= NN) sgrow = NN-1;
  float slope = prelu1[0];
  f32x4 acc[4][2];
  #pragma unroll
  for (int mt=0;mt<4;mt++)
    #pragma unroll
    for (int nt=0;nt<2;nt++){ f32x4 z = {0.f,0.f,0.f,0.f}; acc[mt][nt] = z; }

  const u16* bbase = WtT + ((size_t)quad<<12) + (size_t)(col0 + l15)*8;
  bf16x8 B0h[2],B0l[2],B1h[2],B1l[2];
  float4 vaA, vaB;

  auto loadA = [&](int kc, float4& dst){
    const float* ab = (kc < HH) ? graw : agg;
    int ac = (kc < HH) ? kc : kc - HH;
    dst = *((const float4*)(ab + (size_t)sgrow*HH + ac + sg*4));
  };
  auto writeA = [&](int kc, int wb, float4 v){
    if (kc < HH){
      int kcol = kc + sg*4;
      v = bnprelu4(v, *((const float4*)(scale1+kcol)), *((const float4*)(shift1+kcol)), slope);
    }
    bf16x4 h, l;
    split4(v, h, l);
    int cell = (sg>>1)*ASTRIDE + sm_*8 + (sg&1)*4;
    *((bf16x4*)&As[wb][cell]) = h;
    *((bf16x4*)&As[wb][cell + 4*ASTRIDE]) = l;
  };
  auto loadB = [&](int ck, bf16x8 (&Bh)[2], bf16x8 (&Bl)[2]){
    const u16* bb = bbase + ((size_t)ck<<14);
    #pragma unroll
    for (int nt=0;nt<2;nt++){
      Bh[nt] = *((const bf16x8*)(bb + nt*128));
      Bl[nt] = *((const bf16x8*)(bb + 2048 + nt*128));
    }
  };
  auto body = [&](int k, int rb, float4& vaW, float4& vaL, bf16x8 (&Bh)[2], bf16x8 (&Bl)[2], bf16x8 (&nBh)[2], bf16x8 (&nBl)[2]){
    softBarrier();
    if (k < 15) writeA((k+1)*32, rb^1, vaW);
    if (k < 13) loadA((k+3)*32, vaW);
    if (k < 15) loadB(k+1, nBh, nBl);
    (void)vaL;
    #pragma unroll
    for (int mt=0;mt<4;mt++){
      int m = mt*16 + l15;
      bf16x8 ah = *((bf16x8*)&As[rb][quad*ASTRIDE + m*8]);
      bf16x8 al = *((bf16x8*)&As[rb][(4+quad)*ASTRIDE + m*8]);
      #pragma unroll
      for (int nt=0;nt<2;nt++){
        acc[mt][nt] = __builtin_amdgcn_mfma_f32_16x16x32_bf16(ah, Bh[nt], acc[mt][nt], 0, 0, 0);
        acc[mt][nt] = __builtin_amdgcn_mfma_f32_16x16x32_bf16(al, Bh[nt], acc[mt][nt], 0, 0, 0);
        acc[mt][nt] = __builtin_amdgcn_mfma_f32_16x16x32_bf16(ah, Bl[nt], acc[mt][nt], 0, 0, 0);
      }
    }
  };

  loadA(0, vaA);
  writeA(0, 0, vaA);
  loadA(32, vaA);
  loadA(64, vaB);
  loadB(0, B0h, B0l);
  #pragma unroll 1
  for (int k=0; k<16; k+=2){
    body(k,   0, vaA, vaB, B0h,B0l, B1h,B1l);
    body(k+1, 1, vaB, vaA, B1h,B1l, B0h,B0l);
  }

  float psum[2], psq[2];
  #pragma unroll
  for (int nt=0;nt<2;nt++){
    int c = col0 + nt*16 + l15;
    float bcol = bl[c];
    float s=0.f, q=0.f;
    #pragma unroll
    for (int mt=0;mt<4;mt++){
      int gbase = row0 + mt*16 + quad*4;
      #pragma unroll
      for (int r=0;r<4;r++){
        int grow = gbase + r;
        float v = acc[mt][nt][r] + bcol;
        if (grow < NN){
          out[(size_t)grow*HH + c] = v;
          s += v; q += v*v;
        }
      }
    }
    psum[nt]=s; psq[nt]=q;
  }
  __syncthreads();
  float* sm2 = (float*)As;
  sm2[tid] = 0.f;
  __syncthreads();
  #pragma unroll
  for (int nt=0;nt<2;nt++){
    int c = col0 + nt*16 + l15;
    atomicAdd(&sm2[c], psum[nt]);
    atomicAdd(&sm2[256+c], psq[nt]);
  }
  __syncthreads();
  if (tid < 256){
    atomicAdd(&sums[tid],  sm2[tid]);
    atomicAdd(&sumsq[tid], sm2[256+tid]);
  }
}

// ---------------- pool GEMVs ----------------
__global__ __launch_bounds__(256) void k_gemv2(const float* __restrict__ x2_, const float* __restrict__ scale2_,
    const float* __restrict__ shift2_, const float* __restrict__ p2A, const float* __restrict__ p2B,
    const float* __restrict__ WrelA, const float* __restrict__ WrelB,
    const float* __restrict__ WrootA, const float* __restrict__ WrootB,
    float* __restrict__ y2_, float* __restrict__ y2r_){
  int br = blockIdx.y;
  const float* x2raw = x2_ + (size_t)br*NN*HH;
  const float* scale2 = scale2_ + (size_t)br*HH;
  const float* shift2 = shift2_ + (size_t)br*HH;
  const float* prelu2 = br ? p2B : p2A;
  const float* Wrel = br ? WrelB : WrelA;
  const float* Wroot = br ? WrootB : WrootA;
  float* y2 = y2_ + (size_t)br*NN;
  float* y2r = y2r_ + (size_t)br*NN;

  int node = blockIdx.x*4 + (threadIdx.x>>6);
  int lane = threadIdx.x & 63;
  int c0 = lane*4;
  float slope = prelu2[0];
  float4 v = *((const float4*)&x2raw[(size_t)node*HH + c0]);
  float4 sc = *((const float4*)&scale2[c0]);
  float4 sh = *((const float4*)&shift2[c0]);
  v = bnprelu4(v, sc, sh, slope);
  float4 wr = *((const float4*)&Wrel[c0]);
  float4 wo = *((const float4*)&Wroot[c0]);
  float pr = v.x*wr.x + v.y*wr.y + v.z*wr.z + v.w*wr.w;
  float po = v.x*wo.x + v.y*wo.y + v.z*wo.z + v.w*wo.w;
  pr = wredsum(pr); po = wredsum(po);
  if (lane==0){ y2[node] = pr; y2r[node] = po; }
}

// k_score with fused hist1 (r17: 2-way ILP on y2 gather)
__global__ void k_score(const int* __restrict__ rowptr_, const int* __restrict__ adj_, const float* __restrict__ y2_,
    const float* __restrict__ y2r_, const float* __restrict__ brelA, const float* __restrict__ brelB,
    float* __restrict__ score_, unsigned* __restrict__ keys_, unsigned* __restrict__ hist_){
  int br = blockIdx.y;
  const int* rowptr = rowptr_ + (size_t)br*RPN;
  const int* adj = adj_ + (size_t)br*NE;
  const float* y2 = y2_ + (size_t)br*NN;
  const float* y2r = y2r_ + (size_t)br*NN;
  const float* brel = br ? brelB : brelA;
  float* score = score_ + (size_t)br*NN;
  unsigned* keys = keys_ + (size_t)br*NN;
  unsigned* hist = hist_ + (size_t)br*65536;

  int i = blockIdx.x*blockDim.x + threadIdx.x;
  if (i >= NN) return;
  float s0 = 0.f, s1 = 0.f;
  int rs = rowptr[i], re = rowptr[i+1];
  int j = rs;
  for (; j+1 < re; j += 2){ s0 += y2[adj[j]]; s1 += y2[adj[j+1]]; }
  if (j < re) s0 += y2[adj[j]];
  float sc = s0 + s1 + brel[0] + y2r[i];
  score[i] = sc;
  unsigned u = __float_as_uint(sc);
  u = (u & 0x80000000u) ? ~u : (u | 0x80000000u);
  keys[i] = u;
  atomicAdd(&hist[u>>16], 1u);
}

// parallel suffix-scan findbin: uint4 coarse sums + log-step scans
__global__ __launch_bounds__(256) void k_findbin1(const unsigned* __restrict__ hist_, unsigned* __restrict__ scal_){
  int br = blockIdx.y;
  const unsigned* hist = hist_ + (size_t)br*65536;
  unsigned* scal = scal_ + (size_t)br*16;
  __shared__ unsigned suf[256];
  __shared__ unsigned shc[2];
  int t = threadIdx.x;
  const uint4* h4 = (const uint4*)(hist + t*256);
  unsigned s = 0;
  #pragma unroll 8
  for (int b=0;b<64;b++){ uint4 v = h4[b]; s += v.x+v.y+v.z+v.w; }
  suf[t] = s; __syncthreads();
  #pragma unroll
  for (int o=1;o<256;o<<=1){
    unsigned add = (t+o<256)? suf[t+o] : 0u;
    __syncthreads();
    suf[t] += add;
    __syncthreads();
  }
  unsigned ab = suf[t] - s;
  if (ab < (unsigned)KT && ab + s >= (unsigned)KT){ shc[0] = (unsigned)t; shc[1] = ab; }
  __syncthreads();
  int cb = (int)shc[0]; unsigned runbase = shc[1];
  unsigned f = hist[cb*256 + t];
  suf[t] = f; __syncthreads();
  #pragma unroll
  for (int o=1;o<256;o<<=1){
    unsigned add = (t+o<256)? suf[t+o] : 0u;
    __syncthreads();
    suf[t] += add;
    __syncthreads();
  }
  unsigned ta = runbase + suf[t] - f;
  if (ta < (unsigned)KT && ta + f >= (unsigned)KT){
    scal[0] = (unsigned)(cb*256 + t);
    scal[1] = ta;
  }
}

__global__ void k_hist2(const unsigned* __restrict__ keys_, const unsigned* __restrict__ scal_, unsigned* __restrict__ hist_){
  int br = blockIdx.y;
  const unsigned* keys = keys_ + (size_t)br*NN;
  const unsigned* scal = scal_ + (size_t)br*16;
  unsigned* hist = hist_ + (size_t)br*65536;
  int i = blockIdx.x*blockDim.x + threadIdx.x;
  if (i < NN){ unsigned k = keys[i]; if ((k>>16) == scal[0]) atomicAdd(&hist[k & 0xFFFFu], 1u); }
}

__global__ __launch_bounds__(256) void k_findbin2(const unsigned* __restrict__ hist_, unsigned* __restrict__ scal_){
  int br = blockIdx.y;
  const unsigned* hist = hist_ + (size_t)br*65536;
  unsigned* scal = scal_ + (size_t)br*16;
  __shared__ unsigned suf[256];
  __shared__ unsigned shc[2];
  int t = threadIdx.x;
  unsigned target = (unsigned)KT - scal[1];
  const uint4* h4 = (const uint4*)(hist + t*256);
  unsigned s = 0;
  #pragma unroll 8
  for (int b=0;b<64;b++){ uint4 v = h4[b]; s += v.x+v.y+v.z+v.w; }
  suf[t] = s; __syncthreads();
  #pragma unroll
  for (int o=1;o<256;o<<=1){
    unsigned add = (t+o<256)? suf[t+o] : 0u;
    __syncthreads();
    suf[t] += add;
    __syncthreads();
  }
  unsigned ab = suf[t] - s;
  if (ab < target && ab + s >= target){ shc[0] = (unsigned)t; shc[1] = ab; }
  __syncthreads();
  int cb = (int)shc[0]; unsigned runbase = shc[1];
  unsigned f = hist[cb*256 + t];
  suf[t] = f; __syncthreads();
  #pragma unroll
  for (int o=1;o<256;o<<=1){
    unsigned add = (t+o<256)? suf[t+o] : 0u;
    __syncthreads();
    suf[t] += add;
    __syncthreads();
  }
  unsigned ta = runbase + suf[t] - f;
  if (ta < target && ta + f >= target){
    scal[2] = (scal[0] << 16) | (unsigned)(cb*256 + t);
    scal[3] = target - ta;
    scal[4] = f;
  }
}

__global__ void k_select(const unsigned* __restrict__ keys_, const float* __restrict__ score_,
    unsigned* __restrict__ scal_, int* __restrict__ selidx_, float* __restrict__ tvals_){
  int br = blockIdx.y;
  const unsigned* keys = keys_ + (size_t)br*NN;
  const float* score = score_ + (size_t)br*NN;
  unsigned* scal = scal_ + (size_t)br*16;
  int* selidx = selidx_ + (size_t)br*NN;
  float* tvals = tvals_ + (size_t)br*NN;

  int i = blockIdx.x*blockDim.x + threadIdx.x;
  if (i >= NN) return;
  unsigned T = scal[2], needed = scal[3], cnteq = scal[4];
  unsigned k = keys[i];
  int s = 0;
  if (k > T) s = 1;
  else if (k == T){
    if (cnteq <= needed) s = 1;
    else {
      unsigned rank = 0;
      for (int j=0;j<i;j++) rank += (keys[j] == T) ? 1u : 0u;
      s = (rank < needed) ? 1 : 0;
    }
  }
  if (s){
    unsigned idx = atomicAdd(&scal[8], 1u);
    selidx[idx] = i;
    tvals[idx] = tanhf(score[i]);
  }
}

// r17: 1024 blocks/branch + 2-way unrolled row gather
__global__ __launch_bounds__(256) void k_embed(const float* __restrict__ x2_, const float* __restrict__ scale2_,
    const float* __restrict__ shift2_, const float* __restrict__ p2A, const float* __restrict__ p2B,
    const int* __restrict__ selidx_, const float* __restrict__ tvals_, float* __restrict__ embed){
  int br = blockIdx.y;
  const float* x2raw = x2_ + (size_t)br*NN*HH;
  const float* scale2 = scale2_ + (size_t)br*HH;
  const float* shift2 = shift2_ + (size_t)br*HH;
  const float* prelu2 = br ? p2B : p2A;
  const int* selidx = selidx_ + (size_t)br*NN;
  const float* tvals = tvals_ + (size_t)br*NN;

  int c = threadIdx.x;
  float slope = prelu2[0];
  float scv = scale2[c], shv = shift2[c];
  float best = -INFINITY, best2 = -INFINITY;
  int stride = gridDim.x;
  for (int j = blockIdx.x; j < KT; j += 2*stride){
    int j1 = j + stride;
    int r0 = selidx[j];
    float t0 = tvals[j];
    int r1 = (j1 < KT) ? selidx[j1] : r0;
    float v0 = preluf(x2raw[(size_t)r0*HH + c]*scv + shv, slope);
    best = fmaxf(best, v0*t0);
    if (j1 < KT){
      float t1 = tvals[j1];
      float v1 = preluf(x2raw[(size_t)r1*HH + c]*scv + shv, slope);
      best2 = fmaxf(best2, v1*t1);
    }
  }
  best = fmaxf(best, best2);
  atomicMaxF(&embed[(size_t)br*HH + c], best);
}

__global__ void k_initembed(float* __restrict__ embed){
  int i = threadIdx.x;
  if (i < 2*HH) embed[i] = -INFINITY;
}

// ---------------- head ----------------
__global__ __launch_bounds__(256) void k_head(const float* __restrict__ embed, const float* __restrict__ addf,
    const float* __restrict__ fc1W, const float* __restrict__ fc1b, const float* __restrict__ preluh,
    const float* __restrict__ fc2W, const float* __restrict__ fc2b, float* __restrict__ out){
  __shared__ float z[2*HH + 8];
  __shared__ float h1s[HH];
  __shared__ float red[4];
  int t = threadIdx.x;
  for (int i=t;i<2*HH;i+=256) z[i] = embed[i];
  if (t < 8) z[2*HH + t] = addf[t];
  __syncthreads();
  float acc = fc1b[t];
  for (int k=0;k<2*HH+8;k++) acc += z[k]*fc1W[(size_t)k*HH + t];
  float slope = preluh[0];
  h1s[t] = preluf(acc, slope);
  __syncthreads();
  float p = h1s[t]*fc2W[t];
  p = wredsum(p);
  if ((t & 63) == 0) red[t>>6] = p;
  __syncthreads();
  if (t == 0) out[0] = expf(red[0]+red[1]+red[2]+red[3] + fc2b[0]);
}

// ---------------- orchestration ----------------
extern "C" void kernel_launch(void* const* d_in, const int* in_sizes, int n_in,
                              void* d_out, int out_size, void* d_ws, size_t ws_size,
                              hipStream_t stream) {
  (void)in_sizes; (void)n_in; (void)out_size;
  char* ws = (char*)d_ws;

  float *bufA, *bufB, *asrc, *adst, *sums, *scale1, *shift1, *scale2, *shift2;
  float *y2, *y2r, *score, *tvals, *embed, *gpart;
  int *rowptr, *adj, *cursor, *bsums, *selidx;
  unsigned *keys, *hist1, *hist2, *scal;
  u16 *WtT, *WtT1;

  auto doAlloc = [&](int nb)->size_t{
    size_t o = 0;
    auto al = [&](size_t bytes)->char*{ char* p = ws + o; o = (o + bytes + 255) & ~(size_t)255; return p; };
    bufA   = (float*)al((size_t)nb*NN*HH*4);
    bufB   = (float*)al((size_t)nb*NN*HH*4);
    asrc   = (float*)al((size_t)nb*NN*4);
    adst   = (float*)al((size_t)nb*NN*4);
    rowptr = (int*)  al((size_t)nb*RPN*4);
    adj    = (int*)  al((size_t)nb*NE*4);
    cursor = (int*)  al((size_t)nb*NN*4);
    bsums  = (int*)  al((size_t)nb*128*4);
    sums   = (float*)al((size_t)nb*2*HH*4);
    gpart  = (float*)al((size_t)nb*PCOPIES*512*4);
    scale1 = (float*)al((size_t)nb*HH*4);
    shift1 = (float*)al((size_t)nb*HH*4);
    scale2 = (float*)al((size_t)nb*HH*4);
    shift2 = (float*)al((size_t)nb*HH*4);
    y2     = (float*)al((size_t)nb*NN*4);
    y2r    = (float*)al((size_t)nb*NN*4);
    score  = (float*)al((size_t)nb*NN*4);
    keys   = (unsigned*)al((size_t)nb*NN*4);
    selidx = (int*)  al((size_t)nb*NN*4);
    tvals  = (float*)al((size_t)nb*NN*4);
    hist1  = (unsigned*)al((size_t)nb*65536*4);
    hist2  = (unsigned*)al((size_t)nb*65536*4);
    scal   = (unsigned*)al((size_t)nb*64);
    embed  = (float*)al((size_t)2*HH*4);
    WtT    = (u16*)al((size_t)nb*16*16384*2);
    WtT1   = (u16*)al((size_t)nb*2*16384*2);
    return o;
  };

  int NB = 2;
  if (doAlloc(2) > ws_size) NB = 1;
  doAlloc(NB);

  const float* addf = (const float*)d_in[2];

  k_initembed<<<dim3(1), dim3(512), 0, stream>>>(embed);

  int nIter = (NB==2) ? 1 : 2;
  for (int it = 0; it < nIter; ++it){
    const float *xA, *xB; const int *eiA, *eiB; int pa, pb;
    if (NB == 2){
      xA = (const float*)d_in[0]; xB = (const float*)d_in[1];
      eiA = (const int*)d_in[3]; eiB = (const int*)d_in[4];
      pa = 5; pb = 21;
    } else {
      xA = xB = (const float*)d_in[it];
      eiA = eiB = (const int*)d_in[3+it];
      pa = pb = (it==0) ? 5 : 21;
    }
    auto PA = [&](int i){ return (const float*)d_in[pa+i]; };
    auto PB = [&](int i){ return (const float*)d_in[pb+i]; };

    // CSR by dst (both branches)
    hipMemsetAsync(cursor, 0, (size_t)NB*NN*4, stream);
    hipMemsetAsync(gpart, 0, (size_t)NB*PCOPIES*512*4, stream);
    k_count<<<dim3((NE+255)/256, NB), dim3(256), 0, stream>>>(eiA, eiB, cursor);
    k_scan1<<<dim3(98, NB), dim3(1024), 0, stream>>>(cursor, rowptr, bsums);
    k_scan2<<<dim3(1, NB), dim3(128), 0, stream>>>(bsums, 98);
    k_scan3<<<dim3(98, NB), dim3(1024), 0, stream>>>(rowptr, bsums, cursor);
    k_scatter<<<dim3((NE+255)/256, NB), dim3(256), 0, stream>>>(eiA, eiB, cursor, adj);

    // W pre-splits (merged)
    k_splitWall<<<dim3(576, NB), dim3(256), 0, stream>>>(PA(9), PB(9), PA(7), PB(7), PA(0), PB(0), WtT, WtT1);

    // GAT (BN1 stats fused into k_gat -> gpart partials)
    k_gemm1<<<dim3((NN+63)/64, NB), dim3(256), 0, stream>>>(xA, xB, WtT1,
        PA(1), PB(1), PA(2), PB(2), bufA, asrc, adst);
    k_gat<<<dim3(25000, NB), dim3(256), 0, stream>>>(bufA, asrc, adst, rowptr, adj, PA(3), PB(3), bufB, gpart);

    // BN1 finalize from partials
    k_bnfinP<<<dim3(1, NB), dim3(256), 0, stream>>>(gpart, PA(4), PB(4), PA(5), PB(5), scale1, shift1);

    // SAGE
    k_sageagg<<<dim3(25000, NB), dim3(256), 0, stream>>>(bufB, scale1, shift1, PA(6), PB(6), rowptr, adj, bufA);
    hipMemsetAsync(sums, 0, (size_t)NB*2*HH*4, stream);
    k_gemm2<<<dim3((NN+63)/64, NB), dim3(512), 0, stream>>>(bufB, bufA, WtT,
        scale1, shift1, PA(6), PB(6), PA(8), PB(8), bufB, sums);
    k_bnfin<<<dim3(1, NB), dim3(256), 0, stream>>>(sums, PA(10), PB(10), PA(11), PB(11), scale2, shift2);

    // SAGPool (hist1 fused into k_score; memsets hoisted)
    hipMemsetAsync(scal, 0, (size_t)NB*64, stream);
    hipMemsetAsync(hist1, 0, (size_t)NB*65536*4, stream);
    hipMemsetAsync(hist2, 0, (size_t)NB*65536*4, stream);
    k_gemv2<<<dim3(25000, NB), dim3(256), 0, stream>>>(bufB, scale2, shift2, PA(12), PB(12),
        PA(13), PB(13), PA(15), PB(15), y2, y2r);
    k_score<<<dim3((NN+255)/256, NB), dim3(256), 0, stream>>>(rowptr, adj, y2, y2r, PA(14), PB(14), score, keys, hist1);
    k_findbin1<<<dim3(1, NB), dim3(256), 0, stream>>>(hist1, scal);
    k_hist2<<<dim3((NN+255)/256, NB), dim3(256), 0, stream>>>(keys, scal, hist2);
    k_findbin2<<<dim3(1, NB), dim3(256), 0, stream>>>(hist2, scal);
    k_select<<<dim3((NN+255)/256, NB), dim3(256), 0, stream>>>(keys, score, scal, selidx, tvals);
    float* embDst = (NB==2) ? embed : (embed + it*HH);
    k_embed<<<dim3(1024, NB), dim3(256), 0, stream>>>(bufB, scale2, shift2, PA(12), PB(12), selidx, tvals, embDst);
  }

  k_head<<<dim3(1), dim3(256), 0, stream>>>(embed, addf,
      (const float*)d_in[37], (const float*)d_in[38], (const float*)d_in[39],
      (const float*)d_in[40], (const float*)d_in[41], (float*)d_out);
}

// Round 10
// 1261.864 us; speedup vs baseline: 1.2039x; 1.0363x over previous
//
#include <hip/hip_runtime.h>
#include <math.h>

#define NN 100000
#define NE 400000
#define FI 64
#define HH 256
#define KT 50000
#define RPN (NN+1)
#define PCOPIES 64
#define GB_G1 1563   // gemm1 blocks = (NN+63)/64
#define GB_SC 1563   // scatter blocks = (NE+255)/256
#define GB_CT 1563   // count blocks
#define GB_SW 576    // splitW blocks

typedef unsigned short u16;
typedef __attribute__((ext_vector_type(8))) short bf16x8;
typedef __attribute__((ext_vector_type(4))) short bf16x4;
typedef __attribute__((ext_vector_type(4))) float f32x4;

__device__ __forceinline__ float leaky02(float x){ return x >= 0.f ? x : 0.2f*x; }
__device__ __forceinline__ float preluf(float x, float a){ return x >= 0.f ? x : a*x; }

__device__ __forceinline__ float wredmax(float v){
  #pragma unroll
  for (int o=32;o>0;o>>=1) v = fmaxf(v, __shfl_xor(v, o, 64));
  return v;
}
__device__ __forceinline__ float wredsum(float v){
  #pragma unroll
  for (int o=32;o>0;o>>=1) v += __shfl_xor(v, o, 64);
  return v;
}
__device__ __forceinline__ float qredsum(float v){
  #pragma unroll
  for (int o=8;o>0;o>>=1) v += __shfl_xor(v, o, 64);
  return v;
}

// barrier that does NOT drain vmcnt (keeps prefetch loads in flight)
__device__ __forceinline__ void softBarrier(){
  asm volatile("s_waitcnt lgkmcnt(0)" ::: "memory");
  __builtin_amdgcn_s_barrier();
}

__device__ __forceinline__ void atomicMaxF(float* a, float v){
  if (v >= 0.f) atomicMax((int*)a, __float_as_int(v));
  else atomicMin((unsigned int*)a, __float_as_uint(v));
}

__device__ __forceinline__ float4 bnprelu4(float4 v, float4 sc, float4 sh, float a){
  float4 r;
  r.x = preluf(v.x*sc.x+sh.x, a);
  r.y = preluf(v.y*sc.y+sh.y, a);
  r.z = preluf(v.z*sc.z+sh.z, a);
  r.w = preluf(v.w*sc.w+sh.w, a);
  return r;
}

__device__ __forceinline__ float4 fmax4(float4 a, float4 b){
  return make_float4(fmaxf(a.x,b.x), fmaxf(a.y,b.y), fmaxf(a.z,b.z), fmaxf(a.w,b.w));
}

__device__ __forceinline__ u16 f2bf(float f){
  unsigned u = __float_as_uint(f);
  unsigned r = u + 0x7FFFu + ((u>>16)&1u);
  return (u16)(r>>16);
}
__device__ __forceinline__ float bf2f(u16 h){
  return __uint_as_float(((unsigned)h)<<16);
}
__device__ __forceinline__ void split8(float4 a, float4 b, bf16x8& h, bf16x8& l){
  float va[8] = {a.x,a.y,a.z,a.w,b.x,b.y,b.z,b.w};
  #pragma unroll
  for (int j=0;j<8;j++){
    u16 hh = f2bf(va[j]);
    h[j] = (short)hh;
    l[j] = (short)f2bf(va[j] - bf2f(hh));
  }
}
__device__ __forceinline__ void split4(float4 a, bf16x4& h, bf16x4& l){
  float va[4] = {a.x,a.y,a.z,a.w};
  #pragma unroll
  for (int j=0;j<4;j++){
    u16 hh = f2bf(va[j]);
    h[j] = (short)hh;
    l[j] = (short)f2bf(va[j] - bf2f(hh));
  }
}

// ---------------- k_prep: fused count (deg) + W pre-split ----------------
__global__ __launch_bounds__(256) void k_prep(const int* __restrict__ eiA, const int* __restrict__ eiB,
    int* __restrict__ deg_,
    const float* __restrict__ WrA, const float* __restrict__ WrB,
    const float* __restrict__ WlA, const float* __restrict__ WlB,
    const float* __restrict__ WgA, const float* __restrict__ WgB,
    u16* __restrict__ WtT_, u16* __restrict__ WtT1_){
  int br = blockIdx.y;
  if (blockIdx.x < GB_CT){
    const int* dst = (br ? eiB : eiA) + NE;
    int* deg = deg_ + (size_t)br*NN;
    int e = blockIdx.x*256 + threadIdx.x;
    if (e < NE) atomicAdd(&deg[dst[e]], 1);
    return;
  }
  int sx = blockIdx.x - GB_CT;   // 0..575
  if (sx < 512){
    const float* Wr = br ? WrB : WrA;
    const float* Wl = br ? WlB : WlA;
    u16* WtT = WtT_ + (size_t)br*16*16384;
    int idx = sx*256 + threadIdx.x;
    int k = idx >> 8, n = idx & 255;
    float v = (k < HH) ? Wr[(size_t)k*HH + n] : Wl[(size_t)(k-HH)*HH + n];
    u16 hi = f2bf(v);
    float lo = v - bf2f(hi);
    size_t base = ((size_t)(k>>5))*16384 + (size_t)((k>>3)&3)*4096 + (size_t)n*8 + (k&7);
    WtT[base] = hi;
    WtT[base + 2048] = f2bf(lo);
  } else {
    const float* W = br ? WgB : WgA;
    u16* WtT = WtT1_ + (size_t)br*2*16384;
    int idx = (sx-512)*256 + threadIdx.x;   // 64*256
    int k = idx >> 8, n = idx & 255;
    float v = W[(size_t)k*HH + n];
    u16 hi = f2bf(v);
    float lo = v - bf2f(hi);
    size_t base = ((size_t)(k>>5))*16384 + (size_t)((k>>3)&3)*4096 + (size_t)n*8 + (k&7);
    WtT[base] = hi;
    WtT[base + 2048] = f2bf(lo);
  }
}

__global__ __launch_bounds__(1024) void k_scan1(const int* __restrict__ deg_, int* __restrict__ rowptr_, int* __restrict__ bsums_){
  int br = blockIdx.y;
  const int* deg = deg_ + (size_t)br*NN;
  int* rowptr = rowptr_ + (size_t)br*RPN;
  int* bsums = bsums_ + (size_t)br*128;
  __shared__ int sm[1024];
  int t = threadIdx.x; int g = blockIdx.x*1024 + t;
  int v = (g < NN) ? deg[g] : 0;
  sm[t] = v; __syncthreads();
  for (int o=1;o<1024;o<<=1){
    int add = (t>=o)? sm[t-o] : 0;
    __syncthreads();
    sm[t] += add;
    __syncthreads();
  }
  if (g < NN) rowptr[g] = sm[t] - v;
  if (t == 1023) bsums[blockIdx.x] = sm[1023];
}

// r18: scan3 absorbs scan2 — each block locally scans the 98 block sums
__global__ __launch_bounds__(1024) void k_scan3(int* __restrict__ rowptr_, const int* __restrict__ bsums_, int* __restrict__ cursor_){
  int br = blockIdx.y;
  int* rowptr = rowptr_ + (size_t)br*RPN;
  const int* bsums = bsums_ + (size_t)br*128;
  int* cursor = cursor_ + (size_t)br*NN;
  __shared__ int pbs[128];
  int t = threadIdx.x;
  if (t < 128) pbs[t] = (t < 98) ? bsums[t] : 0;
  __syncthreads();
  for (int o=1;o<128;o<<=1){
    int add = 0;
    if (t < 128 && t >= o) add = pbs[t-o];
    __syncthreads();
    if (t < 128) pbs[t] += add;
    __syncthreads();
  }
  // exclusive offset for this block = inclusive[blk] - own value
  int off = pbs[blockIdx.x] - bsums[blockIdx.x];
  int g = blockIdx.x*1024 + t;
  if (g < NN){ int r = rowptr[g] + off; rowptr[g] = r; cursor[g] = r; }
  if (blockIdx.x==0 && t==0) rowptr[NN] = NE;
}

#define ASTRIDE 528

// ---------------- k_scat_g1: fused GEMM1 (blocks 0..GB_G1-1) + scatter (rest) ----------------
__global__ __launch_bounds__(256, 2) void k_scat_g1(
    const int* __restrict__ eiA, const int* __restrict__ eiB,
    int* __restrict__ cursor_, int* __restrict__ adj_,
    const float* __restrict__ xA, const float* __restrict__ xB,
    const u16* __restrict__ WtT_,
    const float* __restrict__ asA, const float* __restrict__ asB,
    const float* __restrict__ adA, const float* __restrict__ adB,
    float* __restrict__ out_, float* __restrict__ asrc_, float* __restrict__ adst_){
  int br = blockIdx.y;
  __shared__ u16 As[2][8*ASTRIDE];

  if (blockIdx.x >= GB_G1){
    // ---- scatter path ----
    const int* ei = br ? eiB : eiA;
    const int* src = ei;
    const int* dst = ei + NE;
    int* cursor = cursor_ + (size_t)br*NN;
    int* adj = adj_ + (size_t)br*NE;
    int e = (blockIdx.x - GB_G1)*256 + threadIdx.x;
    if (e < NE){ int d = dst[e]; int slot = atomicAdd(&cursor[d], 1); adj[slot] = src[e]; }
    return;
  }

  // ---- gemm1 path ----
  const float* x = br ? xB : xA;
  const u16* WtT = WtT_ + (size_t)br*2*16384;
  const float* a_src = br ? asB : asA;
  const float* a_dst = br ? adB : adA;
  float* out = out_ + (size_t)br*NN*HH;
  float* asrc = asrc_ + (size_t)br*NN;
  float* adst = adst_ + (size_t)br*NN;

  int tid = threadIdx.x;
  int row0 = blockIdx.x*64;
  int wave = tid>>6, lane = tid&63;
  int l15 = lane&15, quad = lane>>4;
  int col0 = wave*64;
  int sm_ = tid >> 2, sg = tid & 3;
  int sgrow = row0 + sm_; if (sgrow >= NN) sgrow = NN-1;
  f32x4 acc[4][4];
  #pragma unroll
  for (int mt=0;mt<4;mt++)
    #pragma unroll
    for (int nt=0;nt<4;nt++){ f32x4 z = {0.f,0.f,0.f,0.f}; acc[mt][nt] = z; }

  const u16* bbase = WtT + ((size_t)quad<<12) + (size_t)(col0 + l15)*8;
  bf16x8 B0h[4],B0l[4],B1h[4],B1l[4];
  float4 va0, va1;

  auto loadA = [&](int kc){
    va0 = *((const float4*)(x + (size_t)sgrow*FI + kc + sg*8));
    va1 = *((const float4*)(x + (size_t)sgrow*FI + kc + sg*8 + 4));
  };
  auto writeA = [&](int wb){
    bf16x8 h, l;
    split8(va0, va1, h, l);
    *((bf16x8*)&As[wb][sg*ASTRIDE + sm_*8]) = h;
    *((bf16x8*)&As[wb][(4+sg)*ASTRIDE + sm_*8]) = l;
  };
  auto loadB = [&](int ck, bf16x8 (&Bh)[4], bf16x8 (&Bl)[4]){
    const u16* bb = bbase + ((size_t)ck<<14);
    #pragma unroll
    for (int nt=0;nt<4;nt++){
      Bh[nt] = *((const bf16x8*)(bb + nt*128));
      Bl[nt] = *((const bf16x8*)(bb + 2048 + nt*128));
    }
  };
  auto mmacc = [&](int rb, bf16x8 (&Bh)[4], bf16x8 (&Bl)[4]){
    bf16x8 ah[4], al[4];
    #pragma unroll
    for (int mt=0;mt<4;mt++){
      int m = mt*16 + l15;
      ah[mt] = *((bf16x8*)&As[rb][quad*ASTRIDE + m*8]);
      al[mt] = *((bf16x8*)&As[rb][(4+quad)*ASTRIDE + m*8]);
    }
    #pragma unroll
    for (int nt=0;nt<4;nt++)
      #pragma unroll
      for (int mt=0;mt<4;mt++){
        acc[mt][nt] = __builtin_amdgcn_mfma_f32_16x16x32_bf16(ah[mt], Bh[nt], acc[mt][nt], 0, 0, 0);
        acc[mt][nt] = __builtin_amdgcn_mfma_f32_16x16x32_bf16(al[mt], Bh[nt], acc[mt][nt], 0, 0, 0);
        acc[mt][nt] = __builtin_amdgcn_mfma_f32_16x16x32_bf16(ah[mt], Bl[nt], acc[mt][nt], 0, 0, 0);
      }
  };

  loadA(0);
  writeA(0);
  loadA(32);
  loadB(0, B0h, B0l);
  softBarrier();
  writeA(1);
  loadB(1, B1h, B1l);
  mmacc(0, B0h, B0l);
  softBarrier();
  mmacc(1, B1h, B1l);

  float ps[4][4], pd[4][4];
  #pragma unroll
  for (int mt=0;mt<4;mt++)
    #pragma unroll
    for (int r=0;r<4;r++){ ps[mt][r]=0.f; pd[mt][r]=0.f; }
  #pragma unroll
  for (int nt=0;nt<4;nt++){
    int c = col0 + nt*16 + l15;
    float av = a_src[c], dv = a_dst[c];
    #pragma unroll
    for (int mt=0;mt<4;mt++){
      int gbase = row0 + mt*16 + quad*4;
      #pragma unroll
      for (int r=0;r<4;r++){
        int grow = gbase + r;
        float v = acc[mt][nt][r];
        if (grow < NN) out[(size_t)grow*HH + c] = v;
        ps[mt][r] += v*av; pd[mt][r] += v*dv;
      }
    }
  }
  __syncthreads();
  float* sda = (float*)As;
  float* sdd = sda + 256;
  #pragma unroll
  for (int mt=0;mt<4;mt++)
    #pragma unroll
    for (int r=0;r<4;r++){
      float s = qredsum(ps[mt][r]);
      float d = qredsum(pd[mt][r]);
      if (l15 == 0){
        int row = mt*16 + quad*4 + r;
        sda[wave*64 + row] = s;
        sdd[wave*64 + row] = d;
      }
    }
  __syncthreads();
  if (tid < 64){
    int grow = row0 + tid;
    if (grow < NN){
      asrc[grow] = sda[tid] + sda[64+tid] + sda[128+tid] + sda[192+tid];
      adst[grow] = sdd[tid] + sdd[64+tid] + sdd[128+tid] + sdd[192+tid];
    }
  }
}

// ---------------- GAT (4-way unrolled gather; fused BN1 partial stats) ----------------
__global__ __launch_bounds__(256) void k_gat(const float* __restrict__ h_, const float* __restrict__ asrc_,
     const float* __restrict__ adst_, const int* __restrict__ rowptr_, const int* __restrict__ adj_,
     const float* __restrict__ biasA, const float* __restrict__ biasB, float* __restrict__ out_,
     float* __restrict__ gpart_){
  int br = blockIdx.y;
  const float* h = h_ + (size_t)br*NN*HH;
  const float* asrc = asrc_ + (size_t)br*NN;
  const float* adst = adst_ + (size_t)br*NN;
  const int* rowptr = rowptr_ + (size_t)br*RPN;
  const int* adj = adj_ + (size_t)br*NE;
  const float* bias = br ? biasB : biasA;
  float* out = out_ + (size_t)br*NN*HH;
  float* gpart = gpart_ + (size_t)br*PCOPIES*512;

  __shared__ float smst[4*512];

  int wid = threadIdx.x>>6;
  int node = blockIdx.x*4 + wid;
  int lane = threadIdx.x & 63;
  int rs = rowptr[node], re = rowptr[node+1];
  int deg = re - rs;
  float adsti = adst[node];
  float eself = leaky02(asrc[node] + adsti);
  int c0 = lane*4;
  float4 acc;
  float4 bv = *((const float4*)&bias[c0]);
  if (deg <= 64){
    bool act = lane < deg;
    int sv = 0; float asv = 0.f;
    if (act){ sv = adj[rs + lane]; asv = asrc[sv]; }
    float e_l = act ? leaky02(asv + adsti) : -INFINITY;
    float m = fmaxf(eself, wredmax(e_l));
    float ex = act ? expf(e_l - m) : 0.f;
    float es = expf(eself - m);
    float denom = wredsum(ex) + es + 1e-16f;
    float aself = es/denom;
    float av = ex/denom;
    float4 hv = *((const float4*)&h[(size_t)node*HH + c0]);
    acc = make_float4(hv.x*aself, hv.y*aself, hv.z*aself, hv.w*aself);
    float4 a2 = make_float4(-INFINITY,-INFINITY,-INFINITY,-INFINITY);
    float4 a3 = a2, a4 = a2;
    int jj = 0;
    for (; jj+3 < deg; jj += 4){
      int sb0 = __shfl(sv, jj,   64); float ab0 = __shfl(av, jj,   64);
      int sb1 = __shfl(sv, jj+1, 64); float ab1 = __shfl(av, jj+1, 64);
      int sb2 = __shfl(sv, jj+2, 64); float ab2 = __shfl(av, jj+2, 64);
      int sb3 = __shfl(sv, jj+3, 64); float ab3 = __shfl(av, jj+3, 64);
      float4 q0 = *((const float4*)&h[(size_t)sb0*HH + c0]);
      float4 q1 = *((const float4*)&h[(size_t)sb1*HH + c0]);
      float4 q2 = *((const float4*)&h[(size_t)sb2*HH + c0]);
      float4 q3 = *((const float4*)&h[(size_t)sb3*HH + c0]);
      acc = fmax4(acc, make_float4(q0.x*ab0, q0.y*ab0, q0.z*ab0, q0.w*ab0));
      a2  = fmax4(a2,  make_float4(q1.x*ab1, q1.y*ab1, q1.z*ab1, q1.w*ab1));
      a3  = fmax4(a3,  make_float4(q2.x*ab2, q2.y*ab2, q2.z*ab2, q2.w*ab2));
      a4  = fmax4(a4,  make_float4(q3.x*ab3, q3.y*ab3, q3.z*ab3, q3.w*ab3));
    }
    for (; jj < deg; jj++){
      int sb = __shfl(sv, jj, 64);
      float ab = __shfl(av, jj, 64);
      float4 q = *((const float4*)&h[(size_t)sb*HH + c0]);
      acc = fmax4(acc, make_float4(q.x*ab, q.y*ab, q.z*ab, q.w*ab));
    }
    acc = fmax4(fmax4(acc, a2), fmax4(a3, a4));
  } else {
    float m = eself;
    for (int j = rs + lane; j < re; j += 64) m = fmaxf(m, leaky02(asrc[adj[j]] + adsti));
    m = wredmax(m);
    float ssum = 0.f;
    for (int j = rs + lane; j < re; j += 64) ssum += expf(leaky02(asrc[adj[j]] + adsti) - m);
    ssum = wredsum(ssum) + expf(eself - m);
    float denom = ssum + 1e-16f;
    float aself = expf(eself - m)/denom;
    float4 hv = *((const float4*)&h[(size_t)node*HH + c0]);
    acc = make_float4(hv.x*aself, hv.y*aself, hv.z*aself, hv.w*aself);
    float4 a2 = make_float4(-INFINITY,-INFINITY,-INFINITY,-INFINITY);
    float4 a3 = a2, a4 = a2;
    for (int jb = rs; jb < re; jb += 64){
      int cnt = min(64, re - jb);
      int sv = 0; float av = 0.f;
      if (lane < cnt){ sv = adj[jb+lane]; av = expf(leaky02(asrc[sv] + adsti) - m)/denom; }
      int jj = 0;
      for (; jj+3 < cnt; jj += 4){
        int sb0 = __shfl(sv, jj,   64); float ab0 = __shfl(av, jj,   64);
        int sb1 = __shfl(sv, jj+1, 64); float ab1 = __shfl(av, jj+1, 64);
        int sb2 = __shfl(sv, jj+2, 64); float ab2 = __shfl(av, jj+2, 64);
        int sb3 = __shfl(sv, jj+3, 64); float ab3 = __shfl(av, jj+3, 64);
        float4 q0 = *((const float4*)&h[(size_t)sb0*HH + c0]);
        float4 q1 = *((const float4*)&h[(size_t)sb1*HH + c0]);
        float4 q2 = *((const float4*)&h[(size_t)sb2*HH + c0]);
        float4 q3 = *((const float4*)&h[(size_t)sb3*HH + c0]);
        acc = fmax4(acc, make_float4(q0.x*ab0, q0.y*ab0, q0.z*ab0, q0.w*ab0));
        a2  = fmax4(a2,  make_float4(q1.x*ab1, q1.y*ab1, q1.z*ab1, q1.w*ab1));
        a3  = fmax4(a3,  make_float4(q2.x*ab2, q2.y*ab2, q2.z*ab2, q2.w*ab2));
        a4  = fmax4(a4,  make_float4(q3.x*ab3, q3.y*ab3, q3.z*ab3, q3.w*ab3));
      }
      for (; jj < cnt; jj++){
        int sb = __shfl(sv, jj, 64);
        float ab = __shfl(av, jj, 64);
        float4 q = *((const float4*)&h[(size_t)sb*HH + c0]);
        acc = fmax4(acc, make_float4(q.x*ab, q.y*ab, q.z*ab, q.w*ab));
      }
    }
    acc = fmax4(fmax4(acc, a2), fmax4(a3, a4));
  }
  acc.x += bv.x; acc.y += bv.y; acc.z += bv.z; acc.w += bv.w;
  *((float4*)&out[(size_t)node*HH + c0]) = acc;

  // fused BN1 partial statistics (value + square per channel, 4 nodes/block)
  float* my = &smst[wid*512];
  my[c0+0] = acc.x; my[c0+1] = acc.y; my[c0+2] = acc.z; my[c0+3] = acc.w;
  my[256+c0+0] = acc.x*acc.x; my[256+c0+1] = acc.y*acc.y;
  my[256+c0+2] = acc.z*acc.z; my[256+c0+3] = acc.w*acc.w;
  __syncthreads();
  int t = threadIdx.x;   // 0..255: channel t
  float p0 = smst[t]     + smst[512+t]     + smst[1024+t]     + smst[1536+t];
  float p1 = smst[256+t] + smst[512+256+t] + smst[1024+256+t] + smst[1536+256+t];
  int copy = blockIdx.x & (PCOPIES-1);
  atomicAdd(&gpart[copy*512 + t], p0);
  atomicAdd(&gpart[copy*512 + 256 + t], p1);
}

// ---------------- BN finalize from gat partials (BN1) ----------------
__global__ __launch_bounds__(256) void k_bnfinP(const float* __restrict__ gpart_,
    const float* __restrict__ gA, const float* __restrict__ gB,
    const float* __restrict__ bA, const float* __restrict__ bB,
    float* __restrict__ scale_, float* __restrict__ shift_){
  int br = blockIdx.y;
  const float* gp = gpart_ + (size_t)br*PCOPIES*512;
  const float* g = br ? gB : gA;
  const float* b = br ? bB : bA;
  float* scale = scale_ + (size_t)br*HH;
  float* shift = shift_ + (size_t)br*HH;
  int c = threadIdx.x;
  float s = 0.f, q = 0.f;
  #pragma unroll 8
  for (int p=0;p<PCOPIES;p++){ s += gp[p*512 + c]; q += gp[p*512 + 256 + c]; }
  float mean = s/(float)NN;
  float var = q/(float)NN - mean*mean;
  float rstd = rsqrtf(var + 1e-5f);
  float sc = g[c]*rstd;
  scale[c] = sc; shift[c] = b[c] - mean*sc;
}

// ---------------- BN finalize from sums (BN2) ----------------
__global__ __launch_bounds__(256) void k_bnfin(const float* __restrict__ sums_,
    const float* __restrict__ gA, const float* __restrict__ gB,
    const float* __restrict__ bA, const float* __restrict__ bB,
    float* __restrict__ scale_, float* __restrict__ shift_){
  int br = blockIdx.y;
  const float* sums = sums_ + (size_t)br*2*HH;
  const float* sumsq = sums + HH;
  const float* g = br ? gB : gA;
  const float* b = br ? bB : bA;
  float* scale = scale_ + (size_t)br*HH;
  float* shift = shift_ + (size_t)br*HH;
  int c = threadIdx.x;
  float mean = sums[c]/(float)NN;
  float var = sumsq[c]/(float)NN - mean*mean;
  float rstd = rsqrtf(var + 1e-5f);
  float sc = g[c]*rstd;
  scale[c] = sc; shift[c] = b[c] - mean*sc;
}

// ---------------- SAGE max-aggregate (4-way unrolled gather) ----------------
__global__ __launch_bounds__(256) void k_sageagg(const float* __restrict__ xin_, const float* __restrict__ scale_,
    const float* __restrict__ shift_, const float* __restrict__ pA, const float* __restrict__ pB,
    const int* __restrict__ rowptr_, const int* __restrict__ adj_, float* __restrict__ agg_){
  int br = blockIdx.y;
  const float* xin = xin_ + (size_t)br*NN*HH;
  const float* scale = scale_ + (size_t)br*HH;
  const float* shift = shift_ + (size_t)br*HH;
  const float* prelu = br ? pB : pA;
  const int* rowptr = rowptr_ + (size_t)br*RPN;
  const int* adj = adj_ + (size_t)br*NE;
  float* agg = agg_ + (size_t)br*NN*HH;

  int node = blockIdx.x*4 + (threadIdx.x>>6);
  int lane = threadIdx.x & 63;
  int rs = rowptr[node], re = rowptr[node+1];
  int c0 = lane*4;
  float slope = prelu[0];
  float4 sc = *((const float4*)&scale[c0]);
  float4 sh = *((const float4*)&shift[c0]);
  float4 acc = make_float4(-INFINITY,-INFINITY,-INFINITY,-INFINITY);
  float4 a2 = acc, a3 = acc, a4 = acc;
  for (int jb = rs; jb < re; jb += 64){
    int cnt = min(64, re - jb);
    int sv = (lane < cnt) ? adj[jb+lane] : 0;
    int jj = 0;
    for (; jj+3 < cnt; jj += 4){
      int sb0 = __shfl(sv, jj,   64);
      int sb1 = __shfl(sv, jj+1, 64);
      int sb2 = __shfl(sv, jj+2, 64);
      int sb3 = __shfl(sv, jj+3, 64);
      float4 q0 = *((const float4*)&xin[(size_t)sb0*HH + c0]);
      float4 q1 = *((const float4*)&xin[(size_t)sb1*HH + c0]);
      float4 q2 = *((const float4*)&xin[(size_t)sb2*HH + c0]);
      float4 q3 = *((const float4*)&xin[(size_t)sb3*HH + c0]);
      acc = fmax4(acc, bnprelu4(q0, sc, sh, slope));
      a2  = fmax4(a2,  bnprelu4(q1, sc, sh, slope));
      a3  = fmax4(a3,  bnprelu4(q2, sc, sh, slope));
      a4  = fmax4(a4,  bnprelu4(q3, sc, sh, slope));
    }
    for (; jj < cnt; jj++){
      int sb = __shfl(sv, jj, 64);
      float4 q = *((const float4*)&xin[(size_t)sb*HH + c0]);
      acc = fmax4(acc, bnprelu4(q, sc, sh, slope));
    }
  }
  acc = fmax4(fmax4(acc, a2), fmax4(a3, a4));
  if (re == rs) acc = make_float4(0.f,0.f,0.f,0.f);
  *((float4*)&agg[(size_t)node*HH + c0]) = acc;
}

// ---------------- GEMM2 (r13-verified: M=64 x N=256, 512 thr / 8 waves, wave 64x32) ----------------
__global__ __launch_bounds__(512, 4) void k_gemm2(const float* __restrict__ graw_, const float* __restrict__ agg_,
    const u16* __restrict__ WtT_,
    const float* __restrict__ scale1_, const float* __restrict__ shift1_,
    const float* __restrict__ p1A, const float* __restrict__ p1B,
    const float* __restrict__ blA, const float* __restrict__ blB,
    float* __restrict__ out_, float* __restrict__ sums_){
  int br = blockIdx.y;
  const float* graw = graw_ + (size_t)br*NN*HH;
  const float* agg = agg_ + (size_t)br*NN*HH;
  const u16* WtT = WtT_ + (size_t)br*16*16384;
  const float* scale1 = scale1_ + (size_t)br*HH;
  const float* shift1 = shift1_ + (size_t)br*HH;
  const float* prelu1 = br ? p1B : p1A;
  const float* bl = br ? blB : blA;
  float* out = out_ + (size_t)br*NN*HH;
  float* sums = sums_ + (size_t)br*2*HH;
  float* sumsq = sums + HH;

  __shared__ u16 As[2][8*ASTRIDE];
  int tid = threadIdx.x;
  int row0 = blockIdx.x*64;
  int wave = tid>>6, lane = tid&63;
  int l15 = lane&15, quad = lane>>4;
  int col0 = wave*32;
  int sm_ = tid >> 3, sg = tid & 7;   // 8 threads per row, 4 floats each
  int sgrow = row0 + sm_; if (sgrow >= NN) sgrow = NN-1;
  float slope = prelu1[0];
  f32x4 acc[4][2];
  #pragma unroll
  for (int mt=0;mt<4;mt++)
    #pragma unroll
    for (int nt=0;nt<2;nt++){ f32x4 z = {0.f,0.f,0.f,0.f}; acc[mt][nt] = z; }

  const u16* bbase = WtT + ((size_t)quad<<12) + (size_t)(col0 + l15)*8;
  bf16x8 B0h[2],B0l[2],B1h[2],B1l[2];
  float4 vaA, vaB;

  auto loadA = [&](int kc, float4& dst){
    const float* ab = (kc < HH) ? graw : agg;
    int ac = (kc < HH) ? kc : kc - HH;
    dst = *((const float4*)(ab + (size_t)sgrow*HH + ac + sg*4));
  };
  auto writeA = [&](int kc, int wb, float4 v){
    if (kc < HH){
      int kcol = kc + sg*4;
      v = bnprelu4(v, *((const float4*)(scale1+kcol)), *((const float4*)(shift1+kcol)), slope);
    }
    bf16x4 h, l;
    split4(v, h, l);
    int cell = (sg>>1)*ASTRIDE + sm_*8 + (sg&1)*4;
    *((bf16x4*)&As[wb][cell]) = h;
    *((bf16x4*)&As[wb][cell + 4*ASTRIDE]) = l;
  };
  auto loadB = [&](int ck, bf16x8 (&Bh)[2], bf16x8 (&Bl)[2]){
    const u16* bb = bbase + ((size_t)ck<<14);
    #pragma unroll
    for (int nt=0;nt<2;nt++){
      Bh[nt] = *((const bf16x8*)(bb + nt*128));
      Bl[nt] = *((const bf16x8*)(bb + 2048 + nt*128));
    }
  };
  auto body = [&](int k, int rb, float4& vaW, float4& vaL, bf16x8 (&Bh)[2], bf16x8 (&Bl)[2], bf16x8 (&nBh)[2], bf16x8 (&nBl)[2]){
    softBarrier();
    if (k < 15) writeA((k+1)*32, rb^1, vaW);
    if (k < 13) loadA((k+3)*32, vaW);
    if (k < 15) loadB(k+1, nBh, nBl);
    (void)vaL;
    #pragma unroll
    for (int mt=0;mt<4;mt++){
      int m = mt*16 + l15;
      bf16x8 ah = *((bf16x8*)&As[rb][quad*ASTRIDE + m*8]);
      bf16x8 al = *((bf16x8*)&As[rb][(4+quad)*ASTRIDE + m*8]);
      #pragma unroll
      for (int nt=0;nt<2;nt++){
        acc[mt][nt] = __builtin_amdgcn_mfma_f32_16x16x32_bf16(ah, Bh[nt], acc[mt][nt], 0, 0, 0);
        acc[mt][nt] = __builtin_amdgcn_mfma_f32_16x16x32_bf16(al, Bh[nt], acc[mt][nt], 0, 0, 0);
        acc[mt][nt] = __builtin_amdgcn_mfma_f32_16x16x32_bf16(ah, Bl[nt], acc[mt][nt], 0, 0, 0);
      }
    }
  };

  loadA(0, vaA);
  writeA(0, 0, vaA);
  loadA(32, vaA);
  loadA(64, vaB);
  loadB(0, B0h, B0l);
  #pragma unroll 1
  for (int k=0; k<16; k+=2){
    body(k,   0, vaA, vaB, B0h,B0l, B1h,B1l);
    body(k+1, 1, vaB, vaA, B1h,B1l, B0h,B0l);
  }

  float psum[2], psq[2];
  #pragma unroll
  for (int nt=0;nt<2;nt++){
    int c = col0 + nt*16 + l15;
    float bcol = bl[c];
    float s=0.f, q=0.f;
    #pragma unroll
    for (int mt=0;mt<4;mt++){
      int gbase = row0 + mt*16 + quad*4;
      #pragma unroll
      for (int r=0;r<4;r++){
        int grow = gbase + r;
        float v = acc[mt][nt][r] + bcol;
        if (grow < NN){
          out[(size_t)grow*HH + c] = v;
          s += v; q += v*v;
        }
      }
    }
    psum[nt]=s; psq[nt]=q;
  }
  __syncthreads();
  float* sm2 = (float*)As;
  sm2[tid] = 0.f;
  __syncthreads();
  #pragma unroll
  for (int nt=0;nt<2;nt++){
    int c = col0 + nt*16 + l15;
    atomicAdd(&sm2[c], psum[nt]);
    atomicAdd(&sm2[256+c], psq[nt]);
  }
  __syncthreads();
  if (tid < 256){
    atomicAdd(&sums[tid],  sm2[tid]);
    atomicAdd(&sumsq[tid], sm2[256+tid]);
  }
}

// ---------------- pool GEMVs ----------------
__global__ __launch_bounds__(256) void k_gemv2(const float* __restrict__ x2_, const float* __restrict__ scale2_,
    const float* __restrict__ shift2_, const float* __restrict__ p2A, const float* __restrict__ p2B,
    const float* __restrict__ WrelA, const float* __restrict__ WrelB,
    const float* __restrict__ WrootA, const float* __restrict__ WrootB,
    float* __restrict__ y2_, float* __restrict__ y2r_){
  int br = blockIdx.y;
  const float* x2raw = x2_ + (size_t)br*NN*HH;
  const float* scale2 = scale2_ + (size_t)br*HH;
  const float* shift2 = shift2_ + (size_t)br*HH;
  const float* prelu2 = br ? p2B : p2A;
  const float* Wrel = br ? WrelB : WrelA;
  const float* Wroot = br ? WrootB : WrootA;
  float* y2 = y2_ + (size_t)br*NN;
  float* y2r = y2r_ + (size_t)br*NN;

  int node = blockIdx.x*4 + (threadIdx.x>>6);
  int lane = threadIdx.x & 63;
  int c0 = lane*4;
  float slope = prelu2[0];
  float4 v = *((const float4*)&x2raw[(size_t)node*HH + c0]);
  float4 sc = *((const float4*)&scale2[c0]);
  float4 sh = *((const float4*)&shift2[c0]);
  v = bnprelu4(v, sc, sh, slope);
  float4 wr = *((const float4*)&Wrel[c0]);
  float4 wo = *((const float4*)&Wroot[c0]);
  float pr = v.x*wr.x + v.y*wr.y + v.z*wr.z + v.w*wr.w;
  float po = v.x*wo.x + v.y*wo.y + v.z*wo.z + v.w*wo.w;
  pr = wredsum(pr); po = wredsum(po);
  if (lane==0){ y2[node] = pr; y2r[node] = po; }
}

// k_score with fused hist1 (2-way ILP on y2 gather)
__global__ void k_score(const int* __restrict__ rowptr_, const int* __restrict__ adj_, const float* __restrict__ y2_,
    const float* __restrict__ y2r_, const float* __restrict__ brelA, const float* __restrict__ brelB,
    float* __restrict__ score_, unsigned* __restrict__ keys_, unsigned* __restrict__ hist_){
  int br = blockIdx.y;
  const int* rowptr = rowptr_ + (size_t)br*RPN;
  const int* adj = adj_ + (size_t)br*NE;
  const float* y2 = y2_ + (size_t)br*NN;
  const float* y2r = y2r_ + (size_t)br*NN;
  const float* brel = br ? brelB : brelA;
  float* score = score_ + (size_t)br*NN;
  unsigned* keys = keys_ + (size_t)br*NN;
  unsigned* hist = hist_ + (size_t)br*65536;

  int i = blockIdx.x*blockDim.x + threadIdx.x;
  if (i >= NN) return;
  float s0 = 0.f, s1 = 0.f;
  int rs = rowptr[i], re = rowptr[i+1];
  int j = rs;
  for (; j+1 < re; j += 2){ s0 += y2[adj[j]]; s1 += y2[adj[j+1]]; }
  if (j < re) s0 += y2[adj[j]];
  float sc = s0 + s1 + brel[0] + y2r[i];
  score[i] = sc;
  unsigned u = __float_as_uint(sc);
  u = (u & 0x80000000u) ? ~u : (u | 0x80000000u);
  keys[i] = u;
  atomicAdd(&hist[u>>16], 1u);
}

// parallel suffix-scan findbin: uint4 coarse sums + log-step scans
__global__ __launch_bounds__(256) void k_findbin1(const unsigned* __restrict__ hist_, unsigned* __restrict__ scal_){
  int br = blockIdx.y;
  const unsigned* hist = hist_ + (size_t)br*65536;
  unsigned* scal = scal_ + (size_t)br*16;
  __shared__ unsigned suf[256];
  __shared__ unsigned shc[2];
  int t = threadIdx.x;
  const uint4* h4 = (const uint4*)(hist + t*256);
  unsigned s = 0;
  #pragma unroll 8
  for (int b=0;b<64;b++){ uint4 v = h4[b]; s += v.x+v.y+v.z+v.w; }
  suf[t] = s; __syncthreads();
  #pragma unroll
  for (int o=1;o<256;o<<=1){
    unsigned add = (t+o<256)? suf[t+o] : 0u;
    __syncthreads();
    suf[t] += add;
    __syncthreads();
  }
  unsigned ab = suf[t] - s;
  if (ab < (unsigned)KT && ab + s >= (unsigned)KT){ shc[0] = (unsigned)t; shc[1] = ab; }
  __syncthreads();
  int cb = (int)shc[0]; unsigned runbase = shc[1];
  unsigned f = hist[cb*256 + t];
  suf[t] = f; __syncthreads();
  #pragma unroll
  for (int o=1;o<256;o<<=1){
    unsigned add = (t+o<256)? suf[t+o] : 0u;
    __syncthreads();
    suf[t] += add;
    __syncthreads();
  }
  unsigned ta = runbase + suf[t] - f;
  if (ta < (unsigned)KT && ta + f >= (unsigned)KT){
    scal[0] = (unsigned)(cb*256 + t);
    scal[1] = ta;
  }
}

__global__ void k_hist2(const unsigned* __restrict__ keys_, const unsigned* __restrict__ scal_, unsigned* __restrict__ hist_){
  int br = blockIdx.y;
  const unsigned* keys = keys_ + (size_t)br*NN;
  const unsigned* scal = scal_ + (size_t)br*16;
  unsigned* hist = hist_ + (size_t)br*65536;
  int i = blockIdx.x*blockDim.x + threadIdx.x;
  if (i < NN){ unsigned k = keys[i]; if ((k>>16) == scal[0]) atomicAdd(&hist[k & 0xFFFFu], 1u); }
}

__global__ __launch_bounds__(256) void k_findbin2(const unsigned* __restrict__ hist_, unsigned* __restrict__ scal_){
  int br = blockIdx.y;
  const unsigned* hist = hist_ + (size_t)br*65536;
  unsigned* scal = scal_ + (size_t)br*16;
  __shared__ unsigned suf[256];
  __shared__ unsigned shc[2];
  int t = threadIdx.x;
  unsigned target = (unsigned)KT - scal[1];
  const uint4* h4 = (const uint4*)(hist + t*256);
  unsigned s = 0;
  #pragma unroll 8
  for (int b=0;b<64;b++){ uint4 v = h4[b]; s += v.x+v.y+v.z+v.w; }
  suf[t] = s; __syncthreads();
  #pragma unroll
  for (int o=1;o<256;o<<=1){
    unsigned add = (t+o<256)? suf[t+o] : 0u;
    __syncthreads();
    suf[t] += add;
    __syncthreads();
  }
  unsigned ab = suf[t] - s;
  if (ab < target && ab + s >= target){ shc[0] = (unsigned)t; shc[1] = ab; }
  __syncthreads();
  int cb = (int)shc[0]; unsigned runbase = shc[1];
  unsigned f = hist[cb*256 + t];
  suf[t] = f; __syncthreads();
  #pragma unroll
  for (int o=1;o<256;o<<=1){
    unsigned add = (t+o<256)? suf[t+o] : 0u;
    __syncthreads();
    suf[t] += add;
    __syncthreads();
  }
  unsigned ta = runbase + suf[t] - f;
  if (ta < target && ta + f >= target){
    scal[2] = (scal[0] << 16) | (unsigned)(cb*256 + t);
    scal[3] = target - ta;
    scal[4] = f;
  }
}

__global__ void k_select(const unsigned* __restrict__ keys_, const float* __restrict__ score_,
    unsigned* __restrict__ scal_, int* __restrict__ selidx_, float* __restrict__ tvals_){
  int br = blockIdx.y;
  const unsigned* keys = keys_ + (size_t)br*NN;
  const float* score = score_ + (size_t)br*NN;
  unsigned* scal = scal_ + (size_t)br*16;
  int* selidx = selidx_ + (size_t)br*NN;
  float* tvals = tvals_ + (size_t)br*NN;

  int i = blockIdx.x*blockDim.x + threadIdx.x;
  if (i >= NN) return;
  unsigned T = scal[2], needed = scal[3], cnteq = scal[4];
  unsigned k = keys[i];
  int s = 0;
  if (k > T) s = 1;
  else if (k == T){
    if (cnteq <= needed) s = 1;
    else {
      unsigned rank = 0;
      for (int j=0;j<i;j++) rank += (keys[j] == T) ? 1u : 0u;
      s = (rank < needed) ? 1 : 0;
    }
  }
  if (s){
    unsigned idx = atomicAdd(&scal[8], 1u);
    selidx[idx] = i;
    tvals[idx] = tanhf(score[i]);
  }
}

// 1024 blocks/branch + 2-way unrolled row gather
__global__ __launch_bounds__(256) void k_embed(const float* __restrict__ x2_, const float* __restrict__ scale2_,
    const float* __restrict__ shift2_, const float* __restrict__ p2A, const float* __restrict__ p2B,
    const int* __restrict__ selidx_, const float* __restrict__ tvals_, float* __restrict__ embed){
  int br = blockIdx.y;
  const float* x2raw = x2_ + (size_t)br*NN*HH;
  const float* scale2 = scale2_ + (size_t)br*HH;
  const float* shift2 = shift2_ + (size_t)br*HH;
  const float* prelu2 = br ? p2B : p2A;
  const int* selidx = selidx_ + (size_t)br*NN;
  const float* tvals = tvals_ + (size_t)br*NN;

  int c = threadIdx.x;
  float slope = prelu2[0];
  float scv = scale2[c], shv = shift2[c];
  float best = -INFINITY, best2 = -INFINITY;
  int stride = gridDim.x;
  for (int j = blockIdx.x; j < KT; j += 2*stride){
    int j1 = j + stride;
    int r0 = selidx[j];
    float t0 = tvals[j];
    int r1 = (j1 < KT) ? selidx[j1] : r0;
    float v0 = preluf(x2raw[(size_t)r0*HH + c]*scv + shv, slope);
    best = fmaxf(best, v0*t0);
    if (j1 < KT){
      float t1 = tvals[j1];
      float v1 = preluf(x2raw[(size_t)r1*HH + c]*scv + shv, slope);
      best2 = fmaxf(best2, v1*t1);
    }
  }
  best = fmaxf(best, best2);
  atomicMaxF(&embed[(size_t)br*HH + c], best);
}

__global__ void k_initembed(float* __restrict__ embed){
  int i = threadIdx.x;
  if (i < 2*HH) embed[i] = -INFINITY;
}

// ---------------- head ----------------
__global__ __launch_bounds__(256) void k_head(const float* __restrict__ embed, const float* __restrict__ addf,
    const float* __restrict__ fc1W, const float* __restrict__ fc1b, const float* __restrict__ preluh,
    const float* __restrict__ fc2W, const float* __restrict__ fc2b, float* __restrict__ out){
  __shared__ float z[2*HH + 8];
  __shared__ float h1s[HH];
  __shared__ float red[4];
  int t = threadIdx.x;
  for (int i=t;i<2*HH;i+=256) z[i] = embed[i];
  if (t < 8) z[2*HH + t] = addf[t];
  __syncthreads();
  float acc = fc1b[t];
  for (int k=0;k<2*HH+8;k++) acc += z[k]*fc1W[(size_t)k*HH + t];
  float slope = preluh[0];
  h1s[t] = preluf(acc, slope);
  __syncthreads();
  float p = h1s[t]*fc2W[t];
  p = wredsum(p);
  if ((t & 63) == 0) red[t>>6] = p;
  __syncthreads();
  if (t == 0) out[0] = expf(red[0]+red[1]+red[2]+red[3] + fc2b[0]);
}

// ---------------- orchestration ----------------
extern "C" void kernel_launch(void* const* d_in, const int* in_sizes, int n_in,
                              void* d_out, int out_size, void* d_ws, size_t ws_size,
                              hipStream_t stream) {
  (void)in_sizes; (void)n_in; (void)out_size;
  char* ws = (char*)d_ws;

  float *bufA, *bufB, *asrc, *adst, *sums, *scale1, *shift1, *scale2, *shift2;
  float *y2, *y2r, *score, *tvals, *embed, *gpart;
  int *rowptr, *adj, *cursor, *bsums, *selidx;
  unsigned *keys, *hist1, *hist2, *scal;
  u16 *WtT, *WtT1;

  auto doAlloc = [&](int nb)->size_t{
    size_t o = 0;
    auto al = [&](size_t bytes)->char*{ char* p = ws + o; o = (o + bytes + 255) & ~(size_t)255; return p; };
    bufA   = (float*)al((size_t)nb*NN*HH*4);
    bufB   = (float*)al((size_t)nb*NN*HH*4);
    asrc   = (float*)al((size_t)nb*NN*4);
    adst   = (float*)al((size_t)nb*NN*4);
    rowptr = (int*)  al((size_t)nb*RPN*4);
    adj    = (int*)  al((size_t)nb*NE*4);
    cursor = (int*)  al((size_t)nb*NN*4);
    bsums  = (int*)  al((size_t)nb*128*4);
    sums   = (float*)al((size_t)nb*2*HH*4);
    gpart  = (float*)al((size_t)nb*PCOPIES*512*4);
    scale1 = (float*)al((size_t)nb*HH*4);
    shift1 = (float*)al((size_t)nb*HH*4);
    scale2 = (float*)al((size_t)nb*HH*4);
    shift2 = (float*)al((size_t)nb*HH*4);
    y2     = (float*)al((size_t)nb*NN*4);
    y2r    = (float*)al((size_t)nb*NN*4);
    score  = (float*)al((size_t)nb*NN*4);
    keys   = (unsigned*)al((size_t)nb*NN*4);
    selidx = (int*)  al((size_t)nb*NN*4);
    tvals  = (float*)al((size_t)nb*NN*4);
    hist1  = (unsigned*)al((size_t)nb*65536*4);
    hist2  = (unsigned*)al((size_t)nb*65536*4);
    scal   = (unsigned*)al((size_t)nb*64);
    embed  = (float*)al((size_t)2*HH*4);
    WtT    = (u16*)al((size_t)nb*16*16384*2);
    WtT1   = (u16*)al((size_t)nb*2*16384*2);
    return o;
  };

  int NB = 2;
  if (doAlloc(2) > ws_size) NB = 1;
  doAlloc(NB);

  const float* addf = (const float*)d_in[2];

  k_initembed<<<dim3(1), dim3(512), 0, stream>>>(embed);

  int nIter = (NB==2) ? 1 : 2;
  for (int it = 0; it < nIter; ++it){
    const float *xA, *xB; const int *eiA, *eiB; int pa, pb;
    if (NB == 2){
      xA = (const float*)d_in[0]; xB = (const float*)d_in[1];
      eiA = (const int*)d_in[3]; eiB = (const int*)d_in[4];
      pa = 5; pb = 21;
    } else {
      xA = xB = (const float*)d_in[it];
      eiA = eiB = (const int*)d_in[3+it];
      pa = pb = (it==0) ? 5 : 21;
    }
    auto PA = [&](int i){ return (const float*)d_in[pa+i]; };
    auto PB = [&](int i){ return (const float*)d_in[pb+i]; };

    // CSR degree count + W pre-split (fused, independent work)
    hipMemsetAsync(cursor, 0, (size_t)NB*NN*4, stream);
    hipMemsetAsync(gpart, 0, (size_t)NB*PCOPIES*512*4, stream);
    k_prep<<<dim3(GB_CT+GB_SW, NB), dim3(256), 0, stream>>>(eiA, eiB, cursor,
        PA(9), PB(9), PA(7), PB(7), PA(0), PB(0), WtT, WtT1);
    k_scan1<<<dim3(98, NB), dim3(1024), 0, stream>>>(cursor, rowptr, bsums);
    k_scan3<<<dim3(98, NB), dim3(1024), 0, stream>>>(rowptr, bsums, cursor);   // absorbs scan2

    // scatter (CSR adj) + GEMM1 fused: independent, overlap in one dispatch
    k_scat_g1<<<dim3(GB_G1+GB_SC, NB), dim3(256), 0, stream>>>(eiA, eiB, cursor, adj,
        xA, xB, WtT1, PA(1), PB(1), PA(2), PB(2), bufA, asrc, adst);

    // GAT (BN1 stats fused -> gpart partials)
    k_gat<<<dim3(25000, NB), dim3(256), 0, stream>>>(bufA, asrc, adst, rowptr, adj, PA(3), PB(3), bufB, gpart);
    k_bnfinP<<<dim3(1, NB), dim3(256), 0, stream>>>(gpart, PA(4), PB(4), PA(5), PB(5), scale1, shift1);

    // SAGE
    k_sageagg<<<dim3(25000, NB), dim3(256), 0, stream>>>(bufB, scale1, shift1, PA(6), PB(6), rowptr, adj, bufA);
    hipMemsetAsync(sums, 0, (size_t)NB*2*HH*4, stream);
    k_gemm2<<<dim3((NN+63)/64, NB), dim3(512), 0, stream>>>(bufB, bufA, WtT,
        scale1, shift1, PA(6), PB(6), PA(8), PB(8), bufB, sums);
    k_bnfin<<<dim3(1, NB), dim3(256), 0, stream>>>(sums, PA(10), PB(10), PA(11), PB(11), scale2, shift2);

    // SAGPool (hist1 fused into k_score; memsets hoisted)
    hipMemsetAsync(scal, 0, (size_t)NB*64, stream);
    hipMemsetAsync(hist1, 0, (size_t)NB*65536*4, stream);
    hipMemsetAsync(hist2, 0, (size_t)NB*65536*4, stream);
    k_gemv2<<<dim3(25000, NB), dim3(256), 0, stream>>>(bufB, scale2, shift2, PA(12), PB(12),
        PA(13), PB(13), PA(15), PB(15), y2, y2r);
    k_score<<<dim3((NN+255)/256, NB), dim3(256), 0, stream>>>(rowptr, adj, y2, y2r, PA(14), PB(14), score, keys, hist1);
    k_findbin1<<<dim3(1, NB), dim3(256), 0, stream>>>(hist1, scal);
    k_hist2<<<dim3((NN+255)/256, NB), dim3(256), 0, stream>>>(keys, scal, hist2);
    k_findbin2<<<dim3(1, NB), dim3(256), 0, stream>>>(hist2, scal);
    k_select<<<dim3((NN+255)/256, NB), dim3(256), 0, stream>>>(keys, score, scal, selidx, tvals);
    float* embDst = (NB==2) ? embed : (embed + it*HH);
    k_embed<<<dim3(1024, NB), dim3(256), 0, stream>>>(bufB, scale2, shift2, PA(12), PB(12), selidx, tvals, embDst);
  }

  k_head<<<dim3(1), dim3(256), 0, stream>>>(embed, addf,
      (const float*)d_in[37], (const float*)d_in[38], (const float*)d_in[39],
      (const float*)d_in[40], (const float*)d_in[41], (float*)d_out);
}